// Round 6
// baseline (3050.412 us; speedup 1.0000x reference)
//
#include <hip/hip_runtime.h>

// MatchLSTM forward pipeline for MI355X.
// R6 = R5 with the macro-ordering compile fix. Pin recurrent weights in
// VGPRs with opaque empty-asm barriers — VGPR_Count=84 proved the compiler
// was REMATERIALIZING the weight loads from L2 every step (~2.7us/step of
// L2 streaming). asm "+v" makes the packed values opaque so they must stay
// register-resident.

typedef _Float16 f16;
typedef f16 f16x2 __attribute__((ext_vector_type(2)));
typedef unsigned int u32;
typedef unsigned short u16;

constexpr int cLP = 400, cLQ = 50, cB = 32, cH = 150, cG = 600;

__device__ __forceinline__ float exp2_(float x){
#if __has_builtin(__builtin_amdgcn_exp2f)
  return __builtin_amdgcn_exp2f(x);
#else
  return exp2f(x);
#endif
}
__device__ __forceinline__ float rcp_(float x){
#if __has_builtin(__builtin_amdgcn_rcpf)
  return __builtin_amdgcn_rcpf(x);
#else
  return 1.0f / x;
#endif
}
__device__ __forceinline__ float sigm(float x){ return rcp_(1.f + exp2_(-1.44269504f * x)); }
__device__ __forceinline__ float tanh_(float x){ return 1.f - 2.f * rcp_(1.f + exp2_(2.88539008f * x)); }

union U2 { u32 u; f16x2 h; };

__device__ __forceinline__ float fdot2_(u32 a, u32 b, float c){
  U2 ua, ub; ua.u = a; ub.u = b;
#if __has_builtin(__builtin_amdgcn_fdot2)
  return __builtin_amdgcn_fdot2(ua.h, ub.h, c, false);
#else
  return c + (float)ua.h[0] * (float)ub.h[0] + (float)ua.h[1] * (float)ub.h[1];
#endif
}
__device__ __forceinline__ u32 pack2(float x, float y){
  U2 p; p.h[0] = (f16)x; p.h[1] = (f16)y; return p.u;
}
__device__ __forceinline__ float2 unp2(u32 v){
  U2 p; p.u = v; return make_float2((float)p.h[0], (float)p.h[1]);
}

// load 4 f16x2 pairs (8 floats) from a weight row at pair offset 4*i
__device__ __forceinline__ uint4 ldw4(const float* __restrict__ wr, int i){
  uint4 r;
  r.x = pack2(wr[8*i+0], wr[8*i+1]);
  r.y = pack2(wr[8*i+2], wr[8*i+3]);
  r.z = pack2(wr[8*i+4], wr[8*i+5]);
  r.w = pack2(wr[8*i+6], wr[8*i+7]);
  return r;
}

// opaque barrier: values become asm outputs -> cannot be rematerialized
#define PIN4(v) asm volatile("" : "+v"(v.x), "+v"(v.y), "+v"(v.z), "+v"(v.w));
#define PIN4W(i) PIN4(w##i)
#define PIN4Q(i) PIN4(q##i)

#define REP18(M) M(0) M(1) M(2) M(3) M(4) M(5) M(6) M(7) M(8) M(9) \
                 M(10) M(11) M(12) M(13) M(14) M(15) M(16) M(17)
#define REP19(M) REP18(M) M(18)
#define REP7(M) M(0) M(1) M(2) M(3) M(4) M(5) M(6)

// ---------------------------------------------------------------------------
// Generic f32 GEMM: C[M][N] = A[M][K] @ W[N][K]^T (+bias). Optional embedding
// gather for A rows. Optional f16 output. Tile 64x64, 4x4/thread, 256 thr.
// ---------------------------------------------------------------------------
__global__ __launch_bounds__(256)
void gemm_k(const float* __restrict__ A, const int* __restrict__ ids,
            const float* __restrict__ emb,
            const float* __restrict__ W, int ldw, const float* __restrict__ bias,
            float* __restrict__ Cf, f16* __restrict__ Ch,
            int M, int N, int K)
{
  __shared__ __align__(16) float As[16][68];
  __shared__ __align__(16) float Wt[16][68];
  __shared__ int sids[64];
  int tid = threadIdx.x;
  int n0 = blockIdx.x * 64;
  int m0 = blockIdx.y * 64;
  int tx = tid & 15, ty = tid >> 4;
  if (ids){ if (tid < 64) sids[tid] = ids[m0 + tid]; }
  __syncthreads();

  float acc[4][4] = {};
  int sm = tid >> 2;
  int kq = (tid & 3) << 2;
  const float* arow = ids ? (emb + (size_t)sids[sm] * K)
                          : (A   + (size_t)(m0 + sm) * K);
  const float* wrow = W + (size_t)(n0 + sm) * ldw;
  bool nok = (n0 + sm) < N;

  for (int k0 = 0; k0 < K; k0 += 16){
    #pragma unroll
    for (int p = 0; p < 4; p++){
      int kk = kq + p, k = k0 + kk;
      As[kk][sm] = (k < K) ? arow[k] : 0.f;
      Wt[kk][sm] = (nok && k < K) ? wrow[k] : 0.f;
    }
    __syncthreads();
    #pragma unroll
    for (int kk = 0; kk < 16; kk++){
      float4 av = *(const float4*)&As[kk][ty << 2];
      float4 wv = *(const float4*)&Wt[kk][tx << 2];
      float a[4] = {av.x, av.y, av.z, av.w};
      float w[4] = {wv.x, wv.y, wv.z, wv.w};
      #pragma unroll
      for (int i = 0; i < 4; i++)
        #pragma unroll
        for (int j = 0; j < 4; j++)
          acc[i][j] += a[i] * w[j];
    }
    __syncthreads();
  }
  float bj[4];
  #pragma unroll
  for (int j = 0; j < 4; j++){
    int n = n0 + (tx << 2) + j;
    bj[j] = (bias && n < N) ? bias[n] : 0.f;
  }
  #pragma unroll
  for (int i = 0; i < 4; i++){
    int m = m0 + (ty << 2) + i;
    #pragma unroll
    for (int j = 0; j < 4; j++){
      int n = n0 + (tx << 2) + j;
      if (n < N){
        size_t ci = (size_t)m * N + n;
        float v = acc[i][j] + bj[j];
        if (Ch) Ch[ci] = (f16)v; else Cf[ci] = v;
      }
    }
  }
}

// ---------------------------------------------------------------------------
// Encoder LSTM. 64 WGs: wg<32 -> passage b, else question b. 640 threads.
// Whh rows in pinned uint4 VGPRs. XG prefetched 1 step ahead.
// ---------------------------------------------------------------------------
__global__ __launch_bounds__(640, 3)
void enc_k(const float* __restrict__ XGp, const float* __restrict__ XGq,
           const float* __restrict__ Whh,
           const int* __restrict__ plens, const int* __restrict__ qlens,
           float* __restrict__ Hp, float* __restrict__ Hq)
{
  int wg = blockIdx.x;
  bool isq = wg >= cB;
  int b = wg & (cB - 1);
  const float* XG = isq ? XGq : XGp;
  float* Hout = isq ? Hq : Hp;
  int T   = isq ? cLQ : cLP;
  int len = (isq ? qlens : plens)[b];
  int tid = threadIdx.x;

  __shared__ float c[cH], gl[cG];
  __shared__ __align__(16) u32 h2s[80];

#define DECLW(i) uint4 w##i;
  REP19(DECLW)
#undef DECLW
  {
    const float* wr = Whh + (size_t)(tid < cG ? tid : 0) * cH;
#define LOADW(i) w##i = ldw4(wr, i);
    REP18(LOADW)
#undef LOADW
    w18.x = pack2(wr[144], wr[145]);
    w18.y = pack2(wr[146], wr[147]);
    w18.z = pack2(wr[148], wr[149]);
    w18.w = 0;
    REP19(PIN4W)
  }
  if (tid < cH) c[tid] = 0.f;
  if (tid < 80) h2s[tid] = 0;
  __syncthreads();

  float xgCur = 0.f;
  if (tid < cG) xgCur = XG[(size_t)b * cG + tid];

  for (int t = 0; t < T; t++){
    int tn = (t + 1 < T) ? t + 1 : t;
    float xgN = 0.f;
    if (tid < cG) xgN = XG[((size_t)tn * cB + b) * cG + tid];

    if (tid < cG){
      float aA = 0.f, aB = 0.f, aC = 0.f, aD = 0.f;
#define DOTW(i) { uint4 hq = *(const uint4*)&h2s[4*(i)]; \
      aA = fdot2_(hq.x, w##i.x, aA); aB = fdot2_(hq.y, w##i.y, aB); \
      aC = fdot2_(hq.z, w##i.z, aC); aD = fdot2_(hq.w, w##i.w, aD); }
      REP19(DOTW)
#undef DOTW
      gl[tid] = xgCur + ((aA + aB) + (aC + aD));
    }
    __syncthreads();
    if (tid < 75){
      float hv[2];
      #pragma unroll
      for (int z = 0; z < 2; z++){
        int u = 2 * tid + z;
        float ig = sigm(gl[u]);
        float fg = sigm(gl[cH + u]);
        float gg = tanh_(gl[2 * cH + u]);
        float og = sigm(gl[3 * cH + u]);
        float c2 = fg * c[u] + ig * gg;
        float hh = og * tanh_(c2);
        c[u] = c2;
        hv[z] = hh;
      }
      h2s[tid] = pack2(hv[0], hv[1]);      // unmasked h carries the recurrence
      float mk = (t < len) ? 1.f : 0.f;
      float2 st; st.x = hv[0] * mk; st.y = hv[1] * mk;
      *(float2*)&Hout[((size_t)t * cB + b) * cH + 2 * tid] = st;
    }
    __syncthreads();
    xgCur = xgN;
  }
}

// ---------------------------------------------------------------------------
// Match-LSTM, fwd + bwd. 64 WGs = dir(2) x batch(32), 640 threads.
// 5-phase structure; Whh (19 uint4) and QW (7 uint4) pinned in registers;
// aq + wa in LDS; XA/pp prefetched one step ahead.
// ---------------------------------------------------------------------------
__global__ __launch_bounds__(640, 3)
void match_k(const f16* __restrict__ XAf, const f16* __restrict__ XAb,
             const f16* __restrict__ QWf, const f16* __restrict__ QWb,
             const float* __restrict__ aq, const float* __restrict__ pp,
             const float* __restrict__ mfWhh, const float* __restrict__ mbWhh,
             const float* __restrict__ mfb, const float* __restrict__ mbb,
             const float* __restrict__ Wr, const float* __restrict__ wa,
             const int* __restrict__ plens, float* __restrict__ Hr)
{
  constexpr int NPAD = 160;
  constexpr int AQS  = 81;
  int wg = blockIdx.x;
  int dir = wg >> 5;
  int b = wg & 31;
  const f16* XA = dir ? XAb : XAf;
  const f16* QW = dir ? QWb : QWf;
  const float* Whh = dir ? mbWhh : mfWhh;
  const float* bm  = dir ? mbb   : mfb;
  int len = plens[b];
  int tid = threadIdx.x;

  __shared__ u32 WrT2[76 * 150];        // [pair p][j], f16x2-packed Wr^T
  __shared__ u32 aq2[cLQ * AQS];        // [l][jp] f16x2 pairs of aq (zero-pad)
  __shared__ float gl[cG];
  __shared__ float sc[NPAD];            // pp_t + h@Wr^T (zero-padded)
  __shared__ float waS[NPAD];
  __shared__ float c[cH];
  __shared__ __align__(16) u32 h2s[80];
  __shared__ float loge[64];
  __shared__ __align__(16) u32 alpha2[28];

  // ---- one-time loads: weights into pinned registers ----
#define DECLW(i) uint4 w##i;
  REP19(DECLW)
#undef DECLW
  float bk = 0.f;
  {
    const float* wr = Whh + (size_t)(tid < cG ? tid : 0) * cH;
#define LOADW(i) w##i = ldw4(wr, i);
    REP18(LOADW)
#undef LOADW
    w18.x = pack2(wr[144], wr[145]);
    w18.y = pack2(wr[146], wr[147]);
    w18.z = pack2(wr[148], wr[149]);
    w18.w = 0;
    REP19(PIN4W)
    if (tid < cG) bk = bm[tid];
  }
#define DECLQ(i) uint4 q##i;
  REP7(DECLQ)
#undef DECLQ
  {
    const u16* QWu = (const u16*)QW;
    int row = (tid < cG) ? tid : 0;
    // pair p holds (alpha_{2p}, alpha_{2p+1}) weights: QW[l][b][row]
#define QP(p) ((u32)QWu[((size_t)(2*(p)) * cB + b) * cG + row] | \
               ((u32)QWu[((size_t)(2*(p)+1) * cB + b) * cG + row] << 16))
#define LOADQ(i) q##i.x = QP(4*(i)+0); q##i.y = QP(4*(i)+1); \
                 q##i.z = QP(4*(i)+2); q##i.w = QP(4*(i)+3);
    LOADQ(0) LOADQ(1) LOADQ(2) LOADQ(3) LOADQ(4) LOADQ(5)
    q6.x = QP(24); q6.y = 0; q6.z = 0; q6.w = 0;
#undef LOADQ
#undef QP
    REP7(PIN4Q)
  }
  for (int idx = tid; idx < cLQ * AQS; idx += 640){
    int l = idx / AQS, jp = idx % AQS;
    u32 v = 0;
    if (jp < 75){
      const float* ap = aq + ((size_t)l * cB + b) * cH;
      v = pack2(ap[2 * jp], ap[2 * jp + 1]);
    }
    aq2[idx] = v;
  }
  for (int i = tid; i < NPAD; i += 640) waS[i] = (i < cH) ? wa[i] : 0.f;
  for (int idx = tid; idx < 76 * 150; idx += 640){
    int p = idx / 150, k2 = idx % 150;
    WrT2[idx] = (p < 75) ? pack2(Wr[(size_t)k2 * cH + 2 * p],
                                 Wr[(size_t)k2 * cH + 2 * p + 1]) : 0u;
  }
  if (tid < cH) c[tid] = 0.f;
  if (tid < 80) h2s[tid] = 0;
  if (tid >= cH && tid < NPAD) sc[tid] = 0.f;
  __syncthreads();

  // prologue prefetch for step 0
  f16 xaCurH = (f16)0.f, xaNxtH = (f16)0.f;
  float ppCur = 0.f, ppNxt = 0.f;
  {
    int t0 = dir ? (cLP - 1) : 0;
    if (tid < cG) xaCurH = XA[((size_t)t0 * cB + b) * cG + tid];
    if (tid < cH) ppCur = pp[((size_t)t0 * cB + b) * cH + tid];
  }

  for (int s = 0; s < cLP; s++){
    int tt = dir ? (cLP - 1 - s) : s;
    float mk = (tt < len) ? 1.f : 0.f;

    // prefetch step s+1 (consumed next iteration)
    {
      int sn = (s + 1 < cLP) ? s + 1 : s;
      int tn = dir ? (cLP - 1 - sn) : sn;
      if (tid < cG) xaNxtH = XA[((size_t)tn * cB + b) * cG + tid];
      if (tid < cH) ppNxt = pp[((size_t)tn * cB + b) * cH + tid];
    }

    // A: sc = h@Wr^T + pp[tt]   (150 threads, conflict-free WrT2 reads)
    if (tid < cH){
      float sA = 0.f, sB = 0.f, sC = 0.f, sD = 0.f;
#define DOTA(i) { uint4 hq = *(const uint4*)&h2s[4*(i)]; \
      sA = fdot2_(hq.x, WrT2[(4*(i)+0)*150 + tid], sA); \
      sB = fdot2_(hq.y, WrT2[(4*(i)+1)*150 + tid], sB); \
      sC = fdot2_(hq.z, WrT2[(4*(i)+2)*150 + tid], sC); \
      sD = fdot2_(hq.w, WrT2[(4*(i)+3)*150 + tid], sD); }
      REP19(DOTA)
#undef DOTA
      sc[tid] = ((sA + sB) + (sC + sD)) + ppCur;
    }
    __syncthreads();

    // B: attention logits; 8 lanes/l, 20-wide even-aligned j-chunks.
    if (tid < 400){
      int l = tid >> 3, q = tid & 7;
      const u32* arow = &aq2[l * AQS + q * 10];
      float part = 0.f;
      #pragma unroll
      for (int p = 0; p < 10; p++){
        int j = q * 20 + 2 * p;
        float2 av = unp2(arow[p]);
        float x0 = av.x + sc[j];
        float x1 = av.y + sc[j + 1];
        float r0 = rcp_(1.f + exp2_(2.88539008f * x0));
        float r1 = rcp_(1.f + exp2_(2.88539008f * x1));
        part += waS[j] * r0 + waS[j + 1] * r1;
      }
      part += __shfl_xor(part, 1);
      part += __shfl_xor(part, 2);
      part += __shfl_xor(part, 4);
      if (q == 0) loge[l] = part;
    }
    __syncthreads();

    // C: softmax over 50 on wave 0, f16-packed alpha pairs
    if (tid < 64){
      float lg = (tid < cLQ) ? (-2.f * loge[tid]) : -1e30f;
      float mx = lg;
      #pragma unroll
      for (int off = 32; off; off >>= 1) mx = fmaxf(mx, __shfl_xor(mx, off));
      float e = (tid < cLQ) ? exp2_((lg - mx) * 1.44269504f) : 0.f;
      float sum = e;
      #pragma unroll
      for (int off = 32; off; off >>= 1) sum += __shfl_xor(sum, off);
      float al = e * rcp_(sum);
      float alhi = __shfl_down(al, 1);
      if (tid < cLQ && !(tid & 1)) alpha2[tid >> 1] = pack2(al, alhi);
      if (tid >= 25 && tid < 28) alpha2[tid] = 0;
    }
    __syncthreads();

    // D: gl = b + h@Whh^T + mk*(XA + alpha@QW)   (600 threads, reg weights)
    if (tid < cG){
      float aA = 0.f, aB = 0.f, aC = 0.f, aD = 0.f;
#define DOTW(i) { uint4 hq = *(const uint4*)&h2s[4*(i)]; \
      aA = fdot2_(hq.x, w##i.x, aA); aB = fdot2_(hq.y, w##i.y, aB); \
      aC = fdot2_(hq.z, w##i.z, aC); aD = fdot2_(hq.w, w##i.w, aD); }
      REP19(DOTW)
#undef DOTW
      float qA = 0.f, qB = 0.f;
#define DOTQ(i) { uint4 a4 = *(const uint4*)&alpha2[4*(i)]; \
      qA = fdot2_(a4.x, q##i.x, qA); qB = fdot2_(a4.y, q##i.y, qB); \
      qA = fdot2_(a4.z, q##i.z, qA); qB = fdot2_(a4.w, q##i.w, qB); }
      REP7(DOTQ)
#undef DOTQ
      float acc = ((aA + aB) + (aC + aD));
      gl[tid] = bk + acc + mk * ((float)xaCurH + (qA + qB));
    }
    __syncthreads();

    // E: LSTM cell; h2,c2 masked inside recurrence (ref semantics)
    if (tid < 75){
      float hv[2];
      #pragma unroll
      for (int z = 0; z < 2; z++){
        int u = 2 * tid + z;
        float ig = sigm(gl[u]);
        float fg = sigm(gl[cH + u]);
        float gg = tanh_(gl[2 * cH + u]);
        float og = sigm(gl[3 * cH + u]);
        float c2 = (fg * c[u] + ig * gg) * mk;
        float hh = og * tanh_(c2) * mk;
        c[u] = c2;
        hv[z] = hh;
      }
      h2s[tid] = pack2(hv[0], hv[1]);
      float2 st; st.x = hv[0]; st.y = hv[1];
      *(float2*)&Hr[((size_t)tt * cB + b) * (2 * cH) + dir * cH + 2 * tid] = st;
    }
    __syncthreads();

    xaCurH = xaNxtH;
    ppCur  = ppNxt;
  }
}

// ---------------------------------------------------------------------------
// Answer pointer: 32 WGs (one per batch), 2 sequential iterations.
// ---------------------------------------------------------------------------
__global__ __launch_bounds__(640)
void ptr_k(const float* __restrict__ am, const float* __restrict__ Hr,
           const float* __restrict__ Wa, const float* __restrict__ baa,
           const float* __restrict__ wb,
           const float* __restrict__ apWih, const float* __restrict__ apWhh,
             const float* __restrict__ apb, float* __restrict__ out)
{
  int b = blockIdx.x, tid = threadIdx.x;
  __shared__ float ha[cH], ca[cH], haWa[160], wbs[160];
  __shared__ float beta[cLP], wHr[2 * cH], gl[cG], red[20];
  if (tid < cH){ ha[tid] = 0.f; ca[tid] = 0.f; }
  if (tid < 160) wbs[tid] = (tid < cH) ? wb[tid] : 0.f;
  __syncthreads();

  for (int it = 0; it < 2; ++it){
    if (tid < cH){
      float acc = baa[tid];
      const float* wr = Wa + (size_t)tid * cH;
      for (int i = 0; i < cH; i++) acc += ha[i] * wr[i];
      haWa[tid] = acc;
    } else if (tid < 160) haWa[tid] = 0.f;
    __syncthreads();

    {
      int tt = tid >> 4;
      int jq = tid & 15;
      for (int t0 = 0; t0 < cLP; t0 += 40){
        int t = t0 + tt;
        float part = 0.f;
        const float* amr = am + ((size_t)t * cB + b) * cH;
        #pragma unroll
        for (int i = 0; i < 10; i++){
          int j = jq * 10 + i;
          if (j < cH){
            float F = tanh_(amr[j] + haWa[j]);
            part += wbs[j] * F;
          }
        }
        part += __shfl_xor(part, 1);
        part += __shfl_xor(part, 2);
        part += __shfl_xor(part, 4);
        part += __shfl_xor(part, 8);
        if (jq == 0) beta[t] = part;
      }
    }
    __syncthreads();

    float x = (tid < cLP) ? beta[tid] : -1e30f;
    float mx = x;
    #pragma unroll
    for (int off = 32; off; off >>= 1) mx = fmaxf(mx, __shfl_xor(mx, off));
    if ((tid & 63) == 0) red[tid >> 6] = mx;
    __syncthreads();
    if (tid == 0){
      float m2 = red[0];
      for (int w = 1; w < 10; w++) m2 = fmaxf(m2, red[w]);
      red[16] = m2;
    }
    __syncthreads();
    mx = red[16];
    float e = (tid < cLP) ? exp2_((x - mx) * 1.44269504f) : 0.f;
    float sm = e;
    #pragma unroll
    for (int off = 32; off; off >>= 1) sm += __shfl_xor(sm, off);
    if ((tid & 63) == 0) red[tid >> 6] = sm;
    __syncthreads();
    if (tid == 0){
      float s2 = 0.f;
      for (int w = 0; w < 10; w++) s2 += red[w];
      red[17] = s2;
    }
    __syncthreads();
    float bsum = red[17];
    if (tid < cLP){
      float bt = e * rcp_(bsum);
      beta[tid] = bt;
      out[(size_t)it * cLP * cB + (size_t)tid * cB + b] = bt;
    }
    __syncthreads();

    if (tid < 2 * cH){
      float acc = 0.f;
      for (int t = 0; t < cLP; t++)
        acc += beta[t] * Hr[((size_t)t * cB + b) * (2 * cH) + tid];
      wHr[tid] = acc;
    }
    __syncthreads();

    if (tid < cG){
      float acc = apb[tid];
      const float* r1 = apWih + (size_t)tid * (2 * cH);
      for (int i = 0; i < 2 * cH; i++) acc += wHr[i] * r1[i];
      const float* r2 = apWhh + (size_t)tid * cH;
      for (int i = 0; i < cH; i++) acc += ha[i] * r2[i];
      gl[tid] = acc;
    }
    __syncthreads();
    if (tid < cH){
      float ig = sigm(gl[tid]);
      float fg = sigm(gl[cH + tid]);
      float gg = tanh_(gl[2 * cH + tid]);
      float og = sigm(gl[3 * cH + tid]);
      float c2 = fg * ca[tid] + ig * gg;
      ca[tid] = c2;
      ha[tid] = og * tanh_(c2);
    }
    __syncthreads();
  }
}

// ---------------------------------------------------------------------------
extern "C" void kernel_launch(void* const* d_in, const int* in_sizes, int n_in,
                              void* d_out, int out_size, void* d_ws, size_t ws_size,
                              hipStream_t stream)
{
  (void)in_sizes; (void)n_in; (void)out_size; (void)ws_size;
  const int*   p_ids = (const int*)d_in[0];
  const int*   q_ids = (const int*)d_in[1];
  const int*   plens = (const int*)d_in[2];
  const int*   qlens = (const int*)d_in[3];
  const float* emb   = (const float*)d_in[4];
  const float* pWih  = (const float*)d_in[5];
  const float* pWhh  = (const float*)d_in[6];
  const float* pb    = (const float*)d_in[7];
  const float* Wq    = (const float*)d_in[8];
  const float* Wp    = (const float*)d_in[9];
  const float* bp    = (const float*)d_in[10];
  const float* Wr    = (const float*)d_in[11];
  const float* wa    = (const float*)d_in[12];
  const float* mfWih = (const float*)d_in[14];
  const float* mfWhh = (const float*)d_in[15];
  const float* mfb   = (const float*)d_in[16];
  const float* mbWih = (const float*)d_in[17];
  const float* mbWhh = (const float*)d_in[18];
  const float* mbb   = (const float*)d_in[19];
  const float* Vm    = (const float*)d_in[20];
  const float* Waa   = (const float*)d_in[21];
  const float* baa   = (const float*)d_in[22];
  const float* wb    = (const float*)d_in[23];
  const float* apWih = (const float*)d_in[25];
  const float* apWhh = (const float*)d_in[26];
  const float* apb   = (const float*)d_in[27];
  float* out = (float*)d_out;

  // workspace layout (floats); total 22,560,000 f = 90.24 MB
  float* ws  = (float*)d_ws;
  float* XGp = ws;                       // [400*32][600] f32 (later aliased XAf)
  float* XGq = ws + 7680000;             // [50*32][600]  f32 (later aliased QW)
  f16*   XAb = (f16*)(ws + 8640000);     // [400*32][600] f16
  float* Hp  = ws + 12480000;            // [400*32][150]
  float* Hq  = ws + 14400000;            // [50*32][150]
  float* aqb = ws + 14640000;            // [50*32][150]
  float* ppb = ws + 14880000;            // [400*32][150]
  float* Hr  = ws + 16800000;            // [400*32][300]
  float* am  = ws + 20640000;            // [400*32][150]
  f16*   XAf = (f16*)XGp;                // alias: XGp dead after enc_k
  f16*   QWf = (f16*)XGq;                // alias: XGq dead after enc_k
  f16*   QWb = QWf + (size_t)1600 * 600;

  dim3 blk(256);
  gemm_k<<<dim3(10,200), blk, 0, stream>>>(nullptr, p_ids, emb, pWih, 300, pb,
                                           XGp, nullptr, 12800, 600, 300);
  gemm_k<<<dim3(10, 25), blk, 0, stream>>>(nullptr, q_ids, emb, pWih, 300, pb,
                                           XGq, nullptr, 1600, 600, 300);
  enc_k<<<64, 640, 0, stream>>>(XGp, XGq, pWhh, plens, qlens, Hp, Hq);
  gemm_k<<<dim3(3,200), blk, 0, stream>>>(Hp, nullptr, nullptr, Wp, 150, bp,
                                          ppb, nullptr, 12800, 150, 150);
  gemm_k<<<dim3(3, 25), blk, 0, stream>>>(Hq, nullptr, nullptr, Wq, 150, nullptr,
                                          aqb, nullptr, 1600, 150, 150);
  gemm_k<<<dim3(10,200), blk, 0, stream>>>(Hp, nullptr, nullptr, mfWih, 300, nullptr,
                                           nullptr, XAf, 12800, 600, 150);
  gemm_k<<<dim3(10,200), blk, 0, stream>>>(Hp, nullptr, nullptr, mbWih, 300, nullptr,
                                           nullptr, XAb, 12800, 600, 150);
  gemm_k<<<dim3(10, 25), blk, 0, stream>>>(Hq, nullptr, nullptr, mfWih + 150, 300, nullptr,
                                           nullptr, QWf, 1600, 600, 150);
  gemm_k<<<dim3(10, 25), blk, 0, stream>>>(Hq, nullptr, nullptr, mbWih + 150, 300, nullptr,
                                           nullptr, QWb, 1600, 600, 150);
  match_k<<<64, 640, 0, stream>>>(XAf, XAb, QWf, QWb, aqb, ppb, mfWhh, mbWhh,
                                  mfb, mbb, Wr, wa, plens, Hr);
  gemm_k<<<dim3(3,200), blk, 0, stream>>>(Hr, nullptr, nullptr, Vm, 300, nullptr,
                                          am, nullptr, 12800, 150, 300);
  ptr_k<<<32, 640, 0, stream>>>(am, Hr, Waa, baa, wb, apWih, apWhh, apb, out);
}

// Round 7
// 3050.248 us; speedup vs baseline: 1.0001x; 1.0001x over previous
//
#include <hip/hip_runtime.h>

// MatchLSTM forward pipeline for MI355X.
// R7 = R6 with __launch_bounds__(640, 2) on the recurrent kernels.
// (640,3) required 2 WGs/CU (10-wave WG -> 3,3,2,2 per EU; min-3 needs a 2nd
// WG) capping VGPRs at ~102 and forcing the weight arrays to spill. (640,2)
// is satisfied by 1 WG/CU -> VGPR cap 256 -> pinned weights fit in registers.

typedef _Float16 f16;
typedef f16 f16x2 __attribute__((ext_vector_type(2)));
typedef unsigned int u32;
typedef unsigned short u16;

constexpr int cLP = 400, cLQ = 50, cB = 32, cH = 150, cG = 600;

__device__ __forceinline__ float exp2_(float x){
#if __has_builtin(__builtin_amdgcn_exp2f)
  return __builtin_amdgcn_exp2f(x);
#else
  return exp2f(x);
#endif
}
__device__ __forceinline__ float rcp_(float x){
#if __has_builtin(__builtin_amdgcn_rcpf)
  return __builtin_amdgcn_rcpf(x);
#else
  return 1.0f / x;
#endif
}
__device__ __forceinline__ float sigm(float x){ return rcp_(1.f + exp2_(-1.44269504f * x)); }
__device__ __forceinline__ float tanh_(float x){ return 1.f - 2.f * rcp_(1.f + exp2_(2.88539008f * x)); }

union U2 { u32 u; f16x2 h; };

__device__ __forceinline__ float fdot2_(u32 a, u32 b, float c){
  U2 ua, ub; ua.u = a; ub.u = b;
#if __has_builtin(__builtin_amdgcn_fdot2)
  return __builtin_amdgcn_fdot2(ua.h, ub.h, c, false);
#else
  return c + (float)ua.h[0] * (float)ub.h[0] + (float)ua.h[1] * (float)ub.h[1];
#endif
}
__device__ __forceinline__ u32 pack2(float x, float y){
  U2 p; p.h[0] = (f16)x; p.h[1] = (f16)y; return p.u;
}
__device__ __forceinline__ float2 unp2(u32 v){
  U2 p; p.u = v; return make_float2((float)p.h[0], (float)p.h[1]);
}

// load 4 f16x2 pairs (8 floats) from a weight row at pair offset 4*i
__device__ __forceinline__ uint4 ldw4(const float* __restrict__ wr, int i){
  uint4 r;
  r.x = pack2(wr[8*i+0], wr[8*i+1]);
  r.y = pack2(wr[8*i+2], wr[8*i+3]);
  r.z = pack2(wr[8*i+4], wr[8*i+5]);
  r.w = pack2(wr[8*i+6], wr[8*i+7]);
  return r;
}

// opaque barrier: values become asm outputs -> cannot be rematerialized
#define PIN4(v) asm volatile("" : "+v"(v.x), "+v"(v.y), "+v"(v.z), "+v"(v.w));
#define PIN4W(i) PIN4(w##i)
#define PIN4Q(i) PIN4(q##i)

#define REP18(M) M(0) M(1) M(2) M(3) M(4) M(5) M(6) M(7) M(8) M(9) \
                 M(10) M(11) M(12) M(13) M(14) M(15) M(16) M(17)
#define REP19(M) REP18(M) M(18)
#define REP7(M) M(0) M(1) M(2) M(3) M(4) M(5) M(6)

// ---------------------------------------------------------------------------
// Generic f32 GEMM: C[M][N] = A[M][K] @ W[N][K]^T (+bias). Optional embedding
// gather for A rows. Optional f16 output. Tile 64x64, 4x4/thread, 256 thr.
// ---------------------------------------------------------------------------
__global__ __launch_bounds__(256)
void gemm_k(const float* __restrict__ A, const int* __restrict__ ids,
            const float* __restrict__ emb,
            const float* __restrict__ W, int ldw, const float* __restrict__ bias,
            float* __restrict__ Cf, f16* __restrict__ Ch,
            int M, int N, int K)
{
  __shared__ __align__(16) float As[16][68];
  __shared__ __align__(16) float Wt[16][68];
  __shared__ int sids[64];
  int tid = threadIdx.x;
  int n0 = blockIdx.x * 64;
  int m0 = blockIdx.y * 64;
  int tx = tid & 15, ty = tid >> 4;
  if (ids){ if (tid < 64) sids[tid] = ids[m0 + tid]; }
  __syncthreads();

  float acc[4][4] = {};
  int sm = tid >> 2;
  int kq = (tid & 3) << 2;
  const float* arow = ids ? (emb + (size_t)sids[sm] * K)
                          : (A   + (size_t)(m0 + sm) * K);
  const float* wrow = W + (size_t)(n0 + sm) * ldw;
  bool nok = (n0 + sm) < N;

  for (int k0 = 0; k0 < K; k0 += 16){
    #pragma unroll
    for (int p = 0; p < 4; p++){
      int kk = kq + p, k = k0 + kk;
      As[kk][sm] = (k < K) ? arow[k] : 0.f;
      Wt[kk][sm] = (nok && k < K) ? wrow[k] : 0.f;
    }
    __syncthreads();
    #pragma unroll
    for (int kk = 0; kk < 16; kk++){
      float4 av = *(const float4*)&As[kk][ty << 2];
      float4 wv = *(const float4*)&Wt[kk][tx << 2];
      float a[4] = {av.x, av.y, av.z, av.w};
      float w[4] = {wv.x, wv.y, wv.z, wv.w};
      #pragma unroll
      for (int i = 0; i < 4; i++)
        #pragma unroll
        for (int j = 0; j < 4; j++)
          acc[i][j] += a[i] * w[j];
    }
    __syncthreads();
  }
  float bj[4];
  #pragma unroll
  for (int j = 0; j < 4; j++){
    int n = n0 + (tx << 2) + j;
    bj[j] = (bias && n < N) ? bias[n] : 0.f;
  }
  #pragma unroll
  for (int i = 0; i < 4; i++){
    int m = m0 + (ty << 2) + i;
    #pragma unroll
    for (int j = 0; j < 4; j++){
      int n = n0 + (tx << 2) + j;
      if (n < N){
        size_t ci = (size_t)m * N + n;
        float v = acc[i][j] + bj[j];
        if (Ch) Ch[ci] = (f16)v; else Cf[ci] = v;
      }
    }
  }
}

// ---------------------------------------------------------------------------
// Encoder LSTM. 64 WGs: wg<32 -> passage b, else question b. 640 threads.
// Whh rows in pinned uint4 VGPRs. XG prefetched 1 step ahead.
// ---------------------------------------------------------------------------
__global__ __launch_bounds__(640, 2)
void enc_k(const float* __restrict__ XGp, const float* __restrict__ XGq,
           const float* __restrict__ Whh,
           const int* __restrict__ plens, const int* __restrict__ qlens,
           float* __restrict__ Hp, float* __restrict__ Hq)
{
  int wg = blockIdx.x;
  bool isq = wg >= cB;
  int b = wg & (cB - 1);
  const float* XG = isq ? XGq : XGp;
  float* Hout = isq ? Hq : Hp;
  int T   = isq ? cLQ : cLP;
  int len = (isq ? qlens : plens)[b];
  int tid = threadIdx.x;

  __shared__ float c[cH], gl[cG];
  __shared__ __align__(16) u32 h2s[80];

#define DECLW(i) uint4 w##i;
  REP19(DECLW)
#undef DECLW
  {
    const float* wr = Whh + (size_t)(tid < cG ? tid : 0) * cH;
#define LOADW(i) w##i = ldw4(wr, i);
    REP18(LOADW)
#undef LOADW
    w18.x = pack2(wr[144], wr[145]);
    w18.y = pack2(wr[146], wr[147]);
    w18.z = pack2(wr[148], wr[149]);
    w18.w = 0;
    REP19(PIN4W)
  }
  if (tid < cH) c[tid] = 0.f;
  if (tid < 80) h2s[tid] = 0;
  __syncthreads();

  float xgCur = 0.f;
  if (tid < cG) xgCur = XG[(size_t)b * cG + tid];

  for (int t = 0; t < T; t++){
    int tn = (t + 1 < T) ? t + 1 : t;
    float xgN = 0.f;
    if (tid < cG) xgN = XG[((size_t)tn * cB + b) * cG + tid];

    if (tid < cG){
      float aA = 0.f, aB = 0.f, aC = 0.f, aD = 0.f;
#define DOTW(i) { uint4 hq = *(const uint4*)&h2s[4*(i)]; \
      aA = fdot2_(hq.x, w##i.x, aA); aB = fdot2_(hq.y, w##i.y, aB); \
      aC = fdot2_(hq.z, w##i.z, aC); aD = fdot2_(hq.w, w##i.w, aD); }
      REP19(DOTW)
#undef DOTW
      gl[tid] = xgCur + ((aA + aB) + (aC + aD));
    }
    __syncthreads();
    if (tid < 75){
      float hv[2];
      #pragma unroll
      for (int z = 0; z < 2; z++){
        int u = 2 * tid + z;
        float ig = sigm(gl[u]);
        float fg = sigm(gl[cH + u]);
        float gg = tanh_(gl[2 * cH + u]);
        float og = sigm(gl[3 * cH + u]);
        float c2 = fg * c[u] + ig * gg;
        float hh = og * tanh_(c2);
        c[u] = c2;
        hv[z] = hh;
      }
      h2s[tid] = pack2(hv[0], hv[1]);      // unmasked h carries the recurrence
      float mk = (t < len) ? 1.f : 0.f;
      float2 st; st.x = hv[0] * mk; st.y = hv[1] * mk;
      *(float2*)&Hout[((size_t)t * cB + b) * cH + 2 * tid] = st;
    }
    __syncthreads();
    xgCur = xgN;
  }
}

// ---------------------------------------------------------------------------
// Match-LSTM, fwd + bwd. 64 WGs = dir(2) x batch(32), 640 threads.
// 5-phase structure; Whh (19 uint4) and QW (7 uint4) pinned in registers;
// aq + wa in LDS; XA/pp prefetched one step ahead.
// ---------------------------------------------------------------------------
__global__ __launch_bounds__(640, 2)
void match_k(const f16* __restrict__ XAf, const f16* __restrict__ XAb,
             const f16* __restrict__ QWf, const f16* __restrict__ QWb,
             const float* __restrict__ aq, const float* __restrict__ pp,
             const float* __restrict__ mfWhh, const float* __restrict__ mbWhh,
             const float* __restrict__ mfb, const float* __restrict__ mbb,
             const float* __restrict__ Wr, const float* __restrict__ wa,
             const int* __restrict__ plens, float* __restrict__ Hr)
{
  constexpr int NPAD = 160;
  constexpr int AQS  = 81;
  int wg = blockIdx.x;
  int dir = wg >> 5;
  int b = wg & 31;
  const f16* XA = dir ? XAb : XAf;
  const f16* QW = dir ? QWb : QWf;
  const float* Whh = dir ? mbWhh : mfWhh;
  const float* bm  = dir ? mbb   : mfb;
  int len = plens[b];
  int tid = threadIdx.x;

  __shared__ u32 WrT2[76 * 150];        // [pair p][j], f16x2-packed Wr^T
  __shared__ u32 aq2[cLQ * AQS];        // [l][jp] f16x2 pairs of aq (zero-pad)
  __shared__ float gl[cG];
  __shared__ float sc[NPAD];            // pp_t + h@Wr^T (zero-padded)
  __shared__ float waS[NPAD];
  __shared__ float c[cH];
  __shared__ __align__(16) u32 h2s[80];
  __shared__ float loge[64];
  __shared__ __align__(16) u32 alpha2[28];

  // ---- one-time loads: weights into pinned registers ----
#define DECLW(i) uint4 w##i;
  REP19(DECLW)
#undef DECLW
  float bk = 0.f;
  {
    const float* wr = Whh + (size_t)(tid < cG ? tid : 0) * cH;
#define LOADW(i) w##i = ldw4(wr, i);
    REP18(LOADW)
#undef LOADW
    w18.x = pack2(wr[144], wr[145]);
    w18.y = pack2(wr[146], wr[147]);
    w18.z = pack2(wr[148], wr[149]);
    w18.w = 0;
    REP19(PIN4W)
    if (tid < cG) bk = bm[tid];
  }
#define DECLQ(i) uint4 q##i;
  REP7(DECLQ)
#undef DECLQ
  {
    const u16* QWu = (const u16*)QW;
    int row = (tid < cG) ? tid : 0;
    // pair p holds (alpha_{2p}, alpha_{2p+1}) weights: QW[l][b][row]
#define QP(p) ((u32)QWu[((size_t)(2*(p)) * cB + b) * cG + row] | \
               ((u32)QWu[((size_t)(2*(p)+1) * cB + b) * cG + row] << 16))
#define LOADQ(i) q##i.x = QP(4*(i)+0); q##i.y = QP(4*(i)+1); \
                 q##i.z = QP(4*(i)+2); q##i.w = QP(4*(i)+3);
    LOADQ(0) LOADQ(1) LOADQ(2) LOADQ(3) LOADQ(4) LOADQ(5)
    q6.x = QP(24); q6.y = 0; q6.z = 0; q6.w = 0;
#undef LOADQ
#undef QP
    REP7(PIN4Q)
  }
  for (int idx = tid; idx < cLQ * AQS; idx += 640){
    int l = idx / AQS, jp = idx % AQS;
    u32 v = 0;
    if (jp < 75){
      const float* ap = aq + ((size_t)l * cB + b) * cH;
      v = pack2(ap[2 * jp], ap[2 * jp + 1]);
    }
    aq2[idx] = v;
  }
  for (int i = tid; i < NPAD; i += 640) waS[i] = (i < cH) ? wa[i] : 0.f;
  for (int idx = tid; idx < 76 * 150; idx += 640){
    int p = idx / 150, k2 = idx % 150;
    WrT2[idx] = (p < 75) ? pack2(Wr[(size_t)k2 * cH + 2 * p],
                                 Wr[(size_t)k2 * cH + 2 * p + 1]) : 0u;
  }
  if (tid < cH) c[tid] = 0.f;
  if (tid < 80) h2s[tid] = 0;
  if (tid >= cH && tid < NPAD) sc[tid] = 0.f;
  __syncthreads();

  // prologue prefetch for step 0
  f16 xaCurH = (f16)0.f, xaNxtH = (f16)0.f;
  float ppCur = 0.f, ppNxt = 0.f;
  {
    int t0 = dir ? (cLP - 1) : 0;
    if (tid < cG) xaCurH = XA[((size_t)t0 * cB + b) * cG + tid];
    if (tid < cH) ppCur = pp[((size_t)t0 * cB + b) * cH + tid];
  }

  for (int s = 0; s < cLP; s++){
    int tt = dir ? (cLP - 1 - s) : s;
    float mk = (tt < len) ? 1.f : 0.f;

    // prefetch step s+1 (consumed next iteration)
    {
      int sn = (s + 1 < cLP) ? s + 1 : s;
      int tn = dir ? (cLP - 1 - sn) : sn;
      if (tid < cG) xaNxtH = XA[((size_t)tn * cB + b) * cG + tid];
      if (tid < cH) ppNxt = pp[((size_t)tn * cB + b) * cH + tid];
    }

    // A: sc = h@Wr^T + pp[tt]   (150 threads, conflict-free WrT2 reads)
    if (tid < cH){
      float sA = 0.f, sB = 0.f, sC = 0.f, sD = 0.f;
#define DOTA(i) { uint4 hq = *(const uint4*)&h2s[4*(i)]; \
      sA = fdot2_(hq.x, WrT2[(4*(i)+0)*150 + tid], sA); \
      sB = fdot2_(hq.y, WrT2[(4*(i)+1)*150 + tid], sB); \
      sC = fdot2_(hq.z, WrT2[(4*(i)+2)*150 + tid], sC); \
      sD = fdot2_(hq.w, WrT2[(4*(i)+3)*150 + tid], sD); }
      REP19(DOTA)
#undef DOTA
      sc[tid] = ((sA + sB) + (sC + sD)) + ppCur;
    }
    __syncthreads();

    // B: attention logits; 8 lanes/l, 20-wide even-aligned j-chunks.
    if (tid < 400){
      int l = tid >> 3, q = tid & 7;
      const u32* arow = &aq2[l * AQS + q * 10];
      float part = 0.f;
      #pragma unroll
      for (int p = 0; p < 10; p++){
        int j = q * 20 + 2 * p;
        float2 av = unp2(arow[p]);
        float x0 = av.x + sc[j];
        float x1 = av.y + sc[j + 1];
        float r0 = rcp_(1.f + exp2_(2.88539008f * x0));
        float r1 = rcp_(1.f + exp2_(2.88539008f * x1));
        part += waS[j] * r0 + waS[j + 1] * r1;
      }
      part += __shfl_xor(part, 1);
      part += __shfl_xor(part, 2);
      part += __shfl_xor(part, 4);
      if (q == 0) loge[l] = part;
    }
    __syncthreads();

    // C: softmax over 50 on wave 0, f16-packed alpha pairs
    if (tid < 64){
      float lg = (tid < cLQ) ? (-2.f * loge[tid]) : -1e30f;
      float mx = lg;
      #pragma unroll
      for (int off = 32; off; off >>= 1) mx = fmaxf(mx, __shfl_xor(mx, off));
      float e = (tid < cLQ) ? exp2_((lg - mx) * 1.44269504f) : 0.f;
      float sum = e;
      #pragma unroll
      for (int off = 32; off; off >>= 1) sum += __shfl_xor(sum, off);
      float al = e * rcp_(sum);
      float alhi = __shfl_down(al, 1);
      if (tid < cLQ && !(tid & 1)) alpha2[tid >> 1] = pack2(al, alhi);
      if (tid >= 25 && tid < 28) alpha2[tid] = 0;
    }
    __syncthreads();

    // D: gl = b + h@Whh^T + mk*(XA + alpha@QW)   (600 threads, reg weights)
    if (tid < cG){
      float aA = 0.f, aB = 0.f, aC = 0.f, aD = 0.f;
#define DOTW(i) { uint4 hq = *(const uint4*)&h2s[4*(i)]; \
      aA = fdot2_(hq.x, w##i.x, aA); aB = fdot2_(hq.y, w##i.y, aB); \
      aC = fdot2_(hq.z, w##i.z, aC); aD = fdot2_(hq.w, w##i.w, aD); }
      REP19(DOTW)
#undef DOTW
      float qA = 0.f, qB = 0.f;
#define DOTQ(i) { uint4 a4 = *(const uint4*)&alpha2[4*(i)]; \
      qA = fdot2_(a4.x, q##i.x, qA); qB = fdot2_(a4.y, q##i.y, qB); \
      qA = fdot2_(a4.z, q##i.z, qA); qB = fdot2_(a4.w, q##i.w, qB); }
      REP7(DOTQ)
#undef DOTQ
      float acc = ((aA + aB) + (aC + aD));
      gl[tid] = bk + acc + mk * ((float)xaCurH + (qA + qB));
    }
    __syncthreads();

    // E: LSTM cell; h2,c2 masked inside recurrence (ref semantics)
    if (tid < 75){
      float hv[2];
      #pragma unroll
      for (int z = 0; z < 2; z++){
        int u = 2 * tid + z;
        float ig = sigm(gl[u]);
        float fg = sigm(gl[cH + u]);
        float gg = tanh_(gl[2 * cH + u]);
        float og = sigm(gl[3 * cH + u]);
        float c2 = (fg * c[u] + ig * gg) * mk;
        float hh = og * tanh_(c2) * mk;
        c[u] = c2;
        hv[z] = hh;
      }
      h2s[tid] = pack2(hv[0], hv[1]);
      float2 st; st.x = hv[0]; st.y = hv[1];
      *(float2*)&Hr[((size_t)tt * cB + b) * (2 * cH) + dir * cH + 2 * tid] = st;
    }
    __syncthreads();

    xaCurH = xaNxtH;
    ppCur  = ppNxt;
  }
}

// ---------------------------------------------------------------------------
// Answer pointer: 32 WGs (one per batch), 2 sequential iterations.
// ---------------------------------------------------------------------------
__global__ __launch_bounds__(640)
void ptr_k(const float* __restrict__ am, const float* __restrict__ Hr,
           const float* __restrict__ Wa, const float* __restrict__ baa,
           const float* __restrict__ wb,
           const float* __restrict__ apWih, const float* __restrict__ apWhh,
             const float* __restrict__ apb, float* __restrict__ out)
{
  int b = blockIdx.x, tid = threadIdx.x;
  __shared__ float ha[cH], ca[cH], haWa[160], wbs[160];
  __shared__ float beta[cLP], wHr[2 * cH], gl[cG], red[20];
  if (tid < cH){ ha[tid] = 0.f; ca[tid] = 0.f; }
  if (tid < 160) wbs[tid] = (tid < cH) ? wb[tid] : 0.f;
  __syncthreads();

  for (int it = 0; it < 2; ++it){
    if (tid < cH){
      float acc = baa[tid];
      const float* wr = Wa + (size_t)tid * cH;
      for (int i = 0; i < cH; i++) acc += ha[i] * wr[i];
      haWa[tid] = acc;
    } else if (tid < 160) haWa[tid] = 0.f;
    __syncthreads();

    {
      int tt = tid >> 4;
      int jq = tid & 15;
      for (int t0 = 0; t0 < cLP; t0 += 40){
        int t = t0 + tt;
        float part = 0.f;
        const float* amr = am + ((size_t)t * cB + b) * cH;
        #pragma unroll
        for (int i = 0; i < 10; i++){
          int j = jq * 10 + i;
          if (j < cH){
            float F = tanh_(amr[j] + haWa[j]);
            part += wbs[j] * F;
          }
        }
        part += __shfl_xor(part, 1);
        part += __shfl_xor(part, 2);
        part += __shfl_xor(part, 4);
        part += __shfl_xor(part, 8);
        if (jq == 0) beta[t] = part;
      }
    }
    __syncthreads();

    float x = (tid < cLP) ? beta[tid] : -1e30f;
    float mx = x;
    #pragma unroll
    for (int off = 32; off; off >>= 1) mx = fmaxf(mx, __shfl_xor(mx, off));
    if ((tid & 63) == 0) red[tid >> 6] = mx;
    __syncthreads();
    if (tid == 0){
      float m2 = red[0];
      for (int w = 1; w < 10; w++) m2 = fmaxf(m2, red[w]);
      red[16] = m2;
    }
    __syncthreads();
    mx = red[16];
    float e = (tid < cLP) ? exp2_((x - mx) * 1.44269504f) : 0.f;
    float sm = e;
    #pragma unroll
    for (int off = 32; off; off >>= 1) sm += __shfl_xor(sm, off);
    if ((tid & 63) == 0) red[tid >> 6] = sm;
    __syncthreads();
    if (tid == 0){
      float s2 = 0.f;
      for (int w = 0; w < 10; w++) s2 += red[w];
      red[17] = s2;
    }
    __syncthreads();
    float bsum = red[17];
    if (tid < cLP){
      float bt = e * rcp_(bsum);
      beta[tid] = bt;
      out[(size_t)it * cLP * cB + (size_t)tid * cB + b] = bt;
    }
    __syncthreads();

    if (tid < 2 * cH){
      float acc = 0.f;
      for (int t = 0; t < cLP; t++)
        acc += beta[t] * Hr[((size_t)t * cB + b) * (2 * cH) + tid];
      wHr[tid] = acc;
    }
    __syncthreads();

    if (tid < cG){
      float acc = apb[tid];
      const float* r1 = apWih + (size_t)tid * (2 * cH);
      for (int i = 0; i < 2 * cH; i++) acc += wHr[i] * r1[i];
      const float* r2 = apWhh + (size_t)tid * cH;
      for (int i = 0; i < cH; i++) acc += ha[i] * r2[i];
      gl[tid] = acc;
    }
    __syncthreads();
    if (tid < cH){
      float ig = sigm(gl[tid]);
      float fg = sigm(gl[cH + tid]);
      float gg = tanh_(gl[2 * cH + tid]);
      float og = sigm(gl[3 * cH + tid]);
      float c2 = fg * ca[tid] + ig * gg;
      ca[tid] = c2;
      ha[tid] = og * tanh_(c2);
    }
    __syncthreads();
  }
}

// ---------------------------------------------------------------------------
extern "C" void kernel_launch(void* const* d_in, const int* in_sizes, int n_in,
                              void* d_out, int out_size, void* d_ws, size_t ws_size,
                              hipStream_t stream)
{
  (void)in_sizes; (void)n_in; (void)out_size; (void)ws_size;
  const int*   p_ids = (const int*)d_in[0];
  const int*   q_ids = (const int*)d_in[1];
  const int*   plens = (const int*)d_in[2];
  const int*   qlens = (const int*)d_in[3];
  const float* emb   = (const float*)d_in[4];
  const float* pWih  = (const float*)d_in[5];
  const float* pWhh  = (const float*)d_in[6];
  const float* pb    = (const float*)d_in[7];
  const float* Wq    = (const float*)d_in[8];
  const float* Wp    = (const float*)d_in[9];
  const float* bp    = (const float*)d_in[10];
  const float* Wr    = (const float*)d_in[11];
  const float* wa    = (const float*)d_in[12];
  const float* mfWih = (const float*)d_in[14];
  const float* mfWhh = (const float*)d_in[15];
  const float* mfb   = (const float*)d_in[16];
  const float* mbWih = (const float*)d_in[17];
  const float* mbWhh = (const float*)d_in[18];
  const float* mbb   = (const float*)d_in[19];
  const float* Vm    = (const float*)d_in[20];
  const float* Waa   = (const float*)d_in[21];
  const float* baa   = (const float*)d_in[22];
  const float* wb    = (const float*)d_in[23];
  const float* apWih = (const float*)d_in[25];
  const float* apWhh = (const float*)d_in[26];
  const float* apb   = (const float*)d_in[27];
  float* out = (float*)d_out;

  // workspace layout (floats); total 22,560,000 f = 90.24 MB
  float* ws  = (float*)d_ws;
  float* XGp = ws;                       // [400*32][600] f32 (later aliased XAf)
  float* XGq = ws + 7680000;             // [50*32][600]  f32 (later aliased QW)
  f16*   XAb = (f16*)(ws + 8640000);     // [400*32][600] f16
  float* Hp  = ws + 12480000;            // [400*32][150]
  float* Hq  = ws + 14400000;            // [50*32][150]
  float* aqb = ws + 14640000;            // [50*32][150]
  float* ppb = ws + 14880000;            // [400*32][150]
  float* Hr  = ws + 16800000;            // [400*32][300]
  float* am  = ws + 20640000;            // [400*32][150]
  f16*   XAf = (f16*)XGp;                // alias: XGp dead after enc_k
  f16*   QWf = (f16*)XGq;                // alias: XGq dead after enc_k
  f16*   QWb = QWf + (size_t)1600 * 600;

  dim3 blk(256);
  gemm_k<<<dim3(10,200), blk, 0, stream>>>(nullptr, p_ids, emb, pWih, 300, pb,
                                           XGp, nullptr, 12800, 600, 300);
  gemm_k<<<dim3(10, 25), blk, 0, stream>>>(nullptr, q_ids, emb, pWih, 300, pb,
                                           XGq, nullptr, 1600, 600, 300);
  enc_k<<<64, 640, 0, stream>>>(XGp, XGq, pWhh, plens, qlens, Hp, Hq);
  gemm_k<<<dim3(3,200), blk, 0, stream>>>(Hp, nullptr, nullptr, Wp, 150, bp,
                                          ppb, nullptr, 12800, 150, 150);
  gemm_k<<<dim3(3, 25), blk, 0, stream>>>(Hq, nullptr, nullptr, Wq, 150, nullptr,
                                          aqb, nullptr, 1600, 150, 150);
  gemm_k<<<dim3(10,200), blk, 0, stream>>>(Hp, nullptr, nullptr, mfWih, 300, nullptr,
                                           nullptr, XAf, 12800, 600, 150);
  gemm_k<<<dim3(10,200), blk, 0, stream>>>(Hp, nullptr, nullptr, mbWih, 300, nullptr,
                                           nullptr, XAb, 12800, 600, 150);
  gemm_k<<<dim3(10, 25), blk, 0, stream>>>(Hq, nullptr, nullptr, mfWih + 150, 300, nullptr,
                                           nullptr, QWf, 1600, 600, 150);
  gemm_k<<<dim3(10, 25), blk, 0, stream>>>(Hq, nullptr, nullptr, mbWih + 150, 300, nullptr,
                                           nullptr, QWb, 1600, 600, 150);
  match_k<<<64, 640, 0, stream>>>(XAf, XAb, QWf, QWb, aqb, ppb, mfWhh, mbWhh,
                                  mfb, mbb, Wr, wa, plens, Hr);
  gemm_k<<<dim3(3,200), blk, 0, stream>>>(Hr, nullptr, nullptr, Vm, 300, nullptr,
                                          am, nullptr, 12800, 150, 300);
  ptr_k<<<32, 640, 0, stream>>>(am, Hr, Waa, baa, wb, apWih, apWhh, apb, out);
}

// Round 8
// 3050.046 us; speedup vs baseline: 1.0001x; 1.0001x over previous
//
#include <hip/hip_runtime.h>

// MatchLSTM forward pipeline for MI355X.
// R8: force the register-allocator budget with amdgpu_waves_per_eu(1,3).
// launch_bounds' min-waves arg never raises the RA target — RA budgets for
// the LDS-derived achievable occupancy (67KB -> 2WG/CU -> 5 waves/EU -> ~102
// VGPRs), so the pinned weights spilled to scratch (R6/R7 = 1990us, the
// spill regime). An explicit max=3 waves/EU gives budget 512/3 ~= 170 regs,
// enough for the ~150-reg working set (104 packed weight words + live).

typedef _Float16 f16;
typedef f16 f16x2 __attribute__((ext_vector_type(2)));
typedef unsigned int u32;
typedef unsigned short u16;

constexpr int cLP = 400, cLQ = 50, cB = 32, cH = 150, cG = 600;

__device__ __forceinline__ float exp2_(float x){
#if __has_builtin(__builtin_amdgcn_exp2f)
  return __builtin_amdgcn_exp2f(x);
#else
  return exp2f(x);
#endif
}
__device__ __forceinline__ float rcp_(float x){
#if __has_builtin(__builtin_amdgcn_rcpf)
  return __builtin_amdgcn_rcpf(x);
#else
  return 1.0f / x;
#endif
}
__device__ __forceinline__ float sigm(float x){ return rcp_(1.f + exp2_(-1.44269504f * x)); }
__device__ __forceinline__ float tanh_(float x){ return 1.f - 2.f * rcp_(1.f + exp2_(2.88539008f * x)); }

union U2 { u32 u; f16x2 h; };

__device__ __forceinline__ float fdot2_(u32 a, u32 b, float c){
  U2 ua, ub; ua.u = a; ub.u = b;
#if __has_builtin(__builtin_amdgcn_fdot2)
  return __builtin_amdgcn_fdot2(ua.h, ub.h, c, false);
#else
  return c + (float)ua.h[0] * (float)ub.h[0] + (float)ua.h[1] * (float)ub.h[1];
#endif
}
__device__ __forceinline__ u32 pack2(float x, float y){
  U2 p; p.h[0] = (f16)x; p.h[1] = (f16)y; return p.u;
}
__device__ __forceinline__ float2 unp2(u32 v){
  U2 p; p.u = v; return make_float2((float)p.h[0], (float)p.h[1]);
}

// load 4 f16x2 pairs (8 floats) from a weight row at pair offset 4*i
__device__ __forceinline__ uint4 ldw4(const float* __restrict__ wr, int i){
  uint4 r;
  r.x = pack2(wr[8*i+0], wr[8*i+1]);
  r.y = pack2(wr[8*i+2], wr[8*i+3]);
  r.z = pack2(wr[8*i+4], wr[8*i+5]);
  r.w = pack2(wr[8*i+6], wr[8*i+7]);
  return r;
}

// opaque barrier: values become asm outputs -> cannot be rematerialized
#define PIN4(v) asm volatile("" : "+v"(v.x), "+v"(v.y), "+v"(v.z), "+v"(v.w));
#define PIN4W(i) PIN4(w##i)
#define PIN4Q(i) PIN4(q##i)

#define REP18(M) M(0) M(1) M(2) M(3) M(4) M(5) M(6) M(7) M(8) M(9) \
                 M(10) M(11) M(12) M(13) M(14) M(15) M(16) M(17)
#define REP19(M) REP18(M) M(18)
#define REP7(M) M(0) M(1) M(2) M(3) M(4) M(5) M(6)

// ---------------------------------------------------------------------------
// Generic f32 GEMM: C[M][N] = A[M][K] @ W[N][K]^T (+bias). Optional embedding
// gather for A rows. Optional f16 output. Tile 64x64, 4x4/thread, 256 thr.
// ---------------------------------------------------------------------------
__global__ __launch_bounds__(256)
void gemm_k(const float* __restrict__ A, const int* __restrict__ ids,
            const float* __restrict__ emb,
            const float* __restrict__ W, int ldw, const float* __restrict__ bias,
            float* __restrict__ Cf, f16* __restrict__ Ch,
            int M, int N, int K)
{
  __shared__ __align__(16) float As[16][68];
  __shared__ __align__(16) float Wt[16][68];
  __shared__ int sids[64];
  int tid = threadIdx.x;
  int n0 = blockIdx.x * 64;
  int m0 = blockIdx.y * 64;
  int tx = tid & 15, ty = tid >> 4;
  if (ids){ if (tid < 64) sids[tid] = ids[m0 + tid]; }
  __syncthreads();

  float acc[4][4] = {};
  int sm = tid >> 2;
  int kq = (tid & 3) << 2;
  const float* arow = ids ? (emb + (size_t)sids[sm] * K)
                          : (A   + (size_t)(m0 + sm) * K);
  const float* wrow = W + (size_t)(n0 + sm) * ldw;
  bool nok = (n0 + sm) < N;

  for (int k0 = 0; k0 < K; k0 += 16){
    #pragma unroll
    for (int p = 0; p < 4; p++){
      int kk = kq + p, k = k0 + kk;
      As[kk][sm] = (k < K) ? arow[k] : 0.f;
      Wt[kk][sm] = (nok && k < K) ? wrow[k] : 0.f;
    }
    __syncthreads();
    #pragma unroll
    for (int kk = 0; kk < 16; kk++){
      float4 av = *(const float4*)&As[kk][ty << 2];
      float4 wv = *(const float4*)&Wt[kk][tx << 2];
      float a[4] = {av.x, av.y, av.z, av.w};
      float w[4] = {wv.x, wv.y, wv.z, wv.w};
      #pragma unroll
      for (int i = 0; i < 4; i++)
        #pragma unroll
        for (int j = 0; j < 4; j++)
          acc[i][j] += a[i] * w[j];
    }
    __syncthreads();
  }
  float bj[4];
  #pragma unroll
  for (int j = 0; j < 4; j++){
    int n = n0 + (tx << 2) + j;
    bj[j] = (bias && n < N) ? bias[n] : 0.f;
  }
  #pragma unroll
  for (int i = 0; i < 4; i++){
    int m = m0 + (ty << 2) + i;
    #pragma unroll
    for (int j = 0; j < 4; j++){
      int n = n0 + (tx << 2) + j;
      if (n < N){
        size_t ci = (size_t)m * N + n;
        float v = acc[i][j] + bj[j];
        if (Ch) Ch[ci] = (f16)v; else Cf[ci] = v;
      }
    }
  }
}

// ---------------------------------------------------------------------------
// Encoder LSTM. 64 WGs: wg<32 -> passage b, else question b. 640 threads.
// Whh rows in pinned uint4 VGPRs. XG prefetched 1 step ahead.
// ---------------------------------------------------------------------------
__attribute__((amdgpu_waves_per_eu(1, 3)))
__global__ __launch_bounds__(640)
void enc_k(const float* __restrict__ XGp, const float* __restrict__ XGq,
           const float* __restrict__ Whh,
           const int* __restrict__ plens, const int* __restrict__ qlens,
           float* __restrict__ Hp, float* __restrict__ Hq)
{
  int wg = blockIdx.x;
  bool isq = wg >= cB;
  int b = wg & (cB - 1);
  const float* XG = isq ? XGq : XGp;
  float* Hout = isq ? Hq : Hp;
  int T   = isq ? cLQ : cLP;
  int len = (isq ? qlens : plens)[b];
  int tid = threadIdx.x;

  __shared__ float c[cH], gl[cG];
  __shared__ __align__(16) u32 h2s[80];

#define DECLW(i) uint4 w##i;
  REP19(DECLW)
#undef DECLW
  {
    const float* wr = Whh + (size_t)(tid < cG ? tid : 0) * cH;
#define LOADW(i) w##i = ldw4(wr, i);
    REP18(LOADW)
#undef LOADW
    w18.x = pack2(wr[144], wr[145]);
    w18.y = pack2(wr[146], wr[147]);
    w18.z = pack2(wr[148], wr[149]);
    w18.w = 0;
    REP19(PIN4W)
  }
  if (tid < cH) c[tid] = 0.f;
  if (tid < 80) h2s[tid] = 0;
  __syncthreads();

  float xgCur = 0.f;
  if (tid < cG) xgCur = XG[(size_t)b * cG + tid];

  for (int t = 0; t < T; t++){
    int tn = (t + 1 < T) ? t + 1 : t;
    float xgN = 0.f;
    if (tid < cG) xgN = XG[((size_t)tn * cB + b) * cG + tid];

    if (tid < cG){
      float aA = 0.f, aB = 0.f, aC = 0.f, aD = 0.f;
#define DOTW(i) { uint4 hq = *(const uint4*)&h2s[4*(i)]; \
      aA = fdot2_(hq.x, w##i.x, aA); aB = fdot2_(hq.y, w##i.y, aB); \
      aC = fdot2_(hq.z, w##i.z, aC); aD = fdot2_(hq.w, w##i.w, aD); }
      REP19(DOTW)
#undef DOTW
      gl[tid] = xgCur + ((aA + aB) + (aC + aD));
    }
    __syncthreads();
    if (tid < 75){
      float hv[2];
      #pragma unroll
      for (int z = 0; z < 2; z++){
        int u = 2 * tid + z;
        float ig = sigm(gl[u]);
        float fg = sigm(gl[cH + u]);
        float gg = tanh_(gl[2 * cH + u]);
        float og = sigm(gl[3 * cH + u]);
        float c2 = fg * c[u] + ig * gg;
        float hh = og * tanh_(c2);
        c[u] = c2;
        hv[z] = hh;
      }
      h2s[tid] = pack2(hv[0], hv[1]);      // unmasked h carries the recurrence
      float mk = (t < len) ? 1.f : 0.f;
      float2 st; st.x = hv[0] * mk; st.y = hv[1] * mk;
      *(float2*)&Hout[((size_t)t * cB + b) * cH + 2 * tid] = st;
    }
    __syncthreads();
    xgCur = xgN;
  }
}

// ---------------------------------------------------------------------------
// Match-LSTM, fwd + bwd. 64 WGs = dir(2) x batch(32), 640 threads.
// 5-phase structure; Whh (19 uint4) and QW (7 uint4) pinned in registers;
// aq + wa in LDS; XA/pp prefetched one step ahead.
// ---------------------------------------------------------------------------
__attribute__((amdgpu_waves_per_eu(1, 3)))
__global__ __launch_bounds__(640)
void match_k(const f16* __restrict__ XAf, const f16* __restrict__ XAb,
             const f16* __restrict__ QWf, const f16* __restrict__ QWb,
             const float* __restrict__ aq, const float* __restrict__ pp,
             const float* __restrict__ mfWhh, const float* __restrict__ mbWhh,
             const float* __restrict__ mfb, const float* __restrict__ mbb,
             const float* __restrict__ Wr, const float* __restrict__ wa,
             const int* __restrict__ plens, float* __restrict__ Hr)
{
  constexpr int NPAD = 160;
  constexpr int AQS  = 81;
  int wg = blockIdx.x;
  int dir = wg >> 5;
  int b = wg & 31;
  const f16* XA = dir ? XAb : XAf;
  const f16* QW = dir ? QWb : QWf;
  const float* Whh = dir ? mbWhh : mfWhh;
  const float* bm  = dir ? mbb   : mfb;
  int len = plens[b];
  int tid = threadIdx.x;

  __shared__ u32 WrT2[76 * 150];        // [pair p][j], f16x2-packed Wr^T
  __shared__ u32 aq2[cLQ * AQS];        // [l][jp] f16x2 pairs of aq (zero-pad)
  __shared__ float gl[cG];
  __shared__ float sc[NPAD];            // pp_t + h@Wr^T (zero-padded)
  __shared__ float waS[NPAD];
  __shared__ float c[cH];
  __shared__ __align__(16) u32 h2s[80];
  __shared__ float loge[64];
  __shared__ __align__(16) u32 alpha2[28];

  // ---- one-time loads: weights into pinned registers ----
#define DECLW(i) uint4 w##i;
  REP19(DECLW)
#undef DECLW
  float bk = 0.f;
  {
    const float* wr = Whh + (size_t)(tid < cG ? tid : 0) * cH;
#define LOADW(i) w##i = ldw4(wr, i);
    REP18(LOADW)
#undef LOADW
    w18.x = pack2(wr[144], wr[145]);
    w18.y = pack2(wr[146], wr[147]);
    w18.z = pack2(wr[148], wr[149]);
    w18.w = 0;
    REP19(PIN4W)
    if (tid < cG) bk = bm[tid];
  }
#define DECLQ(i) uint4 q##i;
  REP7(DECLQ)
#undef DECLQ
  {
    const u16* QWu = (const u16*)QW;
    int row = (tid < cG) ? tid : 0;
    // pair p holds (alpha_{2p}, alpha_{2p+1}) weights: QW[l][b][row]
#define QP(p) ((u32)QWu[((size_t)(2*(p)) * cB + b) * cG + row] | \
               ((u32)QWu[((size_t)(2*(p)+1) * cB + b) * cG + row] << 16))
#define LOADQ(i) q##i.x = QP(4*(i)+0); q##i.y = QP(4*(i)+1); \
                 q##i.z = QP(4*(i)+2); q##i.w = QP(4*(i)+3);
    LOADQ(0) LOADQ(1) LOADQ(2) LOADQ(3) LOADQ(4) LOADQ(5)
    q6.x = QP(24); q6.y = 0; q6.z = 0; q6.w = 0;
#undef LOADQ
#undef QP
    REP7(PIN4Q)
  }
  for (int idx = tid; idx < cLQ * AQS; idx += 640){
    int l = idx / AQS, jp = idx % AQS;
    u32 v = 0;
    if (jp < 75){
      const float* ap = aq + ((size_t)l * cB + b) * cH;
      v = pack2(ap[2 * jp], ap[2 * jp + 1]);
    }
    aq2[idx] = v;
  }
  for (int i = tid; i < NPAD; i += 640) waS[i] = (i < cH) ? wa[i] : 0.f;
  for (int idx = tid; idx < 76 * 150; idx += 640){
    int p = idx / 150, k2 = idx % 150;
    WrT2[idx] = (p < 75) ? pack2(Wr[(size_t)k2 * cH + 2 * p],
                                 Wr[(size_t)k2 * cH + 2 * p + 1]) : 0u;
  }
  if (tid < cH) c[tid] = 0.f;
  if (tid < 80) h2s[tid] = 0;
  if (tid >= cH && tid < NPAD) sc[tid] = 0.f;
  __syncthreads();

  // prologue prefetch for step 0
  f16 xaCurH = (f16)0.f, xaNxtH = (f16)0.f;
  float ppCur = 0.f, ppNxt = 0.f;
  {
    int t0 = dir ? (cLP - 1) : 0;
    if (tid < cG) xaCurH = XA[((size_t)t0 * cB + b) * cG + tid];
    if (tid < cH) ppCur = pp[((size_t)t0 * cB + b) * cH + tid];
  }

  for (int s = 0; s < cLP; s++){
    int tt = dir ? (cLP - 1 - s) : s;
    float mk = (tt < len) ? 1.f : 0.f;

    // prefetch step s+1 (consumed next iteration)
    {
      int sn = (s + 1 < cLP) ? s + 1 : s;
      int tn = dir ? (cLP - 1 - sn) : sn;
      if (tid < cG) xaNxtH = XA[((size_t)tn * cB + b) * cG + tid];
      if (tid < cH) ppNxt = pp[((size_t)tn * cB + b) * cH + tid];
    }

    // A: sc = h@Wr^T + pp[tt]   (150 threads, conflict-free WrT2 reads)
    if (tid < cH){
      float sA = 0.f, sB = 0.f, sC = 0.f, sD = 0.f;
#define DOTA(i) { uint4 hq = *(const uint4*)&h2s[4*(i)]; \
      sA = fdot2_(hq.x, WrT2[(4*(i)+0)*150 + tid], sA); \
      sB = fdot2_(hq.y, WrT2[(4*(i)+1)*150 + tid], sB); \
      sC = fdot2_(hq.z, WrT2[(4*(i)+2)*150 + tid], sC); \
      sD = fdot2_(hq.w, WrT2[(4*(i)+3)*150 + tid], sD); }
      REP19(DOTA)
#undef DOTA
      sc[tid] = ((sA + sB) + (sC + sD)) + ppCur;
    }
    __syncthreads();

    // B: attention logits; 8 lanes/l, 20-wide even-aligned j-chunks.
    if (tid < 400){
      int l = tid >> 3, q = tid & 7;
      const u32* arow = &aq2[l * AQS + q * 10];
      float part = 0.f;
      #pragma unroll
      for (int p = 0; p < 10; p++){
        int j = q * 20 + 2 * p;
        float2 av = unp2(arow[p]);
        float x0 = av.x + sc[j];
        float x1 = av.y + sc[j + 1];
        float r0 = rcp_(1.f + exp2_(2.88539008f * x0));
        float r1 = rcp_(1.f + exp2_(2.88539008f * x1));
        part += waS[j] * r0 + waS[j + 1] * r1;
      }
      part += __shfl_xor(part, 1);
      part += __shfl_xor(part, 2);
      part += __shfl_xor(part, 4);
      if (q == 0) loge[l] = part;
    }
    __syncthreads();

    // C: softmax over 50 on wave 0, f16-packed alpha pairs
    if (tid < 64){
      float lg = (tid < cLQ) ? (-2.f * loge[tid]) : -1e30f;
      float mx = lg;
      #pragma unroll
      for (int off = 32; off; off >>= 1) mx = fmaxf(mx, __shfl_xor(mx, off));
      float e = (tid < cLQ) ? exp2_((lg - mx) * 1.44269504f) : 0.f;
      float sum = e;
      #pragma unroll
      for (int off = 32; off; off >>= 1) sum += __shfl_xor(sum, off);
      float al = e * rcp_(sum);
      float alhi = __shfl_down(al, 1);
      if (tid < cLQ && !(tid & 1)) alpha2[tid >> 1] = pack2(al, alhi);
      if (tid >= 25 && tid < 28) alpha2[tid] = 0;
    }
    __syncthreads();

    // D: gl = b + h@Whh^T + mk*(XA + alpha@QW)   (600 threads, reg weights)
    if (tid < cG){
      float aA = 0.f, aB = 0.f, aC = 0.f, aD = 0.f;
#define DOTW(i) { uint4 hq = *(const uint4*)&h2s[4*(i)]; \
      aA = fdot2_(hq.x, w##i.x, aA); aB = fdot2_(hq.y, w##i.y, aB); \
      aC = fdot2_(hq.z, w##i.z, aC); aD = fdot2_(hq.w, w##i.w, aD); }
      REP19(DOTW)
#undef DOTW
      float qA = 0.f, qB = 0.f;
#define DOTQ(i) { uint4 a4 = *(const uint4*)&alpha2[4*(i)]; \
      qA = fdot2_(a4.x, q##i.x, qA); qB = fdot2_(a4.y, q##i.y, qB); \
      qA = fdot2_(a4.z, q##i.z, qA); qB = fdot2_(a4.w, q##i.w, qB); }
      REP7(DOTQ)
#undef DOTQ
      float acc = ((aA + aB) + (aC + aD));
      gl[tid] = bk + acc + mk * ((float)xaCurH + (qA + qB));
    }
    __syncthreads();

    // E: LSTM cell; h2,c2 masked inside recurrence (ref semantics)
    if (tid < 75){
      float hv[2];
      #pragma unroll
      for (int z = 0; z < 2; z++){
        int u = 2 * tid + z;
        float ig = sigm(gl[u]);
        float fg = sigm(gl[cH + u]);
        float gg = tanh_(gl[2 * cH + u]);
        float og = sigm(gl[3 * cH + u]);
        float c2 = (fg * c[u] + ig * gg) * mk;
        float hh = og * tanh_(c2) * mk;
        c[u] = c2;
        hv[z] = hh;
      }
      h2s[tid] = pack2(hv[0], hv[1]);
      float2 st; st.x = hv[0]; st.y = hv[1];
      *(float2*)&Hr[((size_t)tt * cB + b) * (2 * cH) + dir * cH + 2 * tid] = st;
    }
    __syncthreads();

    xaCurH = xaNxtH;
    ppCur  = ppNxt;
  }
}

// ---------------------------------------------------------------------------
// Answer pointer: 32 WGs (one per batch), 2 sequential iterations.
// ---------------------------------------------------------------------------
__global__ __launch_bounds__(640)
void ptr_k(const float* __restrict__ am, const float* __restrict__ Hr,
           const float* __restrict__ Wa, const float* __restrict__ baa,
           const float* __restrict__ wb,
           const float* __restrict__ apWih, const float* __restrict__ apWhh,
             const float* __restrict__ apb, float* __restrict__ out)
{
  int b = blockIdx.x, tid = threadIdx.x;
  __shared__ float ha[cH], ca[cH], haWa[160], wbs[160];
  __shared__ float beta[cLP], wHr[2 * cH], gl[cG], red[20];
  if (tid < cH){ ha[tid] = 0.f; ca[tid] = 0.f; }
  if (tid < 160) wbs[tid] = (tid < cH) ? wb[tid] : 0.f;
  __syncthreads();

  for (int it = 0; it < 2; ++it){
    if (tid < cH){
      float acc = baa[tid];
      const float* wr = Wa + (size_t)tid * cH;
      for (int i = 0; i < cH; i++) acc += ha[i] * wr[i];
      haWa[tid] = acc;
    } else if (tid < 160) haWa[tid] = 0.f;
    __syncthreads();

    {
      int tt = tid >> 4;
      int jq = tid & 15;
      for (int t0 = 0; t0 < cLP; t0 += 40){
        int t = t0 + tt;
        float part = 0.f;
        const float* amr = am + ((size_t)t * cB + b) * cH;
        #pragma unroll
        for (int i = 0; i < 10; i++){
          int j = jq * 10 + i;
          if (j < cH){
            float F = tanh_(amr[j] + haWa[j]);
            part += wbs[j] * F;
          }
        }
        part += __shfl_xor(part, 1);
        part += __shfl_xor(part, 2);
        part += __shfl_xor(part, 4);
        part += __shfl_xor(part, 8);
        if (jq == 0) beta[t] = part;
      }
    }
    __syncthreads();

    float x = (tid < cLP) ? beta[tid] : -1e30f;
    float mx = x;
    #pragma unroll
    for (int off = 32; off; off >>= 1) mx = fmaxf(mx, __shfl_xor(mx, off));
    if ((tid & 63) == 0) red[tid >> 6] = mx;
    __syncthreads();
    if (tid == 0){
      float m2 = red[0];
      for (int w = 1; w < 10; w++) m2 = fmaxf(m2, red[w]);
      red[16] = m2;
    }
    __syncthreads();
    mx = red[16];
    float e = (tid < cLP) ? exp2_((x - mx) * 1.44269504f) : 0.f;
    float sm = e;
    #pragma unroll
    for (int off = 32; off; off >>= 1) sm += __shfl_xor(sm, off);
    if ((tid & 63) == 0) red[tid >> 6] = sm;
    __syncthreads();
    if (tid == 0){
      float s2 = 0.f;
      for (int w = 0; w < 10; w++) s2 += red[w];
      red[17] = s2;
    }
    __syncthreads();
    float bsum = red[17];
    if (tid < cLP){
      float bt = e * rcp_(bsum);
      beta[tid] = bt;
      out[(size_t)it * cLP * cB + (size_t)tid * cB + b] = bt;
    }
    __syncthreads();

    if (tid < 2 * cH){
      float acc = 0.f;
      for (int t = 0; t < cLP; t++)
        acc += beta[t] * Hr[((size_t)t * cB + b) * (2 * cH) + tid];
      wHr[tid] = acc;
    }
    __syncthreads();

    if (tid < cG){
      float acc = apb[tid];
      const float* r1 = apWih + (size_t)tid * (2 * cH);
      for (int i = 0; i < 2 * cH; i++) acc += wHr[i] * r1[i];
      const float* r2 = apWhh + (size_t)tid * cH;
      for (int i = 0; i < cH; i++) acc += ha[i] * r2[i];
      gl[tid] = acc;
    }
    __syncthreads();
    if (tid < cH){
      float ig = sigm(gl[tid]);
      float fg = sigm(gl[cH + tid]);
      float gg = tanh_(gl[2 * cH + tid]);
      float og = sigm(gl[3 * cH + tid]);
      float c2 = fg * ca[tid] + ig * gg;
      ca[tid] = c2;
      ha[tid] = og * tanh_(c2);
    }
    __syncthreads();
  }
}

// ---------------------------------------------------------------------------
extern "C" void kernel_launch(void* const* d_in, const int* in_sizes, int n_in,
                              void* d_out, int out_size, void* d_ws, size_t ws_size,
                              hipStream_t stream)
{
  (void)in_sizes; (void)n_in; (void)out_size; (void)ws_size;
  const int*   p_ids = (const int*)d_in[0];
  const int*   q_ids = (const int*)d_in[1];
  const int*   plens = (const int*)d_in[2];
  const int*   qlens = (const int*)d_in[3];
  const float* emb   = (const float*)d_in[4];
  const float* pWih  = (const float*)d_in[5];
  const float* pWhh  = (const float*)d_in[6];
  const float* pb    = (const float*)d_in[7];
  const float* Wq    = (const float*)d_in[8];
  const float* Wp    = (const float*)d_in[9];
  const float* bp    = (const float*)d_in[10];
  const float* Wr    = (const float*)d_in[11];
  const float* wa    = (const float*)d_in[12];
  const float* mfWih = (const float*)d_in[14];
  const float* mfWhh = (const float*)d_in[15];
  const float* mfb   = (const float*)d_in[16];
  const float* mbWih = (const float*)d_in[17];
  const float* mbWhh = (const float*)d_in[18];
  const float* mbb   = (const float*)d_in[19];
  const float* Vm    = (const float*)d_in[20];
  const float* Waa   = (const float*)d_in[21];
  const float* baa   = (const float*)d_in[22];
  const float* wb    = (const float*)d_in[23];
  const float* apWih = (const float*)d_in[25];
  const float* apWhh = (const float*)d_in[26];
  const float* apb   = (const float*)d_in[27];
  float* out = (float*)d_out;

  // workspace layout (floats); total 22,560,000 f = 90.24 MB
  float* ws  = (float*)d_ws;
  float* XGp = ws;                       // [400*32][600] f32 (later aliased XAf)
  float* XGq = ws + 7680000;             // [50*32][600]  f32 (later aliased QW)
  f16*   XAb = (f16*)(ws + 8640000);     // [400*32][600] f16
  float* Hp  = ws + 12480000;            // [400*32][150]
  float* Hq  = ws + 14400000;            // [50*32][150]
  float* aqb = ws + 14640000;            // [50*32][150]
  float* ppb = ws + 14880000;            // [400*32][150]
  float* Hr  = ws + 16800000;            // [400*32][300]
  float* am  = ws + 20640000;            // [400*32][150]
  f16*   XAf = (f16*)XGp;                // alias: XGp dead after enc_k
  f16*   QWf = (f16*)XGq;                // alias: XGq dead after enc_k
  f16*   QWb = QWf + (size_t)1600 * 600;

  dim3 blk(256);
  gemm_k<<<dim3(10,200), blk, 0, stream>>>(nullptr, p_ids, emb, pWih, 300, pb,
                                           XGp, nullptr, 12800, 600, 300);
  gemm_k<<<dim3(10, 25), blk, 0, stream>>>(nullptr, q_ids, emb, pWih, 300, pb,
                                           XGq, nullptr, 1600, 600, 300);
  enc_k<<<64, 640, 0, stream>>>(XGp, XGq, pWhh, plens, qlens, Hp, Hq);
  gemm_k<<<dim3(3,200), blk, 0, stream>>>(Hp, nullptr, nullptr, Wp, 150, bp,
                                          ppb, nullptr, 12800, 150, 150);
  gemm_k<<<dim3(3, 25), blk, 0, stream>>>(Hq, nullptr, nullptr, Wq, 150, nullptr,
                                          aqb, nullptr, 1600, 150, 150);
  gemm_k<<<dim3(10,200), blk, 0, stream>>>(Hp, nullptr, nullptr, mfWih, 300, nullptr,
                                           nullptr, XAf, 12800, 600, 150);
  gemm_k<<<dim3(10,200), blk, 0, stream>>>(Hp, nullptr, nullptr, mbWih, 300, nullptr,
                                           nullptr, XAb, 12800, 600, 150);
  gemm_k<<<dim3(10, 25), blk, 0, stream>>>(Hq, nullptr, nullptr, mfWih + 150, 300, nullptr,
                                           nullptr, QWf, 1600, 600, 150);
  gemm_k<<<dim3(10, 25), blk, 0, stream>>>(Hq, nullptr, nullptr, mbWih + 150, 300, nullptr,
                                           nullptr, QWb, 1600, 600, 150);
  match_k<<<64, 640, 0, stream>>>(XAf, XAb, QWf, QWb, aqb, ppb, mfWhh, mbWhh,
                                  mfb, mbb, Wr, wa, plens, Hr);
  gemm_k<<<dim3(3,200), blk, 0, stream>>>(Hr, nullptr, nullptr, Vm, 300, nullptr,
                                          am, nullptr, 12800, 150, 300);
  ptr_k<<<32, 640, 0, stream>>>(am, Hr, Waa, baa, wb, apWih, apWhh, apb, out);
}

// Round 9
// 3000.981 us; speedup vs baseline: 1.0165x; 1.0163x over previous
//
#include <hip/hip_runtime.h>

// MatchLSTM forward pipeline for MI355X.
// R9: break the RA's occupancy-derived VGPR cap by making LDS > 80 KB.
// With 67 KB LDS the allocator budgets for 2 WGs/CU (20 waves -> ~84 regs)
// and spills the pinned weights; no attribute overrode it (R7/R8). Only 64
// WGs exist on 256 CUs, so 1 WG/CU is the real occupancy anyway — pad LDS
// past 80 KB so the RA's achievable occupancy is 10 waves/CU = 3 waves/EU
// -> budget ~170 VGPRs -> the ~150-reg working set finally allocates.

typedef _Float16 f16;
typedef f16 f16x2 __attribute__((ext_vector_type(2)));
typedef unsigned int u32;
typedef unsigned short u16;

constexpr int cLP = 400, cLQ = 50, cB = 32, cH = 150, cG = 600;

__device__ __forceinline__ float exp2_(float x){
#if __has_builtin(__builtin_amdgcn_exp2f)
  return __builtin_amdgcn_exp2f(x);
#else
  return exp2f(x);
#endif
}
__device__ __forceinline__ float rcp_(float x){
#if __has_builtin(__builtin_amdgcn_rcpf)
  return __builtin_amdgcn_rcpf(x);
#else
  return 1.0f / x;
#endif
}
__device__ __forceinline__ float sigm(float x){ return rcp_(1.f + exp2_(-1.44269504f * x)); }
__device__ __forceinline__ float tanh_(float x){ return 1.f - 2.f * rcp_(1.f + exp2_(2.88539008f * x)); }

union U2 { u32 u; f16x2 h; };

__device__ __forceinline__ float fdot2_(u32 a, u32 b, float c){
  U2 ua, ub; ua.u = a; ub.u = b;
#if __has_builtin(__builtin_amdgcn_fdot2)
  return __builtin_amdgcn_fdot2(ua.h, ub.h, c, false);
#else
  return c + (float)ua.h[0] * (float)ub.h[0] + (float)ua.h[1] * (float)ub.h[1];
#endif
}
__device__ __forceinline__ u32 pack2(float x, float y){
  U2 p; p.h[0] = (f16)x; p.h[1] = (f16)y; return p.u;
}
__device__ __forceinline__ float2 unp2(u32 v){
  U2 p; p.u = v; return make_float2((float)p.h[0], (float)p.h[1]);
}

// load 4 f16x2 pairs (8 floats) from a weight row at pair offset 4*i
__device__ __forceinline__ uint4 ldw4(const float* __restrict__ wr, int i){
  uint4 r;
  r.x = pack2(wr[8*i+0], wr[8*i+1]);
  r.y = pack2(wr[8*i+2], wr[8*i+3]);
  r.z = pack2(wr[8*i+4], wr[8*i+5]);
  r.w = pack2(wr[8*i+6], wr[8*i+7]);
  return r;
}

// opaque barrier: values become asm outputs -> cannot be rematerialized
#define PIN4(v) asm volatile("" : "+v"(v.x), "+v"(v.y), "+v"(v.z), "+v"(v.w));
#define PIN4W(i) PIN4(w##i)
#define PIN4Q(i) PIN4(q##i)

#define REP18(M) M(0) M(1) M(2) M(3) M(4) M(5) M(6) M(7) M(8) M(9) \
                 M(10) M(11) M(12) M(13) M(14) M(15) M(16) M(17)
#define REP19(M) REP18(M) M(18)
#define REP7(M) M(0) M(1) M(2) M(3) M(4) M(5) M(6)

// ---------------------------------------------------------------------------
// Generic f32 GEMM: C[M][N] = A[M][K] @ W[N][K]^T (+bias). Optional embedding
// gather for A rows. Optional f16 output. Tile 64x64, 4x4/thread, 256 thr.
// ---------------------------------------------------------------------------
__global__ __launch_bounds__(256)
void gemm_k(const float* __restrict__ A, const int* __restrict__ ids,
            const float* __restrict__ emb,
            const float* __restrict__ W, int ldw, const float* __restrict__ bias,
            float* __restrict__ Cf, f16* __restrict__ Ch,
            int M, int N, int K)
{
  __shared__ __align__(16) float As[16][68];
  __shared__ __align__(16) float Wt[16][68];
  __shared__ int sids[64];
  int tid = threadIdx.x;
  int n0 = blockIdx.x * 64;
  int m0 = blockIdx.y * 64;
  int tx = tid & 15, ty = tid >> 4;
  if (ids){ if (tid < 64) sids[tid] = ids[m0 + tid]; }
  __syncthreads();

  float acc[4][4] = {};
  int sm = tid >> 2;
  int kq = (tid & 3) << 2;
  const float* arow = ids ? (emb + (size_t)sids[sm] * K)
                          : (A   + (size_t)(m0 + sm) * K);
  const float* wrow = W + (size_t)(n0 + sm) * ldw;
  bool nok = (n0 + sm) < N;

  for (int k0 = 0; k0 < K; k0 += 16){
    #pragma unroll
    for (int p = 0; p < 4; p++){
      int kk = kq + p, k = k0 + kk;
      As[kk][sm] = (k < K) ? arow[k] : 0.f;
      Wt[kk][sm] = (nok && k < K) ? wrow[k] : 0.f;
    }
    __syncthreads();
    #pragma unroll
    for (int kk = 0; kk < 16; kk++){
      float4 av = *(const float4*)&As[kk][ty << 2];
      float4 wv = *(const float4*)&Wt[kk][tx << 2];
      float a[4] = {av.x, av.y, av.z, av.w};
      float w[4] = {wv.x, wv.y, wv.z, wv.w};
      #pragma unroll
      for (int i = 0; i < 4; i++)
        #pragma unroll
        for (int j = 0; j < 4; j++)
          acc[i][j] += a[i] * w[j];
    }
    __syncthreads();
  }
  float bj[4];
  #pragma unroll
  for (int j = 0; j < 4; j++){
    int n = n0 + (tx << 2) + j;
    bj[j] = (bias && n < N) ? bias[n] : 0.f;
  }
  #pragma unroll
  for (int i = 0; i < 4; i++){
    int m = m0 + (ty << 2) + i;
    #pragma unroll
    for (int j = 0; j < 4; j++){
      int n = n0 + (tx << 2) + j;
      if (n < N){
        size_t ci = (size_t)m * N + n;
        float v = acc[i][j] + bj[j];
        if (Ch) Ch[ci] = (f16)v; else Cf[ci] = v;
      }
    }
  }
}

// ---------------------------------------------------------------------------
// Encoder LSTM. 64 WGs: wg<32 -> passage b, else question b. 640 threads.
// Whh rows in pinned uint4 VGPRs. XG prefetched 1 step ahead.
// LDS padded >80 KB to force the RA to budget for 1 WG/CU (~170 VGPRs).
// ---------------------------------------------------------------------------
__attribute__((amdgpu_waves_per_eu(1, 3)))
__global__ __launch_bounds__(640)
void enc_k(const float* __restrict__ XGp, const float* __restrict__ XGq,
           const float* __restrict__ Whh,
           const int* __restrict__ plens, const int* __restrict__ qlens,
           float* __restrict__ Hp, float* __restrict__ Hq)
{
  int wg = blockIdx.x;
  bool isq = wg >= cB;
  int b = wg & (cB - 1);
  const float* XG = isq ? XGq : XGp;
  float* Hout = isq ? Hq : Hp;
  int T   = isq ? cLQ : cLP;
  int len = (isq ? qlens : plens)[b];
  int tid = threadIdx.x;

  __shared__ float c[cH], gl[cG];
  __shared__ __align__(16) u32 h2s[80];
  __shared__ u32 occupancy_pad[19712];   // ~77 KB: forces 1 WG/CU RA budget
  occupancy_pad[tid] = 0;                // touch so it isn't eliminated

#define DECLW(i) uint4 w##i;
  REP19(DECLW)
#undef DECLW
  {
    const float* wr = Whh + (size_t)(tid < cG ? tid : 0) * cH;
#define LOADW(i) w##i = ldw4(wr, i);
    REP18(LOADW)
#undef LOADW
    w18.x = pack2(wr[144], wr[145]);
    w18.y = pack2(wr[146], wr[147]);
    w18.z = pack2(wr[148], wr[149]);
    w18.w = 0;
    REP19(PIN4W)
  }
  if (tid < cH) c[tid] = 0.f;
  if (tid < 80) h2s[tid] = 0;
  __syncthreads();

  float xgCur = 0.f;
  if (tid < cG) xgCur = XG[(size_t)b * cG + tid];

  for (int t = 0; t < T; t++){
    int tn = (t + 1 < T) ? t + 1 : t;
    float xgN = 0.f;
    if (tid < cG) xgN = XG[((size_t)tn * cB + b) * cG + tid];

    if (tid < cG){
      float aA = 0.f, aB = 0.f, aC = 0.f, aD = 0.f;
#define DOTW(i) { uint4 hq = *(const uint4*)&h2s[4*(i)]; \
      aA = fdot2_(hq.x, w##i.x, aA); aB = fdot2_(hq.y, w##i.y, aB); \
      aC = fdot2_(hq.z, w##i.z, aC); aD = fdot2_(hq.w, w##i.w, aD); }
      REP19(DOTW)
#undef DOTW
      gl[tid] = xgCur + ((aA + aB) + (aC + aD));
    }
    __syncthreads();
    if (tid < 75){
      float hv[2];
      #pragma unroll
      for (int z = 0; z < 2; z++){
        int u = 2 * tid + z;
        float ig = sigm(gl[u]);
        float fg = sigm(gl[cH + u]);
        float gg = tanh_(gl[2 * cH + u]);
        float og = sigm(gl[3 * cH + u]);
        float c2 = fg * c[u] + ig * gg;
        float hh = og * tanh_(c2);
        c[u] = c2;
        hv[z] = hh;
      }
      h2s[tid] = pack2(hv[0], hv[1]);      // unmasked h carries the recurrence
      float mk = (t < len) ? 1.f : 0.f;
      float2 st; st.x = hv[0] * mk; st.y = hv[1] * mk;
      *(float2*)&Hout[((size_t)t * cB + b) * cH + 2 * tid] = st;
    }
    __syncthreads();
    xgCur = xgN;
  }
}

// ---------------------------------------------------------------------------
// Match-LSTM, fwd + bwd. 64 WGs = dir(2) x batch(32), 640 threads.
// 5-phase structure; Whh (19 uint4) and QW (7 uint4) pinned in registers;
// aq + wa in LDS; XA/pp prefetched one step ahead.
// LDS padded >80 KB to force the RA to budget for 1 WG/CU (~170 VGPRs).
// ---------------------------------------------------------------------------
__attribute__((amdgpu_waves_per_eu(1, 3)))
__global__ __launch_bounds__(640)
void match_k(const f16* __restrict__ XAf, const f16* __restrict__ XAb,
             const f16* __restrict__ QWf, const f16* __restrict__ QWb,
             const float* __restrict__ aq, const float* __restrict__ pp,
             const float* __restrict__ mfWhh, const float* __restrict__ mbWhh,
             const float* __restrict__ mfb, const float* __restrict__ mbb,
             const float* __restrict__ Wr, const float* __restrict__ wa,
             const int* __restrict__ plens, float* __restrict__ Hr)
{
  constexpr int NPAD = 160;
  constexpr int AQS  = 81;
  int wg = blockIdx.x;
  int dir = wg >> 5;
  int b = wg & 31;
  const f16* XA = dir ? XAb : XAf;
  const f16* QW = dir ? QWb : QWf;
  const float* Whh = dir ? mbWhh : mfWhh;
  const float* bm  = dir ? mbb   : mfb;
  int len = plens[b];
  int tid = threadIdx.x;

  __shared__ u32 WrT2[76 * 150];        // [pair p][j], f16x2-packed Wr^T
  __shared__ u32 aq2[cLQ * AQS];        // [l][jp] f16x2 pairs of aq (zero-pad)
  __shared__ float gl[cG];
  __shared__ float sc[NPAD];            // pp_t + h@Wr^T (zero-padded)
  __shared__ float waS[NPAD];
  __shared__ float c[cH];
  __shared__ __align__(16) u32 h2s[80];
  __shared__ float loge[64];
  __shared__ __align__(16) u32 alpha2[28];
  __shared__ u32 occupancy_pad[5120];   // +20 KB -> ~87 KB total: 1 WG/CU
  occupancy_pad[tid] = 0;               // touch so it isn't eliminated

  // ---- one-time loads: weights into pinned registers ----
#define DECLW(i) uint4 w##i;
  REP19(DECLW)
#undef DECLW
  float bk = 0.f;
  {
    const float* wr = Whh + (size_t)(tid < cG ? tid : 0) * cH;
#define LOADW(i) w##i = ldw4(wr, i);
    REP18(LOADW)
#undef LOADW
    w18.x = pack2(wr[144], wr[145]);
    w18.y = pack2(wr[146], wr[147]);
    w18.z = pack2(wr[148], wr[149]);
    w18.w = 0;
    REP19(PIN4W)
    if (tid < cG) bk = bm[tid];
  }
#define DECLQ(i) uint4 q##i;
  REP7(DECLQ)
#undef DECLQ
  {
    const u16* QWu = (const u16*)QW;
    int row = (tid < cG) ? tid : 0;
    // pair p holds (alpha_{2p}, alpha_{2p+1}) weights: QW[l][b][row]
#define QP(p) ((u32)QWu[((size_t)(2*(p)) * cB + b) * cG + row] | \
               ((u32)QWu[((size_t)(2*(p)+1) * cB + b) * cG + row] << 16))
#define LOADQ(i) q##i.x = QP(4*(i)+0); q##i.y = QP(4*(i)+1); \
                 q##i.z = QP(4*(i)+2); q##i.w = QP(4*(i)+3);
    LOADQ(0) LOADQ(1) LOADQ(2) LOADQ(3) LOADQ(4) LOADQ(5)
    q6.x = QP(24); q6.y = 0; q6.z = 0; q6.w = 0;
#undef LOADQ
#undef QP
    REP7(PIN4Q)
  }
  for (int idx = tid; idx < cLQ * AQS; idx += 640){
    int l = idx / AQS, jp = idx % AQS;
    u32 v = 0;
    if (jp < 75){
      const float* ap = aq + ((size_t)l * cB + b) * cH;
      v = pack2(ap[2 * jp], ap[2 * jp + 1]);
    }
    aq2[idx] = v;
  }
  for (int i = tid; i < NPAD; i += 640) waS[i] = (i < cH) ? wa[i] : 0.f;
  for (int idx = tid; idx < 76 * 150; idx += 640){
    int p = idx / 150, k2 = idx % 150;
    WrT2[idx] = (p < 75) ? pack2(Wr[(size_t)k2 * cH + 2 * p],
                                 Wr[(size_t)k2 * cH + 2 * p + 1]) : 0u;
  }
  if (tid < cH) c[tid] = 0.f;
  if (tid < 80) h2s[tid] = 0;
  if (tid >= cH && tid < NPAD) sc[tid] = 0.f;
  __syncthreads();

  // prologue prefetch for step 0
  f16 xaCurH = (f16)0.f, xaNxtH = (f16)0.f;
  float ppCur = 0.f, ppNxt = 0.f;
  {
    int t0 = dir ? (cLP - 1) : 0;
    if (tid < cG) xaCurH = XA[((size_t)t0 * cB + b) * cG + tid];
    if (tid < cH) ppCur = pp[((size_t)t0 * cB + b) * cH + tid];
  }

  for (int s = 0; s < cLP; s++){
    int tt = dir ? (cLP - 1 - s) : s;
    float mk = (tt < len) ? 1.f : 0.f;

    // prefetch step s+1 (consumed next iteration)
    {
      int sn = (s + 1 < cLP) ? s + 1 : s;
      int tn = dir ? (cLP - 1 - sn) : sn;
      if (tid < cG) xaNxtH = XA[((size_t)tn * cB + b) * cG + tid];
      if (tid < cH) ppNxt = pp[((size_t)tn * cB + b) * cH + tid];
    }

    // A: sc = h@Wr^T + pp[tt]   (150 threads, conflict-free WrT2 reads)
    if (tid < cH){
      float sA = 0.f, sB = 0.f, sC = 0.f, sD = 0.f;
#define DOTA(i) { uint4 hq = *(const uint4*)&h2s[4*(i)]; \
      sA = fdot2_(hq.x, WrT2[(4*(i)+0)*150 + tid], sA); \
      sB = fdot2_(hq.y, WrT2[(4*(i)+1)*150 + tid], sB); \
      sC = fdot2_(hq.z, WrT2[(4*(i)+2)*150 + tid], sC); \
      sD = fdot2_(hq.w, WrT2[(4*(i)+3)*150 + tid], sD); }
      REP19(DOTA)
#undef DOTA
      sc[tid] = ((sA + sB) + (sC + sD)) + ppCur;
    }
    __syncthreads();

    // B: attention logits; 8 lanes/l, 20-wide even-aligned j-chunks.
    if (tid < 400){
      int l = tid >> 3, q = tid & 7;
      const u32* arow = &aq2[l * AQS + q * 10];
      float part = 0.f;
      #pragma unroll
      for (int p = 0; p < 10; p++){
        int j = q * 20 + 2 * p;
        float2 av = unp2(arow[p]);
        float x0 = av.x + sc[j];
        float x1 = av.y + sc[j + 1];
        float r0 = rcp_(1.f + exp2_(2.88539008f * x0));
        float r1 = rcp_(1.f + exp2_(2.88539008f * x1));
        part += waS[j] * r0 + waS[j + 1] * r1;
      }
      part += __shfl_xor(part, 1);
      part += __shfl_xor(part, 2);
      part += __shfl_xor(part, 4);
      if (q == 0) loge[l] = part;
    }
    __syncthreads();

    // C: softmax over 50 on wave 0, f16-packed alpha pairs
    if (tid < 64){
      float lg = (tid < cLQ) ? (-2.f * loge[tid]) : -1e30f;
      float mx = lg;
      #pragma unroll
      for (int off = 32; off; off >>= 1) mx = fmaxf(mx, __shfl_xor(mx, off));
      float e = (tid < cLQ) ? exp2_((lg - mx) * 1.44269504f) : 0.f;
      float sum = e;
      #pragma unroll
      for (int off = 32; off; off >>= 1) sum += __shfl_xor(sum, off);
      float al = e * rcp_(sum);
      float alhi = __shfl_down(al, 1);
      if (tid < cLQ && !(tid & 1)) alpha2[tid >> 1] = pack2(al, alhi);
      if (tid >= 25 && tid < 28) alpha2[tid] = 0;
    }
    __syncthreads();

    // D: gl = b + h@Whh^T + mk*(XA + alpha@QW)   (600 threads, reg weights)
    if (tid < cG){
      float aA = 0.f, aB = 0.f, aC = 0.f, aD = 0.f;
#define DOTW(i) { uint4 hq = *(const uint4*)&h2s[4*(i)]; \
      aA = fdot2_(hq.x, w##i.x, aA); aB = fdot2_(hq.y, w##i.y, aB); \
      aC = fdot2_(hq.z, w##i.z, aC); aD = fdot2_(hq.w, w##i.w, aD); }
      REP19(DOTW)
#undef DOTW
      float qA = 0.f, qB = 0.f;
#define DOTQ(i) { uint4 a4 = *(const uint4*)&alpha2[4*(i)]; \
      qA = fdot2_(a4.x, q##i.x, qA); qB = fdot2_(a4.y, q##i.y, qB); \
      qA = fdot2_(a4.z, q##i.z, qA); qB = fdot2_(a4.w, q##i.w, qB); }
      REP7(DOTQ)
#undef DOTQ
      float acc = ((aA + aB) + (aC + aD));
      gl[tid] = bk + acc + mk * ((float)xaCurH + (qA + qB));
    }
    __syncthreads();

    // E: LSTM cell; h2,c2 masked inside recurrence (ref semantics)
    if (tid < 75){
      float hv[2];
      #pragma unroll
      for (int z = 0; z < 2; z++){
        int u = 2 * tid + z;
        float ig = sigm(gl[u]);
        float fg = sigm(gl[cH + u]);
        float gg = tanh_(gl[2 * cH + u]);
        float og = sigm(gl[3 * cH + u]);
        float c2 = (fg * c[u] + ig * gg) * mk;
        float hh = og * tanh_(c2) * mk;
        c[u] = c2;
        hv[z] = hh;
      }
      h2s[tid] = pack2(hv[0], hv[1]);
      float2 st; st.x = hv[0]; st.y = hv[1];
      *(float2*)&Hr[((size_t)tt * cB + b) * (2 * cH) + dir * cH + 2 * tid] = st;
    }
    __syncthreads();

    xaCurH = xaNxtH;
    ppCur  = ppNxt;
  }
}

// ---------------------------------------------------------------------------
// Answer pointer: 32 WGs (one per batch), 2 sequential iterations.
// ---------------------------------------------------------------------------
__global__ __launch_bounds__(640)
void ptr_k(const float* __restrict__ am, const float* __restrict__ Hr,
           const float* __restrict__ Wa, const float* __restrict__ baa,
           const float* __restrict__ wb,
           const float* __restrict__ apWih, const float* __restrict__ apWhh,
             const float* __restrict__ apb, float* __restrict__ out)
{
  int b = blockIdx.x, tid = threadIdx.x;
  __shared__ float ha[cH], ca[cH], haWa[160], wbs[160];
  __shared__ float beta[cLP], wHr[2 * cH], gl[cG], red[20];
  if (tid < cH){ ha[tid] = 0.f; ca[tid] = 0.f; }
  if (tid < 160) wbs[tid] = (tid < cH) ? wb[tid] : 0.f;
  __syncthreads();

  for (int it = 0; it < 2; ++it){
    if (tid < cH){
      float acc = baa[tid];
      const float* wr = Wa + (size_t)tid * cH;
      for (int i = 0; i < cH; i++) acc += ha[i] * wr[i];
      haWa[tid] = acc;
    } else if (tid < 160) haWa[tid] = 0.f;
    __syncthreads();

    {
      int tt = tid >> 4;
      int jq = tid & 15;
      for (int t0 = 0; t0 < cLP; t0 += 40){
        int t = t0 + tt;
        float part = 0.f;
        const float* amr = am + ((size_t)t * cB + b) * cH;
        #pragma unroll
        for (int i = 0; i < 10; i++){
          int j = jq * 10 + i;
          if (j < cH){
            float F = tanh_(amr[j] + haWa[j]);
            part += wbs[j] * F;
          }
        }
        part += __shfl_xor(part, 1);
        part += __shfl_xor(part, 2);
        part += __shfl_xor(part, 4);
        part += __shfl_xor(part, 8);
        if (jq == 0) beta[t] = part;
      }
    }
    __syncthreads();

    float x = (tid < cLP) ? beta[tid] : -1e30f;
    float mx = x;
    #pragma unroll
    for (int off = 32; off; off >>= 1) mx = fmaxf(mx, __shfl_xor(mx, off));
    if ((tid & 63) == 0) red[tid >> 6] = mx;
    __syncthreads();
    if (tid == 0){
      float m2 = red[0];
      for (int w = 1; w < 10; w++) m2 = fmaxf(m2, red[w]);
      red[16] = m2;
    }
    __syncthreads();
    mx = red[16];
    float e = (tid < cLP) ? exp2_((x - mx) * 1.44269504f) : 0.f;
    float sm = e;
    #pragma unroll
    for (int off = 32; off; off >>= 1) sm += __shfl_xor(sm, off);
    if ((tid & 63) == 0) red[tid >> 6] = sm;
    __syncthreads();
    if (tid == 0){
      float s2 = 0.f;
      for (int w = 0; w < 10; w++) s2 += red[w];
      red[17] = s2;
    }
    __syncthreads();
    float bsum = red[17];
    if (tid < cLP){
      float bt = e * rcp_(bsum);
      beta[tid] = bt;
      out[(size_t)it * cLP * cB + (size_t)tid * cB + b] = bt;
    }
    __syncthreads();

    if (tid < 2 * cH){
      float acc = 0.f;
      for (int t = 0; t < cLP; t++)
        acc += beta[t] * Hr[((size_t)t * cB + b) * (2 * cH) + tid];
      wHr[tid] = acc;
    }
    __syncthreads();

    if (tid < cG){
      float acc = apb[tid];
      const float* r1 = apWih + (size_t)tid * (2 * cH);
      for (int i = 0; i < 2 * cH; i++) acc += wHr[i] * r1[i];
      const float* r2 = apWhh + (size_t)tid * cH;
      for (int i = 0; i < cH; i++) acc += ha[i] * r2[i];
      gl[tid] = acc;
    }
    __syncthreads();
    if (tid < cH){
      float ig = sigm(gl[tid]);
      float fg = sigm(gl[cH + tid]);
      float gg = tanh_(gl[2 * cH + tid]);
      float og = sigm(gl[3 * cH + tid]);
      float c2 = fg * ca[tid] + ig * gg;
      ca[tid] = c2;
      ha[tid] = og * tanh_(c2);
    }
    __syncthreads();
  }
}

// ---------------------------------------------------------------------------
extern "C" void kernel_launch(void* const* d_in, const int* in_sizes, int n_in,
                              void* d_out, int out_size, void* d_ws, size_t ws_size,
                              hipStream_t stream)
{
  (void)in_sizes; (void)n_in; (void)out_size; (void)ws_size;
  const int*   p_ids = (const int*)d_in[0];
  const int*   q_ids = (const int*)d_in[1];
  const int*   plens = (const int*)d_in[2];
  const int*   qlens = (const int*)d_in[3];
  const float* emb   = (const float*)d_in[4];
  const float* pWih  = (const float*)d_in[5];
  const float* pWhh  = (const float*)d_in[6];
  const float* pb    = (const float*)d_in[7];
  const float* Wq    = (const float*)d_in[8];
  const float* Wp    = (const float*)d_in[9];
  const float* bp    = (const float*)d_in[10];
  const float* Wr    = (const float*)d_in[11];
  const float* wa    = (const float*)d_in[12];
  const float* mfWih = (const float*)d_in[14];
  const float* mfWhh = (const float*)d_in[15];
  const float* mfb   = (const float*)d_in[16];
  const float* mbWih = (const float*)d_in[17];
  const float* mbWhh = (const float*)d_in[18];
  const float* mbb   = (const float*)d_in[19];
  const float* Vm    = (const float*)d_in[20];
  const float* Waa   = (const float*)d_in[21];
  const float* baa   = (const float*)d_in[22];
  const float* wb    = (const float*)d_in[23];
  const float* apWih = (const float*)d_in[25];
  const float* apWhh = (const float*)d_in[26];
  const float* apb   = (const float*)d_in[27];
  float* out = (float*)d_out;

  // workspace layout (floats); total 22,560,000 f = 90.24 MB
  float* ws  = (float*)d_ws;
  float* XGp = ws;                       // [400*32][600] f32 (later aliased XAf)
  float* XGq = ws + 7680000;             // [50*32][600]  f32 (later aliased QW)
  f16*   XAb = (f16*)(ws + 8640000);     // [400*32][600] f16
  float* Hp  = ws + 12480000;            // [400*32][150]
  float* Hq  = ws + 14400000;            // [50*32][150]
  float* aqb = ws + 14640000;            // [50*32][150]
  float* ppb = ws + 14880000;            // [400*32][150]
  float* Hr  = ws + 16800000;            // [400*32][300]
  float* am  = ws + 20640000;            // [400*32][150]
  f16*   XAf = (f16*)XGp;                // alias: XGp dead after enc_k
  f16*   QWf = (f16*)XGq;                // alias: XGq dead after enc_k
  f16*   QWb = QWf + (size_t)1600 * 600;

  dim3 blk(256);
  gemm_k<<<dim3(10,200), blk, 0, stream>>>(nullptr, p_ids, emb, pWih, 300, pb,
                                           XGp, nullptr, 12800, 600, 300);
  gemm_k<<<dim3(10, 25), blk, 0, stream>>>(nullptr, q_ids, emb, pWih, 300, pb,
                                           XGq, nullptr, 1600, 600, 300);
  enc_k<<<64, 640, 0, stream>>>(XGp, XGq, pWhh, plens, qlens, Hp, Hq);
  gemm_k<<<dim3(3,200), blk, 0, stream>>>(Hp, nullptr, nullptr, Wp, 150, bp,
                                          ppb, nullptr, 12800, 150, 150);
  gemm_k<<<dim3(3, 25), blk, 0, stream>>>(Hq, nullptr, nullptr, Wq, 150, nullptr,
                                          aqb, nullptr, 1600, 150, 150);
  gemm_k<<<dim3(10,200), blk, 0, stream>>>(Hp, nullptr, nullptr, mfWih, 300, nullptr,
                                           nullptr, XAf, 12800, 600, 150);
  gemm_k<<<dim3(10,200), blk, 0, stream>>>(Hp, nullptr, nullptr, mbWih, 300, nullptr,
                                           nullptr, XAb, 12800, 600, 150);
  gemm_k<<<dim3(10, 25), blk, 0, stream>>>(Hq, nullptr, nullptr, mfWih + 150, 300, nullptr,
                                           nullptr, QWf, 1600, 600, 150);
  gemm_k<<<dim3(10, 25), blk, 0, stream>>>(Hq, nullptr, nullptr, mbWih + 150, 300, nullptr,
                                           nullptr, QWb, 1600, 600, 150);
  match_k<<<64, 640, 0, stream>>>(XAf, XAb, QWf, QWb, aqb, ppb, mfWhh, mbWhh,
                                  mfb, mbb, Wr, wa, plens, Hr);
  gemm_k<<<dim3(3,200), blk, 0, stream>>>(Hr, nullptr, nullptr, Vm, 300, nullptr,
                                          am, nullptr, 12800, 150, 300);
  ptr_k<<<32, 640, 0, stream>>>(am, Hr, Waa, baa, wb, apWih, apWhh, apb, out);
}

// Round 10
// 2698.126 us; speedup vs baseline: 1.1306x; 1.1122x over previous
//
#include <hip/hip_runtime.h>

// MatchLSTM forward pipeline for MI355X.
// R10: stop fighting the RA's 84-VGPR budget — restructure the recurrent
// matvecs so the per-thread weight arrays FIT: Whh pairs 0..39 in registers
// (40 u32), pairs 40..74 in LDS WhhL[35][600] (84 KB, [p][r] layout =
// conflict-free consecutive-lane reads). Per-thread arrays now 65 u32
// (40 W + 25 QW) <= budget. LDS is legitimately >80 KB (used, not DCE-able)
// -> 1 WG/CU, which may also raise the RA budget to ~170.

typedef _Float16 f16;
typedef f16 f16x2 __attribute__((ext_vector_type(2)));
typedef unsigned int u32;
typedef unsigned short u16;

constexpr int cLP = 400, cLQ = 50, cB = 32, cH = 150, cG = 600;

__device__ __forceinline__ float exp2_(float x){
#if __has_builtin(__builtin_amdgcn_exp2f)
  return __builtin_amdgcn_exp2f(x);
#else
  return exp2f(x);
#endif
}
__device__ __forceinline__ float rcp_(float x){
#if __has_builtin(__builtin_amdgcn_rcpf)
  return __builtin_amdgcn_rcpf(x);
#else
  return 1.0f / x;
#endif
}
__device__ __forceinline__ float sigm(float x){ return rcp_(1.f + exp2_(-1.44269504f * x)); }
__device__ __forceinline__ float tanh_(float x){ return 1.f - 2.f * rcp_(1.f + exp2_(2.88539008f * x)); }

union U2 { u32 u; f16x2 h; };

__device__ __forceinline__ float fdot2_(u32 a, u32 b, float c){
  U2 ua, ub; ua.u = a; ub.u = b;
#if __has_builtin(__builtin_amdgcn_fdot2)
  return __builtin_amdgcn_fdot2(ua.h, ub.h, c, false);
#else
  return c + (float)ua.h[0] * (float)ub.h[0] + (float)ua.h[1] * (float)ub.h[1];
#endif
}
__device__ __forceinline__ u32 pack2(float x, float y){
  U2 p; p.h[0] = (f16)x; p.h[1] = (f16)y; return p.u;
}
__device__ __forceinline__ float2 unp2(u32 v){
  U2 p; p.u = v; return make_float2((float)p.h[0], (float)p.h[1]);
}

// load 4 f16x2 pairs (8 floats) from a weight row at pair offset 4*i
__device__ __forceinline__ uint4 ldw4(const float* __restrict__ wr, int i){
  uint4 r;
  r.x = pack2(wr[8*i+0], wr[8*i+1]);
  r.y = pack2(wr[8*i+2], wr[8*i+3]);
  r.z = pack2(wr[8*i+4], wr[8*i+5]);
  r.w = pack2(wr[8*i+6], wr[8*i+7]);
  return r;
}

// opaque barrier: values become asm outputs -> cannot be rematerialized
#define PIN4(v) asm volatile("" : "+v"(v.x), "+v"(v.y), "+v"(v.z), "+v"(v.w));
#define PIN4W(i) PIN4(w##i)
#define PIN4Q(i) PIN4(q##i)

#define REP10(M) M(0) M(1) M(2) M(3) M(4) M(5) M(6) M(7) M(8) M(9)
#define REP6(M) M(0) M(1) M(2) M(3) M(4) M(5)

// ---------------------------------------------------------------------------
// Generic f32 GEMM: C[M][N] = A[M][K] @ W[N][K]^T (+bias). Optional embedding
// gather for A rows. Optional f16 output. Tile 64x64, 4x4/thread, 256 thr.
// ---------------------------------------------------------------------------
__global__ __launch_bounds__(256)
void gemm_k(const float* __restrict__ A, const int* __restrict__ ids,
            const float* __restrict__ emb,
            const float* __restrict__ W, int ldw, const float* __restrict__ bias,
            float* __restrict__ Cf, f16* __restrict__ Ch,
            int M, int N, int K)
{
  __shared__ __align__(16) float As[16][68];
  __shared__ __align__(16) float Wt[16][68];
  __shared__ int sids[64];
  int tid = threadIdx.x;
  int n0 = blockIdx.x * 64;
  int m0 = blockIdx.y * 64;
  int tx = tid & 15, ty = tid >> 4;
  if (ids){ if (tid < 64) sids[tid] = ids[m0 + tid]; }
  __syncthreads();

  float acc[4][4] = {};
  int sm = tid >> 2;
  int kq = (tid & 3) << 2;
  const float* arow = ids ? (emb + (size_t)sids[sm] * K)
                          : (A   + (size_t)(m0 + sm) * K);
  const float* wrow = W + (size_t)(n0 + sm) * ldw;
  bool nok = (n0 + sm) < N;

  for (int k0 = 0; k0 < K; k0 += 16){
    #pragma unroll
    for (int p = 0; p < 4; p++){
      int kk = kq + p, k = k0 + kk;
      As[kk][sm] = (k < K) ? arow[k] : 0.f;
      Wt[kk][sm] = (nok && k < K) ? wrow[k] : 0.f;
    }
    __syncthreads();
    #pragma unroll
    for (int kk = 0; kk < 16; kk++){
      float4 av = *(const float4*)&As[kk][ty << 2];
      float4 wv = *(const float4*)&Wt[kk][tx << 2];
      float a[4] = {av.x, av.y, av.z, av.w};
      float w[4] = {wv.x, wv.y, wv.z, wv.w};
      #pragma unroll
      for (int i = 0; i < 4; i++)
        #pragma unroll
        for (int j = 0; j < 4; j++)
          acc[i][j] += a[i] * w[j];
    }
    __syncthreads();
  }
  float bj[4];
  #pragma unroll
  for (int j = 0; j < 4; j++){
    int n = n0 + (tx << 2) + j;
    bj[j] = (bias && n < N) ? bias[n] : 0.f;
  }
  #pragma unroll
  for (int i = 0; i < 4; i++){
    int m = m0 + (ty << 2) + i;
    #pragma unroll
    for (int j = 0; j < 4; j++){
      int n = n0 + (tx << 2) + j;
      if (n < N){
        size_t ci = (size_t)m * N + n;
        float v = acc[i][j] + bj[j];
        if (Ch) Ch[ci] = (f16)v; else Cf[ci] = v;
      }
    }
  }
}

// ---------------------------------------------------------------------------
// Encoder LSTM. 64 WGs: wg<32 -> passage b, else question b. 640 threads.
// Whh pairs 0..39 in registers, pairs 40..74 in LDS ([p][r] layout).
// ---------------------------------------------------------------------------
__attribute__((amdgpu_waves_per_eu(1, 3)))
__global__ __launch_bounds__(640)
void enc_k(const float* __restrict__ XGp, const float* __restrict__ XGq,
           const float* __restrict__ Whh,
           const int* __restrict__ plens, const int* __restrict__ qlens,
           float* __restrict__ Hp, float* __restrict__ Hq)
{
  int wg = blockIdx.x;
  bool isq = wg >= cB;
  int b = wg & (cB - 1);
  const float* XG = isq ? XGq : XGp;
  float* Hout = isq ? Hq : Hp;
  int T   = isq ? cLQ : cLP;
  int len = (isq ? qlens : plens)[b];
  int tid = threadIdx.x;

  __shared__ u32 WhhL[35 * 600];        // pairs 40..74, [p][r]: 84 KB
  __shared__ float c[cH], gl[cG];
  __shared__ __align__(16) u32 h2s[80];

#define DECLW(i) uint4 w##i;
  REP10(DECLW)
#undef DECLW
  {
    const float* wr = Whh + (size_t)(tid < cG ? tid : 0) * cH;
#define LOADW(i) w##i = ldw4(wr, i);
    REP10(LOADW)
#undef LOADW
    REP10(PIN4W)
  }
  for (int idx = tid; idx < 35 * 600; idx += 640){
    int r = idx / 35, p = idx % 35;
    const float* wrow = Whh + (size_t)r * cH;
    WhhL[p * 600 + r] = pack2(wrow[80 + 2 * p], wrow[81 + 2 * p]);
  }
  if (tid < cH) c[tid] = 0.f;
  if (tid < 80) h2s[tid] = 0;
  __syncthreads();

  float xgCur = 0.f;
  if (tid < cG) xgCur = XG[(size_t)b * cG + tid];

  for (int t = 0; t < T; t++){
    int tn = (t + 1 < T) ? t + 1 : t;
    float xgN = 0.f;
    if (tid < cG) xgN = XG[((size_t)tn * cB + b) * cG + tid];

    if (tid < cG){
      float aA = 0.f, aB = 0.f, aC = 0.f, aD = 0.f;
#define DOTW(i) { uint4 hq = *(const uint4*)&h2s[4*(i)]; \
      aA = fdot2_(hq.x, w##i.x, aA); aB = fdot2_(hq.y, w##i.y, aB); \
      aC = fdot2_(hq.z, w##i.z, aC); aD = fdot2_(hq.w, w##i.w, aD); }
      REP10(DOTW)
#undef DOTW
      #pragma unroll
      for (int jj = 0; jj < 8; jj++){
        uint4 hq = *(const uint4*)&h2s[40 + 4 * jj];
        aA = fdot2_(hq.x, WhhL[(4*jj+0)*600 + tid], aA);
        aB = fdot2_(hq.y, WhhL[(4*jj+1)*600 + tid], aB);
        aC = fdot2_(hq.z, WhhL[(4*jj+2)*600 + tid], aC);
        aD = fdot2_(hq.w, WhhL[(4*jj+3)*600 + tid], aD);
      }
      {
        uint4 hq = *(const uint4*)&h2s[72];
        aA = fdot2_(hq.x, WhhL[32*600 + tid], aA);
        aB = fdot2_(hq.y, WhhL[33*600 + tid], aB);
        aC = fdot2_(hq.z, WhhL[34*600 + tid], aC);
      }
      gl[tid] = xgCur + ((aA + aB) + (aC + aD));
    }
    __syncthreads();
    if (tid < 75){
      float hv[2];
      #pragma unroll
      for (int z = 0; z < 2; z++){
        int u = 2 * tid + z;
        float ig = sigm(gl[u]);
        float fg = sigm(gl[cH + u]);
        float gg = tanh_(gl[2 * cH + u]);
        float og = sigm(gl[3 * cH + u]);
        float c2 = fg * c[u] + ig * gg;
        float hh = og * tanh_(c2);
        c[u] = c2;
        hv[z] = hh;
      }
      h2s[tid] = pack2(hv[0], hv[1]);      // unmasked h carries the recurrence
      float mk = (t < len) ? 1.f : 0.f;
      float2 st; st.x = hv[0] * mk; st.y = hv[1] * mk;
      *(float2*)&Hout[((size_t)t * cB + b) * cH + 2 * tid] = st;
    }
    __syncthreads();
    xgCur = xgN;
  }
}

// ---------------------------------------------------------------------------
// Match-LSTM, fwd + bwd. 64 WGs = dir(2) x batch(32), 640 threads.
// 5-phase structure; Whh split regs(40 pairs)+LDS(35 pairs); QW (25 pairs)
// in registers; aq + wa in LDS; XA/pp prefetched one step ahead.
// ---------------------------------------------------------------------------
__attribute__((amdgpu_waves_per_eu(1, 3)))
__global__ __launch_bounds__(640)
void match_k(const f16* __restrict__ XAf, const f16* __restrict__ XAb,
             const f16* __restrict__ QWf, const f16* __restrict__ QWb,
             const float* __restrict__ aq, const float* __restrict__ pp,
             const float* __restrict__ mfWhh, const float* __restrict__ mbWhh,
             const float* __restrict__ mfb, const float* __restrict__ mbb,
             const float* __restrict__ Wr, const float* __restrict__ wa,
             const int* __restrict__ plens, float* __restrict__ Hr)
{
  constexpr int NPAD = 160;
  constexpr int AQS  = 81;
  int wg = blockIdx.x;
  int dir = wg >> 5;
  int b = wg & 31;
  const f16* XA = dir ? XAb : XAf;
  const f16* QW = dir ? QWb : QWf;
  const float* Whh = dir ? mbWhh : mfWhh;
  const float* bm  = dir ? mbb   : mfb;
  int len = plens[b];
  int tid = threadIdx.x;

  __shared__ u32 WhhL[35 * 600];        // Whh pairs 40..74, [p][r]: 84 KB
  __shared__ u32 WrT2[76 * 150];        // [pair p][j], f16x2-packed Wr^T
  __shared__ u32 aq2[cLQ * AQS];        // [l][jp] f16x2 pairs of aq (zero-pad)
  __shared__ float gl[cG];
  __shared__ float sc[NPAD];            // pp_t + h@Wr^T (zero-padded)
  __shared__ float waS[NPAD];
  __shared__ float c[cH];
  __shared__ __align__(16) u32 h2s[80];
  __shared__ float loge[64];
  __shared__ __align__(16) u32 alpha2[28];

  // ---- one-time loads ----
#define DECLW(i) uint4 w##i;
  REP10(DECLW)
#undef DECLW
  float bk = 0.f;
  {
    const float* wr = Whh + (size_t)(tid < cG ? tid : 0) * cH;
#define LOADW(i) w##i = ldw4(wr, i);
    REP10(LOADW)
#undef LOADW
    REP10(PIN4W)
    if (tid < cG) bk = bm[tid];
  }
#define DECLQ(i) uint4 q##i;
  REP6(DECLQ)
#undef DECLQ
  u32 q24s;
  {
    const u16* QWu = (const u16*)QW;
    int row = (tid < cG) ? tid : 0;
    // pair p holds (alpha_{2p}, alpha_{2p+1}) weights: QW[l][b][row]
#define QP(p) ((u32)QWu[((size_t)(2*(p)) * cB + b) * cG + row] | \
               ((u32)QWu[((size_t)(2*(p)+1) * cB + b) * cG + row] << 16))
#define LOADQ(i) q##i.x = QP(4*(i)+0); q##i.y = QP(4*(i)+1); \
                 q##i.z = QP(4*(i)+2); q##i.w = QP(4*(i)+3);
    LOADQ(0) LOADQ(1) LOADQ(2) LOADQ(3) LOADQ(4) LOADQ(5)
    q24s = QP(24);
#undef LOADQ
#undef QP
    REP6(PIN4Q)
    asm volatile("" : "+v"(q24s));
  }
  for (int idx = tid; idx < 35 * 600; idx += 640){
    int r = idx / 35, p = idx % 35;
    const float* wrow = Whh + (size_t)r * cH;
    WhhL[p * 600 + r] = pack2(wrow[80 + 2 * p], wrow[81 + 2 * p]);
  }
  for (int idx = tid; idx < cLQ * AQS; idx += 640){
    int l = idx / AQS, jp = idx % AQS;
    u32 v = 0;
    if (jp < 75){
      const float* ap = aq + ((size_t)l * cB + b) * cH;
      v = pack2(ap[2 * jp], ap[2 * jp + 1]);
    }
    aq2[idx] = v;
  }
  for (int i = tid; i < NPAD; i += 640) waS[i] = (i < cH) ? wa[i] : 0.f;
  for (int idx = tid; idx < 76 * 150; idx += 640){
    int p = idx / 150, k2 = idx % 150;
    WrT2[idx] = (p < 75) ? pack2(Wr[(size_t)k2 * cH + 2 * p],
                                 Wr[(size_t)k2 * cH + 2 * p + 1]) : 0u;
  }
  if (tid < cH) c[tid] = 0.f;
  if (tid < 80) h2s[tid] = 0;
  if (tid >= cH && tid < NPAD) sc[tid] = 0.f;
  if (tid >= 25 && tid < 28) alpha2[tid] = 0;
  __syncthreads();

  // prologue prefetch for step 0
  f16 xaCurH = (f16)0.f, xaNxtH = (f16)0.f;
  float ppCur = 0.f, ppNxt = 0.f;
  {
    int t0 = dir ? (cLP - 1) : 0;
    if (tid < cG) xaCurH = XA[((size_t)t0 * cB + b) * cG + tid];
    if (tid < cH) ppCur = pp[((size_t)t0 * cB + b) * cH + tid];
  }

  for (int s = 0; s < cLP; s++){
    int tt = dir ? (cLP - 1 - s) : s;
    float mk = (tt < len) ? 1.f : 0.f;

    // prefetch step s+1 (consumed next iteration)
    {
      int sn = (s + 1 < cLP) ? s + 1 : s;
      int tn = dir ? (cLP - 1 - sn) : sn;
      if (tid < cG) xaNxtH = XA[((size_t)tn * cB + b) * cG + tid];
      if (tid < cH) ppNxt = pp[((size_t)tn * cB + b) * cH + tid];
    }

    // A: sc = h@Wr^T + pp[tt]   (150 threads, conflict-free WrT2 reads)
    if (tid < cH){
      float sA = 0.f, sB = 0.f, sC = 0.f, sD = 0.f;
      #pragma unroll
      for (int i = 0; i < 19; i++){
        uint4 hq = *(const uint4*)&h2s[4 * i];
        sA = fdot2_(hq.x, WrT2[(4*i+0)*150 + tid], sA);
        sB = fdot2_(hq.y, WrT2[(4*i+1)*150 + tid], sB);
        sC = fdot2_(hq.z, WrT2[(4*i+2)*150 + tid], sC);
        sD = fdot2_(hq.w, WrT2[(4*i+3)*150 + tid], sD);
      }
      sc[tid] = ((sA + sB) + (sC + sD)) + ppCur;
    }
    __syncthreads();

    // B: attention logits; 8 lanes/l, 20-wide even-aligned j-chunks.
    if (tid < 400){
      int l = tid >> 3, q = tid & 7;
      const u32* arow = &aq2[l * AQS + q * 10];
      float part = 0.f;
      #pragma unroll
      for (int p = 0; p < 10; p++){
        int j = q * 20 + 2 * p;
        float2 av = unp2(arow[p]);
        float x0 = av.x + sc[j];
        float x1 = av.y + sc[j + 1];
        float r0 = rcp_(1.f + exp2_(2.88539008f * x0));
        float r1 = rcp_(1.f + exp2_(2.88539008f * x1));
        part += waS[j] * r0 + waS[j + 1] * r1;
      }
      part += __shfl_xor(part, 1);
      part += __shfl_xor(part, 2);
      part += __shfl_xor(part, 4);
      if (q == 0) loge[l] = part;
    }
    __syncthreads();

    // C: softmax over 50 on wave 0, f16-packed alpha pairs
    if (tid < 64){
      float lg = (tid < cLQ) ? (-2.f * loge[tid]) : -1e30f;
      float mx = lg;
      #pragma unroll
      for (int off = 32; off; off >>= 1) mx = fmaxf(mx, __shfl_xor(mx, off));
      float e = (tid < cLQ) ? exp2_((lg - mx) * 1.44269504f) : 0.f;
      float sum = e;
      #pragma unroll
      for (int off = 32; off; off >>= 1) sum += __shfl_xor(sum, off);
      float al = e * rcp_(sum);
      float alhi = __shfl_down(al, 1);
      if (tid < cLQ && !(tid & 1)) alpha2[tid >> 1] = pack2(al, alhi);
    }
    __syncthreads();

    // D: gl = b + h@Whh^T + mk*(XA + alpha@QW)
    if (tid < cG){
      float aA = 0.f, aB = 0.f, aC = 0.f, aD = 0.f;
#define DOTW(i) { uint4 hq = *(const uint4*)&h2s[4*(i)]; \
      aA = fdot2_(hq.x, w##i.x, aA); aB = fdot2_(hq.y, w##i.y, aB); \
      aC = fdot2_(hq.z, w##i.z, aC); aD = fdot2_(hq.w, w##i.w, aD); }
      REP10(DOTW)
#undef DOTW
      #pragma unroll
      for (int jj = 0; jj < 8; jj++){
        uint4 hq = *(const uint4*)&h2s[40 + 4 * jj];
        aA = fdot2_(hq.x, WhhL[(4*jj+0)*600 + tid], aA);
        aB = fdot2_(hq.y, WhhL[(4*jj+1)*600 + tid], aB);
        aC = fdot2_(hq.z, WhhL[(4*jj+2)*600 + tid], aC);
        aD = fdot2_(hq.w, WhhL[(4*jj+3)*600 + tid], aD);
      }
      {
        uint4 hq = *(const uint4*)&h2s[72];
        aA = fdot2_(hq.x, WhhL[32*600 + tid], aA);
        aB = fdot2_(hq.y, WhhL[33*600 + tid], aB);
        aC = fdot2_(hq.z, WhhL[34*600 + tid], aC);
      }
      float qA = 0.f, qB = 0.f;
#define DOTQ(i) { uint4 a4 = *(const uint4*)&alpha2[4*(i)]; \
      qA = fdot2_(a4.x, q##i.x, qA); qB = fdot2_(a4.y, q##i.y, qB); \
      qA = fdot2_(a4.z, q##i.z, qA); qB = fdot2_(a4.w, q##i.w, qB); }
      REP6(DOTQ)
#undef DOTQ
      qA = fdot2_(alpha2[24], q24s, qA);
      float acc = ((aA + aB) + (aC + aD));
      gl[tid] = bk + acc + mk * ((float)xaCurH + (qA + qB));
    }
    __syncthreads();

    // E: LSTM cell; h2,c2 masked inside recurrence (ref semantics)
    if (tid < 75){
      float hv[2];
      #pragma unroll
      for (int z = 0; z < 2; z++){
        int u = 2 * tid + z;
        float ig = sigm(gl[u]);
        float fg = sigm(gl[cH + u]);
        float gg = tanh_(gl[2 * cH + u]);
        float og = sigm(gl[3 * cH + u]);
        float c2 = (fg * c[u] + ig * gg) * mk;
        float hh = og * tanh_(c2) * mk;
        c[u] = c2;
        hv[z] = hh;
      }
      h2s[tid] = pack2(hv[0], hv[1]);
      float2 st; st.x = hv[0]; st.y = hv[1];
      *(float2*)&Hr[((size_t)tt * cB + b) * (2 * cH) + dir * cH + 2 * tid] = st;
    }
    __syncthreads();

    xaCurH = xaNxtH;
    ppCur  = ppNxt;
  }
}

// ---------------------------------------------------------------------------
// Answer pointer: 32 WGs (one per batch), 2 sequential iterations.
// ---------------------------------------------------------------------------
__global__ __launch_bounds__(640)
void ptr_k(const float* __restrict__ am, const float* __restrict__ Hr,
           const float* __restrict__ Wa, const float* __restrict__ baa,
           const float* __restrict__ wb,
           const float* __restrict__ apWih, const float* __restrict__ apWhh,
             const float* __restrict__ apb, float* __restrict__ out)
{
  int b = blockIdx.x, tid = threadIdx.x;
  __shared__ float ha[cH], ca[cH], haWa[160], wbs[160];
  __shared__ float beta[cLP], wHr[2 * cH], gl[cG], red[20];
  if (tid < cH){ ha[tid] = 0.f; ca[tid] = 0.f; }
  if (tid < 160) wbs[tid] = (tid < cH) ? wb[tid] : 0.f;
  __syncthreads();

  for (int it = 0; it < 2; ++it){
    if (tid < cH){
      float acc = baa[tid];
      const float* wr = Wa + (size_t)tid * cH;
      for (int i = 0; i < cH; i++) acc += ha[i] * wr[i];
      haWa[tid] = acc;
    } else if (tid < 160) haWa[tid] = 0.f;
    __syncthreads();

    {
      int tt = tid >> 4;
      int jq = tid & 15;
      for (int t0 = 0; t0 < cLP; t0 += 40){
        int t = t0 + tt;
        float part = 0.f;
        const float* amr = am + ((size_t)t * cB + b) * cH;
        #pragma unroll
        for (int i = 0; i < 10; i++){
          int j = jq * 10 + i;
          if (j < cH){
            float F = tanh_(amr[j] + haWa[j]);
            part += wbs[j] * F;
          }
        }
        part += __shfl_xor(part, 1);
        part += __shfl_xor(part, 2);
        part += __shfl_xor(part, 4);
        part += __shfl_xor(part, 8);
        if (jq == 0) beta[t] = part;
      }
    }
    __syncthreads();

    float x = (tid < cLP) ? beta[tid] : -1e30f;
    float mx = x;
    #pragma unroll
    for (int off = 32; off; off >>= 1) mx = fmaxf(mx, __shfl_xor(mx, off));
    if ((tid & 63) == 0) red[tid >> 6] = mx;
    __syncthreads();
    if (tid == 0){
      float m2 = red[0];
      for (int w = 1; w < 10; w++) m2 = fmaxf(m2, red[w]);
      red[16] = m2;
    }
    __syncthreads();
    mx = red[16];
    float e = (tid < cLP) ? exp2_((x - mx) * 1.44269504f) : 0.f;
    float sm = e;
    #pragma unroll
    for (int off = 32; off; off >>= 1) sm += __shfl_xor(sm, off);
    if ((tid & 63) == 0) red[tid >> 6] = sm;
    __syncthreads();
    if (tid == 0){
      float s2 = 0.f;
      for (int w = 0; w < 10; w++) s2 += red[w];
      red[17] = s2;
    }
    __syncthreads();
    float bsum = red[17];
    if (tid < cLP){
      float bt = e * rcp_(bsum);
      beta[tid] = bt;
      out[(size_t)it * cLP * cB + (size_t)tid * cB + b] = bt;
    }
    __syncthreads();

    if (tid < 2 * cH){
      float acc = 0.f;
      for (int t = 0; t < cLP; t++)
        acc += beta[t] * Hr[((size_t)t * cB + b) * (2 * cH) + tid];
      wHr[tid] = acc;
    }
    __syncthreads();

    if (tid < cG){
      float acc = apb[tid];
      const float* r1 = apWih + (size_t)tid * (2 * cH);
      for (int i = 0; i < 2 * cH; i++) acc += wHr[i] * r1[i];
      const float* r2 = apWhh + (size_t)tid * cH;
      for (int i = 0; i < cH; i++) acc += ha[i] * r2[i];
      gl[tid] = acc;
    }
    __syncthreads();
    if (tid < cH){
      float ig = sigm(gl[tid]);
      float fg = sigm(gl[cH + tid]);
      float gg = tanh_(gl[2 * cH + tid]);
      float og = sigm(gl[3 * cH + tid]);
      float c2 = fg * ca[tid] + ig * gg;
      ca[tid] = c2;
      ha[tid] = og * tanh_(c2);
    }
    __syncthreads();
  }
}

// ---------------------------------------------------------------------------
extern "C" void kernel_launch(void* const* d_in, const int* in_sizes, int n_in,
                              void* d_out, int out_size, void* d_ws, size_t ws_size,
                              hipStream_t stream)
{
  (void)in_sizes; (void)n_in; (void)out_size; (void)ws_size;
  const int*   p_ids = (const int*)d_in[0];
  const int*   q_ids = (const int*)d_in[1];
  const int*   plens = (const int*)d_in[2];
  const int*   qlens = (const int*)d_in[3];
  const float* emb   = (const float*)d_in[4];
  const float* pWih  = (const float*)d_in[5];
  const float* pWhh  = (const float*)d_in[6];
  const float* pb    = (const float*)d_in[7];
  const float* Wq    = (const float*)d_in[8];
  const float* Wp    = (const float*)d_in[9];
  const float* bp    = (const float*)d_in[10];
  const float* Wr    = (const float*)d_in[11];
  const float* wa    = (const float*)d_in[12];
  const float* mfWih = (const float*)d_in[14];
  const float* mfWhh = (const float*)d_in[15];
  const float* mfb   = (const float*)d_in[16];
  const float* mbWih = (const float*)d_in[17];
  const float* mbWhh = (const float*)d_in[18];
  const float* mbb   = (const float*)d_in[19];
  const float* Vm    = (const float*)d_in[20];
  const float* Waa   = (const float*)d_in[21];
  const float* baa   = (const float*)d_in[22];
  const float* wb    = (const float*)d_in[23];
  const float* apWih = (const float*)d_in[25];
  const float* apWhh = (const float*)d_in[26];
  const float* apb   = (const float*)d_in[27];
  float* out = (float*)d_out;

  // workspace layout (floats); total 22,560,000 f = 90.24 MB
  float* ws  = (float*)d_ws;
  float* XGp = ws;                       // [400*32][600] f32 (later aliased XAf)
  float* XGq = ws + 7680000;             // [50*32][600]  f32 (later aliased QW)
  f16*   XAb = (f16*)(ws + 8640000);     // [400*32][600] f16
  float* Hp  = ws + 12480000;            // [400*32][150]
  float* Hq  = ws + 14400000;            // [50*32][150]
  float* aqb = ws + 14640000;            // [50*32][150]
  float* ppb = ws + 14880000;            // [400*32][150]
  float* Hr  = ws + 16800000;            // [400*32][300]
  float* am  = ws + 20640000;            // [400*32][150]
  f16*   XAf = (f16*)XGp;                // alias: XGp dead after enc_k
  f16*   QWf = (f16*)XGq;                // alias: XGq dead after enc_k
  f16*   QWb = QWf + (size_t)1600 * 600;

  dim3 blk(256);
  gemm_k<<<dim3(10,200), blk, 0, stream>>>(nullptr, p_ids, emb, pWih, 300, pb,
                                           XGp, nullptr, 12800, 600, 300);
  gemm_k<<<dim3(10, 25), blk, 0, stream>>>(nullptr, q_ids, emb, pWih, 300, pb,
                                           XGq, nullptr, 1600, 600, 300);
  enc_k<<<64, 640, 0, stream>>>(XGp, XGq, pWhh, plens, qlens, Hp, Hq);
  gemm_k<<<dim3(3,200), blk, 0, stream>>>(Hp, nullptr, nullptr, Wp, 150, bp,
                                          ppb, nullptr, 12800, 150, 150);
  gemm_k<<<dim3(3, 25), blk, 0, stream>>>(Hq, nullptr, nullptr, Wq, 150, nullptr,
                                          aqb, nullptr, 1600, 150, 150);
  gemm_k<<<dim3(10,200), blk, 0, stream>>>(Hp, nullptr, nullptr, mfWih, 300, nullptr,
                                           nullptr, XAf, 12800, 600, 150);
  gemm_k<<<dim3(10,200), blk, 0, stream>>>(Hp, nullptr, nullptr, mbWih, 300, nullptr,
                                           nullptr, XAb, 12800, 600, 150);
  gemm_k<<<dim3(10, 25), blk, 0, stream>>>(Hq, nullptr, nullptr, mfWih + 150, 300, nullptr,
                                           nullptr, QWf, 1600, 600, 150);
  gemm_k<<<dim3(10, 25), blk, 0, stream>>>(Hq, nullptr, nullptr, mbWih + 150, 300, nullptr,
                                           nullptr, QWb, 1600, 600, 150);
  match_k<<<64, 640, 0, stream>>>(XAf, XAb, QWf, QWb, aqb, ppb, mfWhh, mbWhh,
                                  mfb, mbb, Wr, wa, plens, Hr);
  gemm_k<<<dim3(3,200), blk, 0, stream>>>(Hr, nullptr, nullptr, Vm, 300, nullptr,
                                          am, nullptr, 12800, 150, 300);
  ptr_k<<<32, 640, 0, stream>>>(am, Hr, Waa, baa, wb, apWih, apWhh, apb, out);
}

// Round 11
// 2307.867 us; speedup vs baseline: 1.3217x; 1.1691x over previous
//
#include <hip/hip_runtime.h>

// MatchLSTM forward pipeline for MI355X.
// R11: the recurrent kernels are LDS-instruction-throughput-bound (~50+35+76
// ds_read_b32 per wave per step ~= the whole 3.78us step on the one LDS pipe).
// Vectorize every hot LDS stream to b128: WrT4[19][150] uint4, WhhL4[9][600]
// uint4, phase-B sc/waS as float4 and aq via aligned 12-slot chunks.

typedef _Float16 f16;
typedef f16 f16x2 __attribute__((ext_vector_type(2)));
typedef unsigned int u32;
typedef unsigned short u16;

constexpr int cLP = 400, cLQ = 50, cB = 32, cH = 150, cG = 600;

__device__ __forceinline__ float exp2_(float x){
#if __has_builtin(__builtin_amdgcn_exp2f)
  return __builtin_amdgcn_exp2f(x);
#else
  return exp2f(x);
#endif
}
__device__ __forceinline__ float rcp_(float x){
#if __has_builtin(__builtin_amdgcn_rcpf)
  return __builtin_amdgcn_rcpf(x);
#else
  return 1.0f / x;
#endif
}
__device__ __forceinline__ float sigm(float x){ return rcp_(1.f + exp2_(-1.44269504f * x)); }
__device__ __forceinline__ float tanh_(float x){ return 1.f - 2.f * rcp_(1.f + exp2_(2.88539008f * x)); }

union U2 { u32 u; f16x2 h; };

__device__ __forceinline__ float fdot2_(u32 a, u32 b, float c){
  U2 ua, ub; ua.u = a; ub.u = b;
#if __has_builtin(__builtin_amdgcn_fdot2)
  return __builtin_amdgcn_fdot2(ua.h, ub.h, c, false);
#else
  return c + (float)ua.h[0] * (float)ub.h[0] + (float)ua.h[1] * (float)ub.h[1];
#endif
}
__device__ __forceinline__ u32 pack2(float x, float y){
  U2 p; p.h[0] = (f16)x; p.h[1] = (f16)y; return p.u;
}
__device__ __forceinline__ float2 unp2(u32 v){
  U2 p; p.u = v; return make_float2((float)p.h[0], (float)p.h[1]);
}

// load 4 f16x2 pairs (8 floats) from a weight row at float offset 8*i
__device__ __forceinline__ uint4 ldw4(const float* __restrict__ wr, int i){
  uint4 r;
  r.x = pack2(wr[8*i+0], wr[8*i+1]);
  r.y = pack2(wr[8*i+2], wr[8*i+3]);
  r.z = pack2(wr[8*i+4], wr[8*i+5]);
  r.w = pack2(wr[8*i+6], wr[8*i+7]);
  return r;
}

// opaque barrier: values become asm outputs -> cannot be rematerialized
#define PIN4(v) asm volatile("" : "+v"(v.x), "+v"(v.y), "+v"(v.z), "+v"(v.w));
#define PIN4W(i) PIN4(w##i)
#define PIN4Q(i) PIN4(q##i)

#define REP10(M) M(0) M(1) M(2) M(3) M(4) M(5) M(6) M(7) M(8) M(9)
#define REP6(M) M(0) M(1) M(2) M(3) M(4) M(5)

// ---------------------------------------------------------------------------
// Generic f32 GEMM (unchanged).
// ---------------------------------------------------------------------------
__global__ __launch_bounds__(256)
void gemm_k(const float* __restrict__ A, const int* __restrict__ ids,
            const float* __restrict__ emb,
            const float* __restrict__ W, int ldw, const float* __restrict__ bias,
            float* __restrict__ Cf, f16* __restrict__ Ch,
            int M, int N, int K)
{
  __shared__ __align__(16) float As[16][68];
  __shared__ __align__(16) float Wt[16][68];
  __shared__ int sids[64];
  int tid = threadIdx.x;
  int n0 = blockIdx.x * 64;
  int m0 = blockIdx.y * 64;
  int tx = tid & 15, ty = tid >> 4;
  if (ids){ if (tid < 64) sids[tid] = ids[m0 + tid]; }
  __syncthreads();

  float acc[4][4] = {};
  int sm = tid >> 2;
  int kq = (tid & 3) << 2;
  const float* arow = ids ? (emb + (size_t)sids[sm] * K)
                          : (A   + (size_t)(m0 + sm) * K);
  const float* wrow = W + (size_t)(n0 + sm) * ldw;
  bool nok = (n0 + sm) < N;

  for (int k0 = 0; k0 < K; k0 += 16){
    #pragma unroll
    for (int p = 0; p < 4; p++){
      int kk = kq + p, k = k0 + kk;
      As[kk][sm] = (k < K) ? arow[k] : 0.f;
      Wt[kk][sm] = (nok && k < K) ? wrow[k] : 0.f;
    }
    __syncthreads();
    #pragma unroll
    for (int kk = 0; kk < 16; kk++){
      float4 av = *(const float4*)&As[kk][ty << 2];
      float4 wv = *(const float4*)&Wt[kk][tx << 2];
      float a[4] = {av.x, av.y, av.z, av.w};
      float w[4] = {wv.x, wv.y, wv.z, wv.w};
      #pragma unroll
      for (int i = 0; i < 4; i++)
        #pragma unroll
        for (int j = 0; j < 4; j++)
          acc[i][j] += a[i] * w[j];
    }
    __syncthreads();
  }
  float bj[4];
  #pragma unroll
  for (int j = 0; j < 4; j++){
    int n = n0 + (tx << 2) + j;
    bj[j] = (bias && n < N) ? bias[n] : 0.f;
  }
  #pragma unroll
  for (int i = 0; i < 4; i++){
    int m = m0 + (ty << 2) + i;
    #pragma unroll
    for (int j = 0; j < 4; j++){
      int n = n0 + (tx << 2) + j;
      if (n < N){
        size_t ci = (size_t)m * N + n;
        float v = acc[i][j] + bj[j];
        if (Ch) Ch[ci] = (f16)v; else Cf[ci] = v;
      }
    }
  }
}

// ---------------------------------------------------------------------------
// Encoder LSTM. Whh pairs 0..39 in regs, pairs 40..75 in LDS uint4 [9][600].
// ---------------------------------------------------------------------------
__attribute__((amdgpu_waves_per_eu(1, 3)))
__global__ __launch_bounds__(640)
void enc_k(const float* __restrict__ XGp, const float* __restrict__ XGq,
           const float* __restrict__ Whh,
           const int* __restrict__ plens, const int* __restrict__ qlens,
           float* __restrict__ Hp, float* __restrict__ Hq)
{
  int wg = blockIdx.x;
  bool isq = wg >= cB;
  int b = wg & (cB - 1);
  const float* XG = isq ? XGq : XGp;
  float* Hout = isq ? Hq : Hp;
  int T   = isq ? cLQ : cLP;
  int len = (isq ? qlens : plens)[b];
  int tid = threadIdx.x;

  __shared__ __align__(16) u32 WhhL4[9 * 600 * 4];  // pairs 40..75, uint4 [p4][r]
  __shared__ float c[cH], gl[cG];
  __shared__ __align__(16) u32 h2s[80];

#define DECLW(i) uint4 w##i;
  REP10(DECLW)
#undef DECLW
  {
    const float* wr = Whh + (size_t)(tid < cG ? tid : 0) * cH;
#define LOADW(i) w##i = ldw4(wr, i);
    REP10(LOADW)
#undef LOADW
    REP10(PIN4W)
  }
  for (int idx = tid; idx < 9 * 600; idx += 640){
    int p4 = idx / 600, r = idx % 600;
    const float* wrow = Whh + (size_t)r * cH + 80;
    uint4 v;
    if (p4 < 8) v = ldw4(wrow, p4);
    else {
      v.x = pack2(wrow[64], wrow[65]);
      v.y = pack2(wrow[66], wrow[67]);
      v.z = pack2(wrow[68], wrow[69]);
      v.w = 0;
    }
    *(uint4*)&WhhL4[idx * 4] = v;
  }
  if (tid < cH) c[tid] = 0.f;
  if (tid < 80) h2s[tid] = 0;
  __syncthreads();

  float xgCur = 0.f;
  if (tid < cG) xgCur = XG[(size_t)b * cG + tid];

  for (int t = 0; t < T; t++){
    int tn = (t + 1 < T) ? t + 1 : t;
    float xgN = 0.f;
    if (tid < cG) xgN = XG[((size_t)tn * cB + b) * cG + tid];

    if (tid < cG){
      float aA = 0.f, aB = 0.f, aC = 0.f, aD = 0.f;
#define DOTW(i) { uint4 hq = *(const uint4*)&h2s[4*(i)]; \
      aA = fdot2_(hq.x, w##i.x, aA); aB = fdot2_(hq.y, w##i.y, aB); \
      aC = fdot2_(hq.z, w##i.z, aC); aD = fdot2_(hq.w, w##i.w, aD); }
      REP10(DOTW)
#undef DOTW
      #pragma unroll
      for (int p4 = 0; p4 < 9; p4++){
        uint4 hq = *(const uint4*)&h2s[40 + 4 * p4];
        uint4 wv = *(const uint4*)&WhhL4[(p4 * 600 + tid) * 4];
        aA = fdot2_(hq.x, wv.x, aA);
        aB = fdot2_(hq.y, wv.y, aB);
        aC = fdot2_(hq.z, wv.z, aC);
        aD = fdot2_(hq.w, wv.w, aD);
      }
      gl[tid] = xgCur + ((aA + aB) + (aC + aD));
    }
    __syncthreads();
    if (tid < 75){
      float hv[2];
      #pragma unroll
      for (int z = 0; z < 2; z++){
        int u = 2 * tid + z;
        float ig = sigm(gl[u]);
        float fg = sigm(gl[cH + u]);
        float gg = tanh_(gl[2 * cH + u]);
        float og = sigm(gl[3 * cH + u]);
        float c2 = fg * c[u] + ig * gg;
        float hh = og * tanh_(c2);
        c[u] = c2;
        hv[z] = hh;
      }
      h2s[tid] = pack2(hv[0], hv[1]);      // unmasked h carries the recurrence
      float mk = (t < len) ? 1.f : 0.f;
      float2 st; st.x = hv[0] * mk; st.y = hv[1] * mk;
      *(float2*)&Hout[((size_t)t * cB + b) * cH + 2 * tid] = st;
    }
    __syncthreads();
    xgCur = xgN;
  }
}

// ---------------------------------------------------------------------------
// Match-LSTM, fwd + bwd. 64 WGs = dir(2) x batch(32), 640 threads.
// All hot LDS streams b128-vectorized. Whh split regs(40 pairs)+LDS(36);
// QW (25 pairs) in regs; aq in 12-slot aligned chunks; XA/pp prefetched.
// ---------------------------------------------------------------------------
__attribute__((amdgpu_waves_per_eu(1, 3)))
__global__ __launch_bounds__(640)
void match_k(const f16* __restrict__ XAf, const f16* __restrict__ XAb,
             const f16* __restrict__ QWf, const f16* __restrict__ QWb,
             const float* __restrict__ aq, const float* __restrict__ pp,
             const float* __restrict__ mfWhh, const float* __restrict__ mbWhh,
             const float* __restrict__ mfb, const float* __restrict__ mbb,
             const float* __restrict__ Wr, const float* __restrict__ wa,
             const int* __restrict__ plens, float* __restrict__ Hr)
{
  constexpr int NPAD = 160;
  int wg = blockIdx.x;
  int dir = wg >> 5;
  int b = wg & 31;
  const f16* XA = dir ? XAb : XAf;
  const f16* QW = dir ? QWb : QWf;
  const float* Whh = dir ? mbWhh : mfWhh;
  const float* bm  = dir ? mbb   : mfb;
  int len = plens[b];
  int tid = threadIdx.x;

  __shared__ __align__(16) u32 WhhL4[9 * 600 * 4];   // 86.4 KB
  __shared__ __align__(16) u32 WrT4[19 * 150 * 4];   // 45.6 KB
  __shared__ __align__(16) u32 aq3[cLQ * 96];        // 19.2 KB, [l][8 chunks x 12]
  __shared__ float gl[cG];
  __shared__ __align__(16) float sc[NPAD];           // zero-padded
  __shared__ __align__(16) float waS[NPAD];
  __shared__ float c[cH];
  __shared__ __align__(16) u32 h2s[80];
  __shared__ float loge[64];
  __shared__ __align__(16) u32 alpha2[28];

  // ---- one-time loads ----
#define DECLW(i) uint4 w##i;
  REP10(DECLW)
#undef DECLW
  float bk = 0.f;
  {
    const float* wr = Whh + (size_t)(tid < cG ? tid : 0) * cH;
#define LOADW(i) w##i = ldw4(wr, i);
    REP10(LOADW)
#undef LOADW
    REP10(PIN4W)
    if (tid < cG) bk = bm[tid];
  }
#define DECLQ(i) uint4 q##i;
  REP6(DECLQ)
#undef DECLQ
  u32 q24s;
  {
    const u16* QWu = (const u16*)QW;
    int row = (tid < cG) ? tid : 0;
#define QP(p) ((u32)QWu[((size_t)(2*(p)) * cB + b) * cG + row] | \
               ((u32)QWu[((size_t)(2*(p)+1) * cB + b) * cG + row] << 16))
#define LOADQ(i) q##i.x = QP(4*(i)+0); q##i.y = QP(4*(i)+1); \
                 q##i.z = QP(4*(i)+2); q##i.w = QP(4*(i)+3);
    LOADQ(0) LOADQ(1) LOADQ(2) LOADQ(3) LOADQ(4) LOADQ(5)
    q24s = QP(24);
#undef LOADQ
#undef QP
    REP6(PIN4Q)
    asm volatile("" : "+v"(q24s));
  }
  for (int idx = tid; idx < 9 * 600; idx += 640){
    int p4 = idx / 600, r = idx % 600;
    const float* wrow = Whh + (size_t)r * cH + 80;
    uint4 v;
    if (p4 < 8) v = ldw4(wrow, p4);
    else {
      v.x = pack2(wrow[64], wrow[65]);
      v.y = pack2(wrow[66], wrow[67]);
      v.z = pack2(wrow[68], wrow[69]);
      v.w = 0;
    }
    *(uint4*)&WhhL4[idx * 4] = v;
  }
  for (int idx = tid; idx < 19 * 150; idx += 640){
    int i = idx / 150, j = idx % 150;
    const float* wrow = Wr + (size_t)j * cH;
    uint4 v;
    if (i < 18) v = ldw4(wrow, i);
    else {
      v.x = pack2(wrow[144], wrow[145]);
      v.y = pack2(wrow[146], wrow[147]);
      v.z = pack2(wrow[148], wrow[149]);
      v.w = 0;
    }
    *(uint4*)&WrT4[idx * 4] = v;
  }
  for (int idx = tid; idx < cLQ * 96; idx += 640){
    int l = idx / 96, s = idx % 96;
    int ch = s / 12, t = s % 12;
    u32 v = 0;
    if (t < 10){
      int p = ch * 10 + t;
      if (p < 75){
        const float* ap = aq + ((size_t)l * cB + b) * cH;
        v = pack2(ap[2 * p], ap[2 * p + 1]);
      }
    }
    aq3[idx] = v;
  }
  for (int i = tid; i < NPAD; i += 640) waS[i] = (i < cH) ? wa[i] : 0.f;
  if (tid < cH) c[tid] = 0.f;
  if (tid < 80) h2s[tid] = 0;
  if (tid >= cH && tid < NPAD) sc[tid] = 0.f;
  if (tid >= 25 && tid < 28) alpha2[tid] = 0;
  __syncthreads();

  // prologue prefetch for step 0
  f16 xaCurH = (f16)0.f, xaNxtH = (f16)0.f;
  float ppCur = 0.f, ppNxt = 0.f;
  {
    int t0 = dir ? (cLP - 1) : 0;
    if (tid < cG) xaCurH = XA[((size_t)t0 * cB + b) * cG + tid];
    if (tid < cH) ppCur = pp[((size_t)t0 * cB + b) * cH + tid];
  }

  for (int s = 0; s < cLP; s++){
    int tt = dir ? (cLP - 1 - s) : s;
    float mk = (tt < len) ? 1.f : 0.f;

    // prefetch step s+1 (consumed next iteration)
    {
      int sn = (s + 1 < cLP) ? s + 1 : s;
      int tn = dir ? (cLP - 1 - sn) : sn;
      if (tid < cG) xaNxtH = XA[((size_t)tn * cB + b) * cG + tid];
      if (tid < cH) ppNxt = pp[((size_t)tn * cB + b) * cH + tid];
    }

    // A: sc = h@Wr^T + pp[tt]   (150 threads, 19 b128 reads)
    if (tid < cH){
      float sA = 0.f, sB = 0.f, sC = 0.f, sD = 0.f;
      #pragma unroll
      for (int i = 0; i < 19; i++){
        uint4 hq = *(const uint4*)&h2s[4 * i];
        uint4 wv = *(const uint4*)&WrT4[(i * 150 + tid) * 4];
        sA = fdot2_(hq.x, wv.x, sA);
        sB = fdot2_(hq.y, wv.y, sB);
        sC = fdot2_(hq.z, wv.z, sC);
        sD = fdot2_(hq.w, wv.w, sD);
      }
      sc[tid] = ((sA + sB) + (sC + sD)) + ppCur;
    }
    __syncthreads();

    // B: attention logits; 8 lanes/l, 20-wide j-chunks, vector loads.
    if (tid < 400){
      int l = tid >> 3, q = tid & 7;
      const u32* ab = aq3 + l * 96 + q * 12;
      uint4 A0 = *(const uint4*)(ab);
      uint4 A1 = *(const uint4*)(ab + 4);
      uint2 A2 = *(const uint2*)(ab + 8);
      u32 aqp[10] = {A0.x, A0.y, A0.z, A0.w, A1.x, A1.y, A1.z, A1.w, A2.x, A2.y};
      const float4* scv = (const float4*)(sc  + 20 * q);
      const float4* wav = (const float4*)(waS + 20 * q);
      float p0 = 0.f, p1 = 0.f;
      #pragma unroll
      for (int i = 0; i < 5; i++){
        float4 sv = scv[i];
        float4 wv = wav[i];
        float2 a0 = unp2(aqp[2 * i]);
        float2 a1 = unp2(aqp[2 * i + 1]);
        p0 += wv.x * rcp_(1.f + exp2_(2.88539008f * (a0.x + sv.x)));
        p1 += wv.y * rcp_(1.f + exp2_(2.88539008f * (a0.y + sv.y)));
        p0 += wv.z * rcp_(1.f + exp2_(2.88539008f * (a1.x + sv.z)));
        p1 += wv.w * rcp_(1.f + exp2_(2.88539008f * (a1.y + sv.w)));
      }
      float part = p0 + p1;
      part += __shfl_xor(part, 1);
      part += __shfl_xor(part, 2);
      part += __shfl_xor(part, 4);
      if (q == 0) loge[l] = part;
    }
    __syncthreads();

    // C: softmax over 50 on wave 0, f16-packed alpha pairs
    if (tid < 64){
      float lg = (tid < cLQ) ? (-2.f * loge[tid]) : -1e30f;
      float mx = lg;
      #pragma unroll
      for (int off = 32; off; off >>= 1) mx = fmaxf(mx, __shfl_xor(mx, off));
      float e = (tid < cLQ) ? exp2_((lg - mx) * 1.44269504f) : 0.f;
      float sum = e;
      #pragma unroll
      for (int off = 32; off; off >>= 1) sum += __shfl_xor(sum, off);
      float al = e * rcp_(sum);
      float alhi = __shfl_down(al, 1);
      if (tid < cLQ && !(tid & 1)) alpha2[tid >> 1] = pack2(al, alhi);
    }
    __syncthreads();

    // D: gl = b + h@Whh^T + mk*(XA + alpha@QW)
    if (tid < cG){
      float aA = 0.f, aB = 0.f, aC = 0.f, aD = 0.f;
#define DOTW(i) { uint4 hq = *(const uint4*)&h2s[4*(i)]; \
      aA = fdot2_(hq.x, w##i.x, aA); aB = fdot2_(hq.y, w##i.y, aB); \
      aC = fdot2_(hq.z, w##i.z, aC); aD = fdot2_(hq.w, w##i.w, aD); }
      REP10(DOTW)
#undef DOTW
      #pragma unroll
      for (int p4 = 0; p4 < 9; p4++){
        uint4 hq = *(const uint4*)&h2s[40 + 4 * p4];
        uint4 wv = *(const uint4*)&WhhL4[(p4 * 600 + tid) * 4];
        aA = fdot2_(hq.x, wv.x, aA);
        aB = fdot2_(hq.y, wv.y, aB);
        aC = fdot2_(hq.z, wv.z, aC);
        aD = fdot2_(hq.w, wv.w, aD);
      }
      float qA = 0.f, qB = 0.f;
#define DOTQ(i) { uint4 a4 = *(const uint4*)&alpha2[4*(i)]; \
      qA = fdot2_(a4.x, q##i.x, qA); qB = fdot2_(a4.y, q##i.y, qB); \
      qA = fdot2_(a4.z, q##i.z, qA); qB = fdot2_(a4.w, q##i.w, qB); }
      REP6(DOTQ)
#undef DOTQ
      qA = fdot2_(alpha2[24], q24s, qA);
      float acc = ((aA + aB) + (aC + aD));
      gl[tid] = bk + acc + mk * ((float)xaCurH + (qA + qB));
    }
    __syncthreads();

    // E: LSTM cell; h2,c2 masked inside recurrence (ref semantics)
    if (tid < 75){
      float hv[2];
      #pragma unroll
      for (int z = 0; z < 2; z++){
        int u = 2 * tid + z;
        float ig = sigm(gl[u]);
        float fg = sigm(gl[cH + u]);
        float gg = tanh_(gl[2 * cH + u]);
        float og = sigm(gl[3 * cH + u]);
        float c2 = (fg * c[u] + ig * gg) * mk;
        float hh = og * tanh_(c2) * mk;
        c[u] = c2;
        hv[z] = hh;
      }
      h2s[tid] = pack2(hv[0], hv[1]);
      float2 st; st.x = hv[0]; st.y = hv[1];
      *(float2*)&Hr[((size_t)tt * cB + b) * (2 * cH) + dir * cH + 2 * tid] = st;
    }
    __syncthreads();

    xaCurH = xaNxtH;
    ppCur  = ppNxt;
  }
}

// ---------------------------------------------------------------------------
// Answer pointer: 32 WGs (one per batch), 2 sequential iterations.
// ---------------------------------------------------------------------------
__global__ __launch_bounds__(640)
void ptr_k(const float* __restrict__ am, const float* __restrict__ Hr,
           const float* __restrict__ Wa, const float* __restrict__ baa,
           const float* __restrict__ wb,
           const float* __restrict__ apWih, const float* __restrict__ apWhh,
             const float* __restrict__ apb, float* __restrict__ out)
{
  int b = blockIdx.x, tid = threadIdx.x;
  __shared__ float ha[cH], ca[cH], haWa[160], wbs[160];
  __shared__ float beta[cLP], wHr[2 * cH], gl[cG], red[20];
  if (tid < cH){ ha[tid] = 0.f; ca[tid] = 0.f; }
  if (tid < 160) wbs[tid] = (tid < cH) ? wb[tid] : 0.f;
  __syncthreads();

  for (int it = 0; it < 2; ++it){
    if (tid < cH){
      float acc = baa[tid];
      const float* wr = Wa + (size_t)tid * cH;
      for (int i = 0; i < cH; i++) acc += ha[i] * wr[i];
      haWa[tid] = acc;
    } else if (tid < 160) haWa[tid] = 0.f;
    __syncthreads();

    {
      int tt = tid >> 4;
      int jq = tid & 15;
      for (int t0 = 0; t0 < cLP; t0 += 40){
        int t = t0 + tt;
        float part = 0.f;
        const float* amr = am + ((size_t)t * cB + b) * cH;
        #pragma unroll
        for (int i = 0; i < 10; i++){
          int j = jq * 10 + i;
          if (j < cH){
            float F = tanh_(amr[j] + haWa[j]);
            part += wbs[j] * F;
          }
        }
        part += __shfl_xor(part, 1);
        part += __shfl_xor(part, 2);
        part += __shfl_xor(part, 4);
        part += __shfl_xor(part, 8);
        if (jq == 0) beta[t] = part;
      }
    }
    __syncthreads();

    float x = (tid < cLP) ? beta[tid] : -1e30f;
    float mx = x;
    #pragma unroll
    for (int off = 32; off; off >>= 1) mx = fmaxf(mx, __shfl_xor(mx, off));
    if ((tid & 63) == 0) red[tid >> 6] = mx;
    __syncthreads();
    if (tid == 0){
      float m2 = red[0];
      for (int w = 1; w < 10; w++) m2 = fmaxf(m2, red[w]);
      red[16] = m2;
    }
    __syncthreads();
    mx = red[16];
    float e = (tid < cLP) ? exp2_((x - mx) * 1.44269504f) : 0.f;
    float sm = e;
    #pragma unroll
    for (int off = 32; off; off >>= 1) sm += __shfl_xor(sm, off);
    if ((tid & 63) == 0) red[tid >> 6] = sm;
    __syncthreads();
    if (tid == 0){
      float s2 = 0.f;
      for (int w = 0; w < 10; w++) s2 += red[w];
      red[17] = s2;
    }
    __syncthreads();
    float bsum = red[17];
    if (tid < cLP){
      float bt = e * rcp_(bsum);
      beta[tid] = bt;
      out[(size_t)it * cLP * cB + (size_t)tid * cB + b] = bt;
    }
    __syncthreads();

    if (tid < 2 * cH){
      float acc = 0.f;
      for (int t = 0; t < cLP; t++)
        acc += beta[t] * Hr[((size_t)t * cB + b) * (2 * cH) + tid];
      wHr[tid] = acc;
    }
    __syncthreads();

    if (tid < cG){
      float acc = apb[tid];
      const float* r1 = apWih + (size_t)tid * (2 * cH);
      for (int i = 0; i < 2 * cH; i++) acc += wHr[i] * r1[i];
      const float* r2 = apWhh + (size_t)tid * cH;
      for (int i = 0; i < cH; i++) acc += ha[i] * r2[i];
      gl[tid] = acc;
    }
    __syncthreads();
    if (tid < cH){
      float ig = sigm(gl[tid]);
      float fg = sigm(gl[cH + tid]);
      float gg = tanh_(gl[2 * cH + tid]);
      float og = sigm(gl[3 * cH + tid]);
      float c2 = fg * ca[tid] + ig * gg;
      ca[tid] = c2;
      ha[tid] = og * tanh_(c2);
    }
    __syncthreads();
  }
}

// ---------------------------------------------------------------------------
extern "C" void kernel_launch(void* const* d_in, const int* in_sizes, int n_in,
                              void* d_out, int out_size, void* d_ws, size_t ws_size,
                              hipStream_t stream)
{
  (void)in_sizes; (void)n_in; (void)out_size; (void)ws_size;
  const int*   p_ids = (const int*)d_in[0];
  const int*   q_ids = (const int*)d_in[1];
  const int*   plens = (const int*)d_in[2];
  const int*   qlens = (const int*)d_in[3];
  const float* emb   = (const float*)d_in[4];
  const float* pWih  = (const float*)d_in[5];
  const float* pWhh  = (const float*)d_in[6];
  const float* pb    = (const float*)d_in[7];
  const float* Wq    = (const float*)d_in[8];
  const float* Wp    = (const float*)d_in[9];
  const float* bp    = (const float*)d_in[10];
  const float* Wr    = (const float*)d_in[11];
  const float* wa    = (const float*)d_in[12];
  const float* mfWih = (const float*)d_in[14];
  const float* mfWhh = (const float*)d_in[15];
  const float* mfb   = (const float*)d_in[16];
  const float* mbWih = (const float*)d_in[17];
  const float* mbWhh = (const float*)d_in[18];
  const float* mbb   = (const float*)d_in[19];
  const float* Vm    = (const float*)d_in[20];
  const float* Waa   = (const float*)d_in[21];
  const float* baa   = (const float*)d_in[22];
  const float* wb    = (const float*)d_in[23];
  const float* apWih = (const float*)d_in[25];
  const float* apWhh = (const float*)d_in[26];
  const float* apb   = (const float*)d_in[27];
  float* out = (float*)d_out;

  // workspace layout (floats); total 22,560,000 f = 90.24 MB
  float* ws  = (float*)d_ws;
  float* XGp = ws;                       // [400*32][600] f32 (later aliased XAf)
  float* XGq = ws + 7680000;             // [50*32][600]  f32 (later aliased QW)
  f16*   XAb = (f16*)(ws + 8640000);     // [400*32][600] f16
  float* Hp  = ws + 12480000;            // [400*32][150]
  float* Hq  = ws + 14400000;            // [50*32][150]
  float* aqb = ws + 14640000;            // [50*32][150]
  float* ppb = ws + 14880000;            // [400*32][150]
  float* Hr  = ws + 16800000;            // [400*32][300]
  float* am  = ws + 20640000;            // [400*32][150]
  f16*   XAf = (f16*)XGp;                // alias: XGp dead after enc_k
  f16*   QWf = (f16*)XGq;                // alias: XGq dead after enc_k
  f16*   QWb = QWf + (size_t)1600 * 600;

  dim3 blk(256);
  gemm_k<<<dim3(10,200), blk, 0, stream>>>(nullptr, p_ids, emb, pWih, 300, pb,
                                           XGp, nullptr, 12800, 600, 300);
  gemm_k<<<dim3(10, 25), blk, 0, stream>>>(nullptr, q_ids, emb, pWih, 300, pb,
                                           XGq, nullptr, 1600, 600, 300);
  enc_k<<<64, 640, 0, stream>>>(XGp, XGq, pWhh, plens, qlens, Hp, Hq);
  gemm_k<<<dim3(3,200), blk, 0, stream>>>(Hp, nullptr, nullptr, Wp, 150, bp,
                                          ppb, nullptr, 12800, 150, 150);
  gemm_k<<<dim3(3, 25), blk, 0, stream>>>(Hq, nullptr, nullptr, Wq, 150, nullptr,
                                          aqb, nullptr, 1600, 150, 150);
  gemm_k<<<dim3(10,200), blk, 0, stream>>>(Hp, nullptr, nullptr, mfWih, 300, nullptr,
                                           nullptr, XAf, 12800, 600, 150);
  gemm_k<<<dim3(10,200), blk, 0, stream>>>(Hp, nullptr, nullptr, mbWih, 300, nullptr,
                                           nullptr, XAb, 12800, 600, 150);
  gemm_k<<<dim3(10, 25), blk, 0, stream>>>(Hq, nullptr, nullptr, mfWih + 150, 300, nullptr,
                                           nullptr, QWf, 1600, 600, 150);
  gemm_k<<<dim3(10, 25), blk, 0, stream>>>(Hq, nullptr, nullptr, mbWih + 150, 300, nullptr,
                                           nullptr, QWb, 1600, 600, 150);
  match_k<<<64, 640, 0, stream>>>(XAf, XAb, QWf, QWb, aqb, ppb, mfWhh, mbWhh,
                                  mfb, mbb, Wr, wa, plens, Hr);
  gemm_k<<<dim3(3,200), blk, 0, stream>>>(Hr, nullptr, nullptr, Vm, 300, nullptr,
                                          am, nullptr, 12800, 150, 300);
  ptr_k<<<32, 640, 0, stream>>>(am, Hr, Waa, baa, wb, apWih, apWhh, apb, out);
}

// Round 12
// 2237.848 us; speedup vs baseline: 1.3631x; 1.0313x over previous
//
#include <hip/hip_runtime.h>

// MatchLSTM forward pipeline for MI355X.
// R12: overlap LDS weight-streaming with transcendental work. Phase B now
// computes gates_pre (WhhL4 streaming) fused with attention logits (trans
// pipe) in one barrier-phase; sc uses 600 threads (4/column + shfl); cell
// uses 150 threads. Same 5-barrier skeleton, fatter overlapping phases.

typedef _Float16 f16;
typedef f16 f16x2 __attribute__((ext_vector_type(2)));
typedef unsigned int u32;
typedef unsigned short u16;

constexpr int cLP = 400, cLQ = 50, cB = 32, cH = 150, cG = 600;

__device__ __forceinline__ float exp2_(float x){
#if __has_builtin(__builtin_amdgcn_exp2f)
  return __builtin_amdgcn_exp2f(x);
#else
  return exp2f(x);
#endif
}
__device__ __forceinline__ float rcp_(float x){
#if __has_builtin(__builtin_amdgcn_rcpf)
  return __builtin_amdgcn_rcpf(x);
#else
  return 1.0f / x;
#endif
}
__device__ __forceinline__ float sigm(float x){ return rcp_(1.f + exp2_(-1.44269504f * x)); }
__device__ __forceinline__ float tanh_(float x){ return 1.f - 2.f * rcp_(1.f + exp2_(2.88539008f * x)); }

union U2 { u32 u; f16x2 h; };

__device__ __forceinline__ float fdot2_(u32 a, u32 b, float c){
  U2 ua, ub; ua.u = a; ub.u = b;
#if __has_builtin(__builtin_amdgcn_fdot2)
  return __builtin_amdgcn_fdot2(ua.h, ub.h, c, false);
#else
  return c + (float)ua.h[0] * (float)ub.h[0] + (float)ua.h[1] * (float)ub.h[1];
#endif
}
__device__ __forceinline__ u32 pack2(float x, float y){
  U2 p; p.h[0] = (f16)x; p.h[1] = (f16)y; return p.u;
}
__device__ __forceinline__ float2 unp2(u32 v){
  U2 p; p.u = v; return make_float2((float)p.h[0], (float)p.h[1]);
}

// load 4 f16x2 pairs (8 floats) from a weight row at float offset 8*i
__device__ __forceinline__ uint4 ldw4(const float* __restrict__ wr, int i){
  uint4 r;
  r.x = pack2(wr[8*i+0], wr[8*i+1]);
  r.y = pack2(wr[8*i+2], wr[8*i+3]);
  r.z = pack2(wr[8*i+4], wr[8*i+5]);
  r.w = pack2(wr[8*i+6], wr[8*i+7]);
  return r;
}

// opaque barrier: values become asm outputs -> cannot be rematerialized
#define PIN4(v) asm volatile("" : "+v"(v.x), "+v"(v.y), "+v"(v.z), "+v"(v.w));
#define PIN4W(i) PIN4(w##i)
#define PIN4Q(i) PIN4(q##i)

#define REP10(M) M(0) M(1) M(2) M(3) M(4) M(5) M(6) M(7) M(8) M(9)
#define REP6(M) M(0) M(1) M(2) M(3) M(4) M(5)

// ---------------------------------------------------------------------------
// Generic f32 GEMM (unchanged).
// ---------------------------------------------------------------------------
__global__ __launch_bounds__(256)
void gemm_k(const float* __restrict__ A, const int* __restrict__ ids,
            const float* __restrict__ emb,
            const float* __restrict__ W, int ldw, const float* __restrict__ bias,
            float* __restrict__ Cf, f16* __restrict__ Ch,
            int M, int N, int K)
{
  __shared__ __align__(16) float As[16][68];
  __shared__ __align__(16) float Wt[16][68];
  __shared__ int sids[64];
  int tid = threadIdx.x;
  int n0 = blockIdx.x * 64;
  int m0 = blockIdx.y * 64;
  int tx = tid & 15, ty = tid >> 4;
  if (ids){ if (tid < 64) sids[tid] = ids[m0 + tid]; }
  __syncthreads();

  float acc[4][4] = {};
  int sm = tid >> 2;
  int kq = (tid & 3) << 2;
  const float* arow = ids ? (emb + (size_t)sids[sm] * K)
                          : (A   + (size_t)(m0 + sm) * K);
  const float* wrow = W + (size_t)(n0 + sm) * ldw;
  bool nok = (n0 + sm) < N;

  for (int k0 = 0; k0 < K; k0 += 16){
    #pragma unroll
    for (int p = 0; p < 4; p++){
      int kk = kq + p, k = k0 + kk;
      As[kk][sm] = (k < K) ? arow[k] : 0.f;
      Wt[kk][sm] = (nok && k < K) ? wrow[k] : 0.f;
    }
    __syncthreads();
    #pragma unroll
    for (int kk = 0; kk < 16; kk++){
      float4 av = *(const float4*)&As[kk][ty << 2];
      float4 wv = *(const float4*)&Wt[kk][tx << 2];
      float a[4] = {av.x, av.y, av.z, av.w};
      float w[4] = {wv.x, wv.y, wv.z, wv.w};
      #pragma unroll
      for (int i = 0; i < 4; i++)
        #pragma unroll
        for (int j = 0; j < 4; j++)
          acc[i][j] += a[i] * w[j];
    }
    __syncthreads();
  }
  float bj[4];
  #pragma unroll
  for (int j = 0; j < 4; j++){
    int n = n0 + (tx << 2) + j;
    bj[j] = (bias && n < N) ? bias[n] : 0.f;
  }
  #pragma unroll
  for (int i = 0; i < 4; i++){
    int m = m0 + (ty << 2) + i;
    #pragma unroll
    for (int j = 0; j < 4; j++){
      int n = n0 + (tx << 2) + j;
      if (n < N){
        size_t ci = (size_t)m * N + n;
        float v = acc[i][j] + bj[j];
        if (Ch) Ch[ci] = (f16)v; else Cf[ci] = v;
      }
    }
  }
}

// ---------------------------------------------------------------------------
// Encoder LSTM (R11 structure, unchanged).
// ---------------------------------------------------------------------------
__attribute__((amdgpu_waves_per_eu(1, 3)))
__global__ __launch_bounds__(640)
void enc_k(const float* __restrict__ XGp, const float* __restrict__ XGq,
           const float* __restrict__ Whh,
           const int* __restrict__ plens, const int* __restrict__ qlens,
           float* __restrict__ Hp, float* __restrict__ Hq)
{
  int wg = blockIdx.x;
  bool isq = wg >= cB;
  int b = wg & (cB - 1);
  const float* XG = isq ? XGq : XGp;
  float* Hout = isq ? Hq : Hp;
  int T   = isq ? cLQ : cLP;
  int len = (isq ? qlens : plens)[b];
  int tid = threadIdx.x;

  __shared__ __align__(16) u32 WhhL4[9 * 600 * 4];
  __shared__ float c[cH], gl[cG];
  __shared__ __align__(16) u32 h2s[80];

#define DECLW(i) uint4 w##i;
  REP10(DECLW)
#undef DECLW
  {
    const float* wr = Whh + (size_t)(tid < cG ? tid : 0) * cH;
#define LOADW(i) w##i = ldw4(wr, i);
    REP10(LOADW)
#undef LOADW
    REP10(PIN4W)
  }
  for (int idx = tid; idx < 9 * 600; idx += 640){
    int p4 = idx / 600, r = idx % 600;
    const float* wrow = Whh + (size_t)r * cH + 80;
    uint4 v;
    if (p4 < 8) v = ldw4(wrow, p4);
    else {
      v.x = pack2(wrow[64], wrow[65]);
      v.y = pack2(wrow[66], wrow[67]);
      v.z = pack2(wrow[68], wrow[69]);
      v.w = 0;
    }
    *(uint4*)&WhhL4[idx * 4] = v;
  }
  if (tid < cH) c[tid] = 0.f;
  if (tid < 80) h2s[tid] = 0;
  __syncthreads();

  float xgCur = 0.f;
  if (tid < cG) xgCur = XG[(size_t)b * cG + tid];

  for (int t = 0; t < T; t++){
    int tn = (t + 1 < T) ? t + 1 : t;
    float xgN = 0.f;
    if (tid < cG) xgN = XG[((size_t)tn * cB + b) * cG + tid];

    if (tid < cG){
      float aA = 0.f, aB = 0.f, aC = 0.f, aD = 0.f;
#define DOTW(i) { uint4 hq = *(const uint4*)&h2s[4*(i)]; \
      aA = fdot2_(hq.x, w##i.x, aA); aB = fdot2_(hq.y, w##i.y, aB); \
      aC = fdot2_(hq.z, w##i.z, aC); aD = fdot2_(hq.w, w##i.w, aD); }
      REP10(DOTW)
#undef DOTW
      #pragma unroll
      for (int p4 = 0; p4 < 9; p4++){
        uint4 hq = *(const uint4*)&h2s[40 + 4 * p4];
        uint4 wv = *(const uint4*)&WhhL4[(p4 * 600 + tid) * 4];
        aA = fdot2_(hq.x, wv.x, aA);
        aB = fdot2_(hq.y, wv.y, aB);
        aC = fdot2_(hq.z, wv.z, aC);
        aD = fdot2_(hq.w, wv.w, aD);
      }
      gl[tid] = xgCur + ((aA + aB) + (aC + aD));
    }
    __syncthreads();
    if (tid < 75){
      float hv[2];
      #pragma unroll
      for (int z = 0; z < 2; z++){
        int u = 2 * tid + z;
        float ig = sigm(gl[u]);
        float fg = sigm(gl[cH + u]);
        float gg = tanh_(gl[2 * cH + u]);
        float og = sigm(gl[3 * cH + u]);
        float c2 = fg * c[u] + ig * gg;
        float hh = og * tanh_(c2);
        c[u] = c2;
        hv[z] = hh;
      }
      h2s[tid] = pack2(hv[0], hv[1]);
      float mk = (t < len) ? 1.f : 0.f;
      float2 st; st.x = hv[0] * mk; st.y = hv[1] * mk;
      *(float2*)&Hout[((size_t)t * cB + b) * cH + 2 * tid] = st;
    }
    __syncthreads();
    xgCur = xgN;
  }
}

// ---------------------------------------------------------------------------
// Match-LSTM, fwd + bwd. 64 WGs = dir(2) x batch(32), 640 threads.
// P_A: sc 4-lane split (600 thr). P_B: gates_pre (600 thr, WhhL4 stream)
// FUSED with logits (400 thr, trans) -> pipes overlap. P_C: softmax.
// P_D: alpha-dots + gl finalize. P_E: cell on 150 thr.
// ---------------------------------------------------------------------------
__attribute__((amdgpu_waves_per_eu(1, 3)))
__global__ __launch_bounds__(640)
void match_k(const f16* __restrict__ XAf, const f16* __restrict__ XAb,
             const f16* __restrict__ QWf, const f16* __restrict__ QWb,
             const float* __restrict__ aq, const float* __restrict__ pp,
             const float* __restrict__ mfWhh, const float* __restrict__ mbWhh,
             const float* __restrict__ mfb, const float* __restrict__ mbb,
             const float* __restrict__ Wr, const float* __restrict__ wa,
             const int* __restrict__ plens, float* __restrict__ Hr)
{
  constexpr int NPAD = 160;
  int wg = blockIdx.x;
  int dir = wg >> 5;
  int b = wg & 31;
  const f16* XA = dir ? XAb : XAf;
  const f16* QW = dir ? QWb : QWf;
  const float* Whh = dir ? mbWhh : mfWhh;
  const float* bm  = dir ? mbb   : mfb;
  int len = plens[b];
  int tid = threadIdx.x;

  __shared__ __align__(16) u32 WhhL4[9 * 600 * 4];   // 86.4 KB
  __shared__ __align__(16) u32 WrT4[20 * 150 * 4];   // 48 KB (row 19 = zeros)
  __shared__ __align__(16) u32 aq3[cLQ * 96];        // 19.2 KB
  __shared__ float gl[cG];
  __shared__ __align__(16) float sc[NPAD];
  __shared__ __align__(16) float waS[NPAD];
  __shared__ float c[cH];
  __shared__ __align__(16) f16 hsf[160];             // h as raw f16
  __shared__ float loge[64];
  __shared__ __align__(16) u32 alpha2[28];

  // ---- one-time loads ----
#define DECLW(i) uint4 w##i;
  REP10(DECLW)
#undef DECLW
  float bk = 0.f;
  {
    const float* wr = Whh + (size_t)(tid < cG ? tid : 0) * cH;
#define LOADW(i) w##i = ldw4(wr, i);
    REP10(LOADW)
#undef LOADW
    REP10(PIN4W)
    if (tid < cG) bk = bm[tid];
  }
#define DECLQ(i) uint4 q##i;
  REP6(DECLQ)
#undef DECLQ
  u32 q24s;
  {
    const u16* QWu = (const u16*)QW;
    int row = (tid < cG) ? tid : 0;
#define QP(p) ((u32)QWu[((size_t)(2*(p)) * cB + b) * cG + row] | \
               ((u32)QWu[((size_t)(2*(p)+1) * cB + b) * cG + row] << 16))
#define LOADQ(i) q##i.x = QP(4*(i)+0); q##i.y = QP(4*(i)+1); \
                 q##i.z = QP(4*(i)+2); q##i.w = QP(4*(i)+3);
    LOADQ(0) LOADQ(1) LOADQ(2) LOADQ(3) LOADQ(4) LOADQ(5)
    q24s = QP(24);
#undef LOADQ
#undef QP
    REP6(PIN4Q)
    asm volatile("" : "+v"(q24s));
  }
  for (int idx = tid; idx < 9 * 600; idx += 640){
    int p4 = idx / 600, r = idx % 600;
    const float* wrow = Whh + (size_t)r * cH + 80;
    uint4 v;
    if (p4 < 8) v = ldw4(wrow, p4);
    else {
      v.x = pack2(wrow[64], wrow[65]);
      v.y = pack2(wrow[66], wrow[67]);
      v.z = pack2(wrow[68], wrow[69]);
      v.w = 0;
    }
    *(uint4*)&WhhL4[idx * 4] = v;
  }
  for (int idx = tid; idx < 20 * 150; idx += 640){
    int i = idx / 150, j = idx % 150;
    const float* wrow = Wr + (size_t)j * cH;
    uint4 v = {0, 0, 0, 0};
    if (i < 18) v = ldw4(wrow, i);
    else if (i == 18){
      v.x = pack2(wrow[144], wrow[145]);
      v.y = pack2(wrow[146], wrow[147]);
      v.z = pack2(wrow[148], wrow[149]);
      v.w = 0;
    }
    *(uint4*)&WrT4[idx * 4] = v;
  }
  for (int idx = tid; idx < cLQ * 96; idx += 640){
    int l = idx / 96, s = idx % 96;
    int ch = s / 12, t = s % 12;
    u32 v = 0;
    if (t < 10){
      int p = ch * 10 + t;
      if (p < 75){
        const float* ap = aq + ((size_t)l * cB + b) * cH;
        v = pack2(ap[2 * p], ap[2 * p + 1]);
      }
    }
    aq3[idx] = v;
  }
  for (int i = tid; i < NPAD; i += 640) waS[i] = (i < cH) ? wa[i] : 0.f;
  if (tid < cH) c[tid] = 0.f;
  if (tid < 160) hsf[tid] = (f16)0.f;
  if (tid >= cH && tid < NPAD) sc[tid] = 0.f;
  if (tid >= 25 && tid < 28) alpha2[tid] = 0;
  __syncthreads();

  // prologue prefetch for step 0
  f16 xaCurH = (f16)0.f, xaNxtH = (f16)0.f;
  float ppCur = 0.f, ppNxt = 0.f;
  {
    int t0 = dir ? (cLP - 1) : 0;
    if (tid < cG) xaCurH = XA[((size_t)t0 * cB + b) * cG + tid];
    if (tid < cG && (tid & 3) == 0)
      ppCur = pp[((size_t)t0 * cB + b) * cH + (tid >> 2)];
  }

  for (int s = 0; s < cLP; s++){
    int tt = dir ? (cLP - 1 - s) : s;
    float mk = (tt < len) ? 1.f : 0.f;

    // prefetch step s+1 (consumed next iteration)
    {
      int sn = (s + 1 < cLP) ? s + 1 : s;
      int tn = dir ? (cLP - 1 - sn) : sn;
      if (tid < cG) xaNxtH = XA[((size_t)tn * cB + b) * cG + tid];
      if (tid < cG && (tid & 3) == 0)
        ppNxt = pp[((size_t)tn * cB + b) * cH + (tid >> 2)];
    }

    // P_A: sc = h@Wr^T + pp[tt]; 4 lanes per column, shfl reduce.
    if (tid < cG){
      int q = tid & 3, j = tid >> 2;
      float sA = 0.f, sB = 0.f, sC = 0.f, sD = 0.f;
      #pragma unroll
      for (int i0 = 0; i0 < 5; i0++){
        int i = 5 * q + i0;               // q=3,i0=4 -> row 19 (zeros)
        uint4 hq = *(const uint4*)&hsf[8 * i];
        uint4 wv = *(const uint4*)&WrT4[(i * 150 + j) * 4];
        sA = fdot2_(hq.x, wv.x, sA);
        sB = fdot2_(hq.y, wv.y, sB);
        sC = fdot2_(hq.z, wv.z, sC);
        sD = fdot2_(hq.w, wv.w, sD);
      }
      float v = (sA + sB) + (sC + sD);
      v += __shfl_xor(v, 1);
      v += __shfl_xor(v, 2);
      if (q == 0) sc[j] = v + ppCur;
    }
    __syncthreads();

    // P_B: gates_pre (tid<600, WhhL4 stream) FUSED with logits (tid<400).
    if (tid < cG){
      float aA = 0.f, aB = 0.f, aC = 0.f, aD = 0.f;
#define DOTW(i) { uint4 hq = *(const uint4*)&hsf[8*(i)]; \
      aA = fdot2_(hq.x, w##i.x, aA); aB = fdot2_(hq.y, w##i.y, aB); \
      aC = fdot2_(hq.z, w##i.z, aC); aD = fdot2_(hq.w, w##i.w, aD); }
      REP10(DOTW)
#undef DOTW
      #pragma unroll
      for (int p4 = 0; p4 < 9; p4++){
        uint4 hq = *(const uint4*)&hsf[80 + 8 * p4];
        uint4 wv = *(const uint4*)&WhhL4[(p4 * 600 + tid) * 4];
        aA = fdot2_(hq.x, wv.x, aA);
        aB = fdot2_(hq.y, wv.y, aB);
        aC = fdot2_(hq.z, wv.z, aC);
        aD = fdot2_(hq.w, wv.w, aD);
      }
      gl[tid] = bk + ((aA + aB) + (aC + aD));   // gates_pre parked in LDS
    }
    if (tid < 400){
      int l = tid >> 3, q8 = tid & 7;
      const u32* ab = aq3 + l * 96 + q8 * 12;
      uint4 A0 = *(const uint4*)(ab);
      uint4 A1 = *(const uint4*)(ab + 4);
      uint2 A2 = *(const uint2*)(ab + 8);
      u32 aqp[10] = {A0.x, A0.y, A0.z, A0.w, A1.x, A1.y, A1.z, A1.w, A2.x, A2.y};
      const float4* scv = (const float4*)(sc  + 20 * q8);
      const float4* wav = (const float4*)(waS + 20 * q8);
      float p0 = 0.f, p1 = 0.f;
      #pragma unroll
      for (int i = 0; i < 5; i++){
        float4 sv = scv[i];
        float4 wv = wav[i];
        float2 a0 = unp2(aqp[2 * i]);
        float2 a1 = unp2(aqp[2 * i + 1]);
        p0 += wv.x * rcp_(1.f + exp2_(2.88539008f * (a0.x + sv.x)));
        p1 += wv.y * rcp_(1.f + exp2_(2.88539008f * (a0.y + sv.y)));
        p0 += wv.z * rcp_(1.f + exp2_(2.88539008f * (a1.x + sv.z)));
        p1 += wv.w * rcp_(1.f + exp2_(2.88539008f * (a1.y + sv.w)));
      }
      float part = p0 + p1;
      part += __shfl_xor(part, 1);
      part += __shfl_xor(part, 2);
      part += __shfl_xor(part, 4);
      if (q8 == 0) loge[l] = part;
    }
    __syncthreads();

    // P_C: softmax over 50 on wave 0, f16-packed alpha pairs
    if (tid < 64){
      float lg = (tid < cLQ) ? (-2.f * loge[tid]) : -1e30f;
      float mx = lg;
      #pragma unroll
      for (int off = 32; off; off >>= 1) mx = fmaxf(mx, __shfl_xor(mx, off));
      float e = (tid < cLQ) ? exp2_((lg - mx) * 1.44269504f) : 0.f;
      float sum = e;
      #pragma unroll
      for (int off = 32; off; off >>= 1) sum += __shfl_xor(sum, off);
      float al = e * rcp_(sum);
      float alhi = __shfl_down(al, 1);
      if (tid < cLQ && !(tid & 1)) alpha2[tid >> 1] = pack2(al, alhi);
    }
    __syncthreads();

    // P_D: gl = gates_pre + mk*(XA + alpha@QW)
    if (tid < cG){
      float qA = 0.f, qB = 0.f;
#define DOTQ(i) { uint4 a4 = *(const uint4*)&alpha2[4*(i)]; \
      qA = fdot2_(a4.x, q##i.x, qA); qB = fdot2_(a4.y, q##i.y, qB); \
      qA = fdot2_(a4.z, q##i.z, qA); qB = fdot2_(a4.w, q##i.w, qB); }
      REP6(DOTQ)
#undef DOTQ
      qA = fdot2_(alpha2[24], q24s, qA);
      gl[tid] = gl[tid] + mk * ((float)xaCurH + (qA + qB));
    }
    __syncthreads();

    // P_E: cell on 150 threads; h2,c2 masked inside recurrence.
    if (tid < cH){
      float ig = sigm(gl[tid]);
      float fg = sigm(gl[cH + tid]);
      float gg = tanh_(gl[2 * cH + tid]);
      float og = sigm(gl[3 * cH + tid]);
      float c2 = (fg * c[tid] + ig * gg) * mk;
      float hh = og * tanh_(c2) * mk;
      c[tid] = c2;
      hsf[tid] = (f16)hh;
      Hr[((size_t)tt * cB + b) * (2 * cH) + dir * cH + tid] = hh;
    }
    __syncthreads();

    xaCurH = xaNxtH;
    ppCur  = ppNxt;
  }
}

// ---------------------------------------------------------------------------
// Answer pointer: 32 WGs (one per batch), 2 sequential iterations.
// ---------------------------------------------------------------------------
__global__ __launch_bounds__(640)
void ptr_k(const float* __restrict__ am, const float* __restrict__ Hr,
           const float* __restrict__ Wa, const float* __restrict__ baa,
           const float* __restrict__ wb,
           const float* __restrict__ apWih, const float* __restrict__ apWhh,
             const float* __restrict__ apb, float* __restrict__ out)
{
  int b = blockIdx.x, tid = threadIdx.x;
  __shared__ float ha[cH], ca[cH], haWa[160], wbs[160];
  __shared__ float beta[cLP], wHr[2 * cH], gl[cG], red[20];
  if (tid < cH){ ha[tid] = 0.f; ca[tid] = 0.f; }
  if (tid < 160) wbs[tid] = (tid < cH) ? wb[tid] : 0.f;
  __syncthreads();

  for (int it = 0; it < 2; ++it){
    if (tid < cH){
      float acc = baa[tid];
      const float* wr = Wa + (size_t)tid * cH;
      for (int i = 0; i < cH; i++) acc += ha[i] * wr[i];
      haWa[tid] = acc;
    } else if (tid < 160) haWa[tid] = 0.f;
    __syncthreads();

    {
      int tt = tid >> 4;
      int jq = tid & 15;
      for (int t0 = 0; t0 < cLP; t0 += 40){
        int t = t0 + tt;
        float part = 0.f;
        const float* amr = am + ((size_t)t * cB + b) * cH;
        #pragma unroll
        for (int i = 0; i < 10; i++){
          int j = jq * 10 + i;
          if (j < cH){
            float F = tanh_(amr[j] + haWa[j]);
            part += wbs[j] * F;
          }
        }
        part += __shfl_xor(part, 1);
        part += __shfl_xor(part, 2);
        part += __shfl_xor(part, 4);
        part += __shfl_xor(part, 8);
        if (jq == 0) beta[t] = part;
      }
    }
    __syncthreads();

    float x = (tid < cLP) ? beta[tid] : -1e30f;
    float mx = x;
    #pragma unroll
    for (int off = 32; off; off >>= 1) mx = fmaxf(mx, __shfl_xor(mx, off));
    if ((tid & 63) == 0) red[tid >> 6] = mx;
    __syncthreads();
    if (tid == 0){
      float m2 = red[0];
      for (int w = 1; w < 10; w++) m2 = fmaxf(m2, red[w]);
      red[16] = m2;
    }
    __syncthreads();
    mx = red[16];
    float e = (tid < cLP) ? exp2_((x - mx) * 1.44269504f) : 0.f;
    float sm = e;
    #pragma unroll
    for (int off = 32; off; off >>= 1) sm += __shfl_xor(sm, off);
    if ((tid & 63) == 0) red[tid >> 6] = sm;
    __syncthreads();
    if (tid == 0){
      float s2 = 0.f;
      for (int w = 0; w < 10; w++) s2 += red[w];
      red[17] = s2;
    }
    __syncthreads();
    float bsum = red[17];
    if (tid < cLP){
      float bt = e * rcp_(bsum);
      beta[tid] = bt;
      out[(size_t)it * cLP * cB + (size_t)tid * cB + b] = bt;
    }
    __syncthreads();

    if (tid < 2 * cH){
      float acc = 0.f;
      for (int t = 0; t < cLP; t++)
        acc += beta[t] * Hr[((size_t)t * cB + b) * (2 * cH) + tid];
      wHr[tid] = acc;
    }
    __syncthreads();

    if (tid < cG){
      float acc = apb[tid];
      const float* r1 = apWih + (size_t)tid * (2 * cH);
      for (int i = 0; i < 2 * cH; i++) acc += wHr[i] * r1[i];
      const float* r2 = apWhh + (size_t)tid * cH;
      for (int i = 0; i < cH; i++) acc += ha[i] * r2[i];
      gl[tid] = acc;
    }
    __syncthreads();
    if (tid < cH){
      float ig = sigm(gl[tid]);
      float fg = sigm(gl[cH + tid]);
      float gg = tanh_(gl[2 * cH + tid]);
      float og = sigm(gl[3 * cH + tid]);
      float c2 = fg * ca[tid] + ig * gg;
      ca[tid] = c2;
      ha[tid] = og * tanh_(c2);
    }
    __syncthreads();
  }
}

// ---------------------------------------------------------------------------
extern "C" void kernel_launch(void* const* d_in, const int* in_sizes, int n_in,
                              void* d_out, int out_size, void* d_ws, size_t ws_size,
                              hipStream_t stream)
{
  (void)in_sizes; (void)n_in; (void)out_size; (void)ws_size;
  const int*   p_ids = (const int*)d_in[0];
  const int*   q_ids = (const int*)d_in[1];
  const int*   plens = (const int*)d_in[2];
  const int*   qlens = (const int*)d_in[3];
  const float* emb   = (const float*)d_in[4];
  const float* pWih  = (const float*)d_in[5];
  const float* pWhh  = (const float*)d_in[6];
  const float* pb    = (const float*)d_in[7];
  const float* Wq    = (const float*)d_in[8];
  const float* Wp    = (const float*)d_in[9];
  const float* bp    = (const float*)d_in[10];
  const float* Wr    = (const float*)d_in[11];
  const float* wa    = (const float*)d_in[12];
  const float* mfWih = (const float*)d_in[14];
  const float* mfWhh = (const float*)d_in[15];
  const float* mfb   = (const float*)d_in[16];
  const float* mbWih = (const float*)d_in[17];
  const float* mbWhh = (const float*)d_in[18];
  const float* mbb   = (const float*)d_in[19];
  const float* Vm    = (const float*)d_in[20];
  const float* Waa   = (const float*)d_in[21];
  const float* baa   = (const float*)d_in[22];
  const float* wb    = (const float*)d_in[23];
  const float* apWih = (const float*)d_in[25];
  const float* apWhh = (const float*)d_in[26];
  const float* apb   = (const float*)d_in[27];
  float* out = (float*)d_out;

  // workspace layout (floats); total 22,560,000 f = 90.24 MB
  float* ws  = (float*)d_ws;
  float* XGp = ws;                       // [400*32][600] f32 (later aliased XAf)
  float* XGq = ws + 7680000;             // [50*32][600]  f32 (later aliased QW)
  f16*   XAb = (f16*)(ws + 8640000);     // [400*32][600] f16
  float* Hp  = ws + 12480000;            // [400*32][150]
  float* Hq  = ws + 14400000;            // [50*32][150]
  float* aqb = ws + 14640000;            // [50*32][150]
  float* ppb = ws + 14880000;            // [400*32][150]
  float* Hr  = ws + 16800000;            // [400*32][300]
  float* am  = ws + 20640000;            // [400*32][150]
  f16*   XAf = (f16*)XGp;                // alias: XGp dead after enc_k
  f16*   QWf = (f16*)XGq;                // alias: XGq dead after enc_k
  f16*   QWb = QWf + (size_t)1600 * 600;

  dim3 blk(256);
  gemm_k<<<dim3(10,200), blk, 0, stream>>>(nullptr, p_ids, emb, pWih, 300, pb,
                                           XGp, nullptr, 12800, 600, 300);
  gemm_k<<<dim3(10, 25), blk, 0, stream>>>(nullptr, q_ids, emb, pWih, 300, pb,
                                           XGq, nullptr, 1600, 600, 300);
  enc_k<<<64, 640, 0, stream>>>(XGp, XGq, pWhh, plens, qlens, Hp, Hq);
  gemm_k<<<dim3(3,200), blk, 0, stream>>>(Hp, nullptr, nullptr, Wp, 150, bp,
                                          ppb, nullptr, 12800, 150, 150);
  gemm_k<<<dim3(3, 25), blk, 0, stream>>>(Hq, nullptr, nullptr, Wq, 150, nullptr,
                                          aqb, nullptr, 1600, 150, 150);
  gemm_k<<<dim3(10,200), blk, 0, stream>>>(Hp, nullptr, nullptr, mfWih, 300, nullptr,
                                           nullptr, XAf, 12800, 600, 150);
  gemm_k<<<dim3(10,200), blk, 0, stream>>>(Hp, nullptr, nullptr, mbWih, 300, nullptr,
                                           nullptr, XAb, 12800, 600, 150);
  gemm_k<<<dim3(10, 25), blk, 0, stream>>>(Hq, nullptr, nullptr, mfWih + 150, 300, nullptr,
                                           nullptr, QWf, 1600, 600, 150);
  gemm_k<<<dim3(10, 25), blk, 0, stream>>>(Hq, nullptr, nullptr, mbWih + 150, 300, nullptr,
                                           nullptr, QWb, 1600, 600, 150);
  match_k<<<64, 640, 0, stream>>>(XAf, XAb, QWf, QWb, aqb, ppb, mfWhh, mbWhh,
                                  mfb, mbb, Wr, wa, plens, Hr);
  gemm_k<<<dim3(3,200), blk, 0, stream>>>(Hr, nullptr, nullptr, Vm, 300, nullptr,
                                          am, nullptr, 12800, 150, 300);
  ptr_k<<<32, 640, 0, stream>>>(am, Hr, Waa, baa, wb, apWih, apWhh, apb, out);
}